// Round 2
// baseline (1680.758 us; speedup 1.0000x reference)
//
#include <hip/hip_runtime.h>
#include <math.h>

#define HD 256
#define NHEAD 4
#define CH 64
#define NLAYER 3
#define NEG_SLOPE 0.2f

// ---------------------------------------------------------------------------
// h0 = x @ Wn + bn_b      (x: [N,9], Wn: [9,256])
// ---------------------------------------------------------------------------
__global__ __launch_bounds__(256) void node_embed_kernel(
    const float* __restrict__ x, const float* __restrict__ Wn,
    const float* __restrict__ bn_b, float* __restrict__ h, int N) {
  int n = blockIdx.x;
  int c = threadIdx.x;
  __shared__ float xs[9];
  if (c < 9) xs[c] = x[(size_t)n * 9 + c];
  __syncthreads();
  float v = bn_b[c];
#pragma unroll
  for (int k = 0; k < 9; ++k) v += xs[k] * Wn[k * HD + c];
  h[(size_t)n * HD + c] = v;
}

// ---------------------------------------------------------------------------
// Fold edge path: Wc[5][12] = We @ w_eff,  bc[12] = be_b @ w_eff
// where w_eff[j, l*4+h] = sum_c lin_edge_w[l, j, h*64+c] * att_edge[l, h, c]
// ---------------------------------------------------------------------------
__global__ __launch_bounds__(256) void precompute_wc_kernel(
    const float* __restrict__ lin_edge_w, const float* __restrict__ att_edge,
    const float* __restrict__ We, const float* __restrict__ be_b,
    float* __restrict__ Wc, float* __restrict__ bc) {
  __shared__ float weff[256][12];
  int j = threadIdx.x;
#pragma unroll
  for (int l = 0; l < NLAYER; ++l) {
#pragma unroll
    for (int hh = 0; hh < NHEAD; ++hh) {
      float s = 0.f;
      const float* lw = lin_edge_w + (size_t)l * HD * HD + (size_t)j * HD + hh * CH;
      const float* ae = att_edge + l * HD + hh * CH;
      for (int c = 0; c < CH; ++c) s += lw[c] * ae[c];
      weff[j][l * NHEAD + hh] = s;
    }
  }
  __syncthreads();
  if (j < 60) {
    int k = j / 12, lh = j % 12;
    float s = 0.f;
    for (int t = 0; t < 256; ++t) s += We[k * HD + t] * weff[t][lh];
    Wc[k * 12 + lh] = s;
  } else if (j < 72) {
    int lh = j - 60;
    float s = 0.f;
    for (int t = 0; t < 256; ++t) s += be_b[t] * weff[t][lh];
    bc[lh] = s;
  }
}

// ---------------------------------------------------------------------------
// CSR build by destination (col)
// ---------------------------------------------------------------------------
__global__ __launch_bounds__(256) void count_deg_kernel(
    const int* __restrict__ col, int* __restrict__ deg, int E) {
  int e = blockIdx.x * 256 + threadIdx.x;
  if (e < E) atomicAdd(&deg[col[e]], 1);
}

__global__ __launch_bounds__(256) void tile_sums_kernel(
    const int* __restrict__ deg, int* __restrict__ tsum, int N) {
  __shared__ int red[256];
  int i = blockIdx.x * 256 + threadIdx.x;
  red[threadIdx.x] = (i < N) ? deg[i] : 0;
  __syncthreads();
  for (int off = 128; off > 0; off >>= 1) {
    if (threadIdx.x < off) red[threadIdx.x] += red[threadIdx.x + off];
    __syncthreads();
  }
  if (threadIdx.x == 0) tsum[blockIdx.x] = red[0];
}

__global__ __launch_bounds__(64) void scan_tsums_kernel(
    const int* __restrict__ tsum, int* __restrict__ toff, int T) {
  int lane = threadIdx.x;
  int carry = 0;
  for (int base = 0; base < T; base += 64) {
    int i = base + lane;
    int orig = (i < T) ? tsum[i] : 0;
    int v = orig;
#pragma unroll
    for (int off = 1; off < 64; off <<= 1) {
      int t = __shfl_up(v, off, 64);
      if (lane >= off) v += t;
    }
    if (i < T) toff[i] = carry + v - orig;
    carry += __shfl(v, 63, 64);
  }
}

__global__ __launch_bounds__(256) void scan_local_kernel(
    const int* __restrict__ deg, const int* __restrict__ toff,
    int* __restrict__ row_start, int N, int E) {
  __shared__ int buf[256];
  int i = blockIdx.x * 256 + threadIdx.x;
  int v = (i < N) ? deg[i] : 0;
  buf[threadIdx.x] = v;
  __syncthreads();
  for (int off = 1; off < 256; off <<= 1) {
    int t = (threadIdx.x >= off) ? buf[threadIdx.x - off] : 0;
    __syncthreads();
    buf[threadIdx.x] += t;
    __syncthreads();
  }
  if (i < N) row_start[i] = toff[blockIdx.x] + buf[threadIdx.x] - v;
  if (blockIdx.x == 0 && threadIdx.x == 0) row_start[N] = E;
}

__global__ __launch_bounds__(256) void scatter_csr_kernel(
    const int* __restrict__ col, const int* __restrict__ row_start,
    int* __restrict__ cursor, int* __restrict__ csr, int E) {
  int e = blockIdx.x * 256 + threadIdx.x;
  if (e < E) {
    int c = col[e];
    int p = atomicAdd(&cursor[c], 1);
    csr[row_start[c] + p] = e;
  }
}

// ---------------------------------------------------------------------------
// fp32 SGEMM: C[M,256] = A[M,256] @ B[256,256]; 64x64 tile, 256 thr, 4x4/thr
// ---------------------------------------------------------------------------
__global__ __launch_bounds__(256) void sgemm_kernel(
    const float* __restrict__ A, const float* __restrict__ B,
    float* __restrict__ C, int M) {
  __shared__ float As[16][68];  // [k][m], padded
  __shared__ float Bs[16][64];  // [k][n]
  const int tid = threadIdx.x;
  const int bm = blockIdx.x * 64;
  const int bn = blockIdx.y * 64;
  const int tx = tid & 15, ty = tid >> 4;
  const int arow = tid >> 2, acol = (tid & 3) << 2;
  const int brow = tid >> 4, bcol = (tid & 15) << 2;
  const bool avalid = (bm + arow) < M;
  const float* Aptr = A + (size_t)(bm + arow) * HD + acol;
  const float* Bptr = B + (size_t)brow * HD + bn + bcol;
  float acc[4][4] = {};
  for (int k0 = 0; k0 < HD; k0 += 16) {
    float4 av = avalid ? *(const float4*)(Aptr + k0) : make_float4(0.f, 0.f, 0.f, 0.f);
    float4 bv = *(const float4*)(Bptr + (size_t)k0 * HD);
    __syncthreads();
    As[acol + 0][arow] = av.x;
    As[acol + 1][arow] = av.y;
    As[acol + 2][arow] = av.z;
    As[acol + 3][arow] = av.w;
    *(float4*)&Bs[brow][bcol] = bv;
    __syncthreads();
#pragma unroll
    for (int k = 0; k < 16; ++k) {
      float4 a = *(const float4*)&As[k][ty * 4];
      float4 b = *(const float4*)&Bs[k][tx * 4];
      acc[0][0] += a.x * b.x; acc[0][1] += a.x * b.y; acc[0][2] += a.x * b.z; acc[0][3] += a.x * b.w;
      acc[1][0] += a.y * b.x; acc[1][1] += a.y * b.y; acc[1][2] += a.y * b.z; acc[1][3] += a.y * b.w;
      acc[2][0] += a.z * b.x; acc[2][1] += a.z * b.y; acc[2][2] += a.z * b.z; acc[2][3] += a.z * b.w;
      acc[3][0] += a.w * b.x; acc[3][1] += a.w * b.y; acc[3][2] += a.w * b.z; acc[3][3] += a.w * b.w;
    }
  }
#pragma unroll
  for (int i = 0; i < 4; ++i) {
    int r = bm + ty * 4 + i;
    if (r < M)
      *(float4*)&C[(size_t)r * HD + bn + tx * 4] =
          make_float4(acc[i][0], acc[i][1], acc[i][2], acc[i][3]);
  }
}

// ---------------------------------------------------------------------------
// a_src[n,h] = xh[n,h,:]·att_s[h,:],  a_dst likewise. One wave per (n,h).
// ---------------------------------------------------------------------------
__global__ __launch_bounds__(256) void attn_coef_kernel(
    const float* __restrict__ xh, const float* __restrict__ att_s,
    const float* __restrict__ att_d, float* __restrict__ a_src,
    float* __restrict__ a_dst, int N) {
  int n = blockIdx.x;
  int tid = threadIdx.x;
  int hh = tid >> 6, c = tid & 63;
  float v = xh[(size_t)n * HD + tid];
  float ds = v * att_s[tid];
  float dd = v * att_d[tid];
#pragma unroll
  for (int off = 32; off > 0; off >>= 1) {
    ds += __shfl_xor(ds, off, 64);
    dd += __shfl_xor(dd, off, 64);
  }
  if (c == 0) {
    a_src[(size_t)n * NHEAD + hh] = ds;
    a_dst[(size_t)n * NHEAD + hh] = dd;
  }
}

// ---------------------------------------------------------------------------
// Per-edge: a_e (pre-activation, saved for loop_attr) and leaky-relu logit
// ---------------------------------------------------------------------------
__global__ __launch_bounds__(256) void edge_logits_kernel(
    const float* __restrict__ edge_attr, const int* __restrict__ row,
    const int* __restrict__ col, const float* __restrict__ a_src,
    const float* __restrict__ a_dst, const float* __restrict__ Wc,
    const float* __restrict__ bc, int lsel, float* __restrict__ alpha4,
    float* __restrict__ ae4, int E) {
  __shared__ float sWc[60];
  __shared__ float sbc[12];
  int t = threadIdx.x;
  if (t < 60) sWc[t] = Wc[t];
  if (t < 12) sbc[t] = bc[t];
  __syncthreads();
  int e = blockIdx.x * 256 + t;
  if (e >= E) return;
  int r = row[e], c = col[e];
  float ea[5];
#pragma unroll
  for (int k = 0; k < 5; ++k) ea[k] = edge_attr[(size_t)e * 5 + k];
#pragma unroll
  for (int hh = 0; hh < NHEAD; ++hh) {
    int lh = lsel * NHEAD + hh;
    float s = sbc[lh];
#pragma unroll
    for (int k = 0; k < 5; ++k) s += ea[k] * sWc[k * 12 + lh];
    ae4[(size_t)e * NHEAD + hh] = s;
    float lg = a_src[(size_t)r * NHEAD + hh] + a_dst[(size_t)c * NHEAD + hh] + s;
    alpha4[(size_t)e * NHEAD + hh] = (lg >= 0.f) ? lg : NEG_SLOPE * lg;
  }
}

// ---------------------------------------------------------------------------
// Per-node: fused segment-softmax (incl. self-loop) + weighted gather-sum +
// bias + BN(eval) + ReLU.  Block = 1 node, 256 threads (thread = channel).
// ---------------------------------------------------------------------------
__global__ __launch_bounds__(256) void aggregate_kernel(
    const float* __restrict__ xh, const float* __restrict__ alpha4,
    const float* __restrict__ ae4, const float* __restrict__ a_src,
    const float* __restrict__ a_dst, const int* __restrict__ row,
    const int* __restrict__ row_start, const int* __restrict__ csr,
    const float* __restrict__ cb, const float* __restrict__ gm,
    const float* __restrict__ bt, float inv_std, float* __restrict__ hout,
    int N) {
  int n = blockIdx.x;
  int tid = threadIdx.x;
  int hh = tid >> 6;
  __shared__ float s_m[4], s_is[4], s_ws[4];
  int s = row_start[n], e = row_start[n + 1];

  if (tid < 64) {
    int lane = tid;
    float mx[4] = {-3e38f, -3e38f, -3e38f, -3e38f};
    float aes[4] = {0.f, 0.f, 0.f, 0.f};
    for (int i = s + lane; i < e; i += 64) {
      int eid = csr[i];
      float4 al = *(const float4*)(alpha4 + (size_t)eid * 4);
      float4 av = *(const float4*)(ae4 + (size_t)eid * 4);
      mx[0] = fmaxf(mx[0], al.x); mx[1] = fmaxf(mx[1], al.y);
      mx[2] = fmaxf(mx[2], al.z); mx[3] = fmaxf(mx[3], al.w);
      aes[0] += av.x; aes[1] += av.y; aes[2] += av.z; aes[3] += av.w;
    }
#pragma unroll
    for (int off = 32; off > 0; off >>= 1) {
#pragma unroll
      for (int t = 0; t < 4; ++t) {
        mx[t] = fmaxf(mx[t], __shfl_xor(mx[t], off, 64));
        aes[t] += __shfl_xor(aes[t], off, 64);
      }
    }
    float dinv = (e > s) ? 1.0f / (float)(e - s) : 1.0f;
    float4 asv = *(const float4*)(a_src + (size_t)n * 4);
    float4 adv = *(const float4*)(a_dst + (size_t)n * 4);
    float base[4] = {asv.x + adv.x, asv.y + adv.y, asv.z + adv.z, asv.w + adv.w};
    float sl[4], m[4];
#pragma unroll
    for (int t = 0; t < 4; ++t) {
      float lg = base[t] + aes[t] * dinv;
      sl[t] = (lg >= 0.f) ? lg : NEG_SLOPE * lg;
      m[t] = fmaxf(mx[t], sl[t]);
    }
    float sm[4] = {0.f, 0.f, 0.f, 0.f};
    for (int i = s + lane; i < e; i += 64) {
      int eid = csr[i];
      float4 al = *(const float4*)(alpha4 + (size_t)eid * 4);
      sm[0] += __expf(al.x - m[0]); sm[1] += __expf(al.y - m[1]);
      sm[2] += __expf(al.z - m[2]); sm[3] += __expf(al.w - m[3]);
    }
#pragma unroll
    for (int off = 32; off > 0; off >>= 1) {
#pragma unroll
      for (int t = 0; t < 4; ++t) sm[t] += __shfl_xor(sm[t], off, 64);
    }
    if (lane == 0) {
#pragma unroll
      for (int t = 0; t < 4; ++t) {
        float self_e = __expf(sl[t] - m[t]);
        float is = 1.0f / (sm[t] + self_e + 1e-16f);
        s_m[t] = m[t];
        s_is[t] = is;
        s_ws[t] = self_e * is;
      }
    }
  }
  __syncthreads();

  float m_h = s_m[hh], is_h = s_is[hh];
  float acc = s_ws[hh] * xh[(size_t)n * HD + tid];
  for (int i = s; i < e; ++i) {
    int eid = csr[i];
    int r = row[eid];
    float a = alpha4[(size_t)eid * 4 + hh];
    float w = __expf(a - m_h) * is_h;
    acc += w * xh[(size_t)r * HD + tid];
  }
  float v = acc + cb[tid];
  v = v * inv_std * gm[tid] + bt[tid];
  hout[(size_t)n * HD + tid] = fmaxf(v, 0.f);
}

// ---------------------------------------------------------------------------
// Global mean pool over sorted batch ids. One block per graph.
// ---------------------------------------------------------------------------
__global__ __launch_bounds__(256) void pool_kernel(
    const float* __restrict__ h, const int* __restrict__ batch,
    float* __restrict__ out, int N) {
  int g = blockIdx.x;
  int tid = threadIdx.x;
  __shared__ int s_lo, s_hi;
  if (tid == 0) {
    int lo = 0, hi = N;
    while (lo < hi) { int mid = (lo + hi) >> 1; if (batch[mid] < g) lo = mid + 1; else hi = mid; }
    s_lo = lo;
    lo = 0; hi = N;
    while (lo < hi) { int mid = (lo + hi) >> 1; if (batch[mid] < g + 1) lo = mid + 1; else hi = mid; }
    s_hi = lo;
  }
  __syncthreads();
  int lo = s_lo, hi = s_hi;
  float acc = 0.f;
  for (int n = lo; n < hi; ++n) acc += h[(size_t)n * HD + tid];
  int cnt = hi - lo;
  out[(size_t)g * HD + tid] = acc / (float)(cnt > 0 ? cnt : 1);
}

// ---------------------------------------------------------------------------
extern "C" void kernel_launch(void* const* d_in, const int* in_sizes, int n_in,
                              void* d_out, int out_size, void* d_ws, size_t ws_size,
                              hipStream_t stream) {
  const float* x = (const float*)d_in[0];
  const int* ei = (const int*)d_in[1];          // harness passes integers as int32
  const float* edge_attr = (const float*)d_in[2];
  const int* batch = (const int*)d_in[3];       // int32
  const float* Wn = (const float*)d_in[4];
  const float* bn_b = (const float*)d_in[5];
  const float* We = (const float*)d_in[6];
  const float* be_b = (const float*)d_in[7];
  const float* lin_w = (const float*)d_in[8];
  const float* att_src = (const float*)d_in[9];
  const float* att_dst = (const float*)d_in[10];
  const float* lin_edge_w = (const float*)d_in[11];
  const float* att_edge = (const float*)d_in[12];
  const float* conv_bias = (const float*)d_in[13];
  const float* gamma = (const float*)d_in[14];
  const float* beta = (const float*)d_in[15];

  const int N = in_sizes[3];
  const int E = in_sizes[1] / 2;
  const int G = out_size / HD;
  const int* row = ei;
  const int* col = ei + E;

  char* ws = (char*)d_ws;
  size_t off = 0;
  auto alloc = [&](size_t bytes) -> char* {
    char* p = ws + off;
    off += (bytes + 255) & ~(size_t)255;
    return p;
  };
  float* h = (float*)alloc((size_t)N * HD * 4);
  float* xh = (float*)alloc((size_t)N * HD * 4);
  float* a_src = (float*)alloc((size_t)N * NHEAD * 4);
  float* a_dst = (float*)alloc((size_t)N * NHEAD * 4);
  float* alpha4 = (float*)alloc((size_t)E * NHEAD * 4);
  float* ae4 = (float*)alloc((size_t)E * NHEAD * 4);
  int* deg = (int*)alloc((size_t)N * 4);
  int* row_start = (int*)alloc((size_t)(N + 1) * 4);
  int* cursor = (int*)alloc((size_t)N * 4);
  int* csr = (int*)alloc((size_t)E * 4);
  int* tsum = (int*)alloc(4096);
  int* toff = (int*)alloc(4096);
  float* Wc = (float*)alloc(64 * 4);
  float* bc = (float*)alloc(16 * 4);

  hipMemsetAsync(deg, 0, (size_t)N * 4, stream);
  hipMemsetAsync(cursor, 0, (size_t)N * 4, stream);

  node_embed_kernel<<<N, 256, 0, stream>>>(x, Wn, bn_b, h, N);
  precompute_wc_kernel<<<1, 256, 0, stream>>>(lin_edge_w, att_edge, We, be_b, Wc, bc);
  count_deg_kernel<<<(E + 255) / 256, 256, 0, stream>>>(col, deg, E);
  int T = (N + 255) / 256;
  tile_sums_kernel<<<T, 256, 0, stream>>>(deg, tsum, N);
  scan_tsums_kernel<<<1, 64, 0, stream>>>(tsum, toff, T);
  scan_local_kernel<<<T, 256, 0, stream>>>(deg, toff, row_start, N, E);
  scatter_csr_kernel<<<(E + 255) / 256, 256, 0, stream>>>(col, row_start, cursor, csr, E);

  const float inv_std = 1.0f / sqrtf(1.0f + 1e-5f);
  for (int l = 0; l < NLAYER; ++l) {
    dim3 gg((N + 63) / 64, HD / 64);
    sgemm_kernel<<<gg, 256, 0, stream>>>(h, lin_w + (size_t)l * HD * HD, xh, N);
    attn_coef_kernel<<<N, 256, 0, stream>>>(xh, att_src + l * HD, att_dst + l * HD,
                                            a_src, a_dst, N);
    edge_logits_kernel<<<(E + 255) / 256, 256, 0, stream>>>(
        edge_attr, row, col, a_src, a_dst, Wc, bc, l, alpha4, ae4, E);
    aggregate_kernel<<<N, 256, 0, stream>>>(
        xh, alpha4, ae4, a_src, a_dst, row, row_start, csr,
        conv_bias + l * HD, gamma + l * HD, beta + l * HD, inv_std, h, N);
  }
  pool_kernel<<<G, 256, 0, stream>>>(h, batch, (float*)d_out, N);
}

// Round 3
// 1151.209 us; speedup vs baseline: 1.4600x; 1.4600x over previous
//
#include <hip/hip_runtime.h>
#include <math.h>

#define HD 256
#define NHEAD 4
#define CH 64
#define NLAYER 3
#define NEG_SLOPE 0.2f

// ---------------------------------------------------------------------------
// h0 = x @ Wn + bn_b      (x: [N,9], Wn: [9,256])
// ---------------------------------------------------------------------------
__global__ __launch_bounds__(256) void node_embed_kernel(
    const float* __restrict__ x, const float* __restrict__ Wn,
    const float* __restrict__ bn_b, float* __restrict__ h, int N) {
  int n = blockIdx.x;
  int c = threadIdx.x;
  __shared__ float xs[9];
  if (c < 9) xs[c] = x[(size_t)n * 9 + c];
  __syncthreads();
  float v = bn_b[c];
#pragma unroll
  for (int k = 0; k < 9; ++k) v += xs[k] * Wn[k * HD + c];
  h[(size_t)n * HD + c] = v;
}

// ---------------------------------------------------------------------------
// Fold edge path: Wc[5][12] = We @ w_eff,  bc[12] = be_b @ w_eff
// ---------------------------------------------------------------------------
__global__ __launch_bounds__(256) void precompute_wc_kernel(
    const float* __restrict__ lin_edge_w, const float* __restrict__ att_edge,
    const float* __restrict__ We, const float* __restrict__ be_b,
    float* __restrict__ Wc, float* __restrict__ bc) {
  __shared__ float weff[256][12];
  int j = threadIdx.x;
#pragma unroll
  for (int l = 0; l < NLAYER; ++l) {
#pragma unroll
    for (int hh = 0; hh < NHEAD; ++hh) {
      float s = 0.f;
      const float* lw = lin_edge_w + (size_t)l * HD * HD + (size_t)j * HD + hh * CH;
      const float* ae = att_edge + l * HD + hh * CH;
      for (int c = 0; c < CH; ++c) s += lw[c] * ae[c];
      weff[j][l * NHEAD + hh] = s;
    }
  }
  __syncthreads();
  if (j < 60) {
    int k = j / 12, lh = j % 12;
    float s = 0.f;
    for (int t = 0; t < 256; ++t) s += We[k * HD + t] * weff[t][lh];
    Wc[k * 12 + lh] = s;
  } else if (j < 72) {
    int lh = j - 60;
    float s = 0.f;
    for (int t = 0; t < 256; ++t) s += be_b[t] * weff[t][lh];
    bc[lh] = s;
  }
}

// ---------------------------------------------------------------------------
// CSR build by destination (col)
// ---------------------------------------------------------------------------
__global__ __launch_bounds__(256) void count_deg_kernel(
    const int* __restrict__ col, int* __restrict__ deg, int E) {
  int e = blockIdx.x * 256 + threadIdx.x;
  if (e < E) atomicAdd(&deg[col[e]], 1);
}

__global__ __launch_bounds__(256) void tile_sums_kernel(
    const int* __restrict__ deg, int* __restrict__ tsum, int N) {
  __shared__ int red[256];
  int i = blockIdx.x * 256 + threadIdx.x;
  red[threadIdx.x] = (i < N) ? deg[i] : 0;
  __syncthreads();
  for (int off = 128; off > 0; off >>= 1) {
    if (threadIdx.x < off) red[threadIdx.x] += red[threadIdx.x + off];
    __syncthreads();
  }
  if (threadIdx.x == 0) tsum[blockIdx.x] = red[0];
}

__global__ __launch_bounds__(64) void scan_tsums_kernel(
    const int* __restrict__ tsum, int* __restrict__ toff, int T) {
  int lane = threadIdx.x;
  int carry = 0;
  for (int base = 0; base < T; base += 64) {
    int i = base + lane;
    int orig = (i < T) ? tsum[i] : 0;
    int v = orig;
#pragma unroll
    for (int off = 1; off < 64; off <<= 1) {
      int t = __shfl_up(v, off, 64);
      if (lane >= off) v += t;
    }
    if (i < T) toff[i] = carry + v - orig;
    carry += __shfl(v, 63, 64);
  }
}

__global__ __launch_bounds__(256) void scan_local_kernel(
    const int* __restrict__ deg, const int* __restrict__ toff,
    int* __restrict__ row_start, int N, int E) {
  __shared__ int buf[256];
  int i = blockIdx.x * 256 + threadIdx.x;
  int v = (i < N) ? deg[i] : 0;
  buf[threadIdx.x] = v;
  __syncthreads();
  for (int off = 1; off < 256; off <<= 1) {
    int t = (threadIdx.x >= off) ? buf[threadIdx.x - off] : 0;
    __syncthreads();
    buf[threadIdx.x] += t;
    __syncthreads();
  }
  if (i < N) row_start[i] = toff[blockIdx.x] + buf[threadIdx.x] - v;
  if (blockIdx.x == 0 && threadIdx.x == 0) row_start[N] = E;
}

// Writes CSR-ordered source index (rowc) and the inverse permutation ipos.
__global__ __launch_bounds__(256) void scatter_csr_kernel(
    const int* __restrict__ row, const int* __restrict__ col,
    const int* __restrict__ row_start, int* __restrict__ cursor,
    int* __restrict__ rowc, int* __restrict__ ipos, int E) {
  int e = blockIdx.x * 256 + threadIdx.x;
  if (e < E) {
    int c = col[e];
    int p = atomicAdd(&cursor[c], 1);
    int slot = row_start[c] + p;
    rowc[slot] = row[e];
    ipos[e] = slot;
  }
}

// ---------------------------------------------------------------------------
// fp32 SGEMM: C[M,256] = A[M,256] @ B[256,256]; 64x64 tile, 256 thr, 4x4/thr
// ---------------------------------------------------------------------------
__global__ __launch_bounds__(256) void sgemm_kernel(
    const float* __restrict__ A, const float* __restrict__ B,
    float* __restrict__ C, int M) {
  __shared__ float As[16][68];
  __shared__ float Bs[16][64];
  const int tid = threadIdx.x;
  const int bm = blockIdx.x * 64;
  const int bn = blockIdx.y * 64;
  const int tx = tid & 15, ty = tid >> 4;
  const int arow = tid >> 2, acol = (tid & 3) << 2;
  const int brow = tid >> 4, bcol = (tid & 15) << 2;
  const bool avalid = (bm + arow) < M;
  const float* Aptr = A + (size_t)(bm + arow) * HD + acol;
  const float* Bptr = B + (size_t)brow * HD + bn + bcol;
  float acc[4][4] = {};
  for (int k0 = 0; k0 < HD; k0 += 16) {
    float4 av = avalid ? *(const float4*)(Aptr + k0) : make_float4(0.f, 0.f, 0.f, 0.f);
    float4 bv = *(const float4*)(Bptr + (size_t)k0 * HD);
    __syncthreads();
    As[acol + 0][arow] = av.x;
    As[acol + 1][arow] = av.y;
    As[acol + 2][arow] = av.z;
    As[acol + 3][arow] = av.w;
    *(float4*)&Bs[brow][bcol] = bv;
    __syncthreads();
#pragma unroll
    for (int k = 0; k < 16; ++k) {
      float4 a = *(const float4*)&As[k][ty * 4];
      float4 b = *(const float4*)&Bs[k][tx * 4];
      acc[0][0] += a.x * b.x; acc[0][1] += a.x * b.y; acc[0][2] += a.x * b.z; acc[0][3] += a.x * b.w;
      acc[1][0] += a.y * b.x; acc[1][1] += a.y * b.y; acc[1][2] += a.y * b.z; acc[1][3] += a.y * b.w;
      acc[2][0] += a.z * b.x; acc[2][1] += a.z * b.y; acc[2][2] += a.z * b.z; acc[2][3] += a.z * b.w;
      acc[3][0] += a.w * b.x; acc[3][1] += a.w * b.y; acc[3][2] += a.w * b.z; acc[3][3] += a.w * b.w;
    }
  }
#pragma unroll
  for (int i = 0; i < 4; ++i) {
    int r = bm + ty * 4 + i;
    if (r < M)
      *(float4*)&C[(size_t)r * HD + bn + tx * 4] =
          make_float4(acc[i][0], acc[i][1], acc[i][2], acc[i][3]);
  }
}

// ---------------------------------------------------------------------------
// a_src[n,h] = xh[n,h,:]·att_s[h,:],  a_dst likewise. One wave per (n,h).
// ---------------------------------------------------------------------------
__global__ __launch_bounds__(256) void attn_coef_kernel(
    const float* __restrict__ xh, const float* __restrict__ att_s,
    const float* __restrict__ att_d, float* __restrict__ a_src,
    float* __restrict__ a_dst, int N) {
  int n = blockIdx.x;
  int tid = threadIdx.x;
  int hh = tid >> 6, c = tid & 63;
  float v = xh[(size_t)n * HD + tid];
  float ds = v * att_s[tid];
  float dd = v * att_d[tid];
#pragma unroll
  for (int off = 32; off > 0; off >>= 1) {
    ds += __shfl_xor(ds, off, 64);
    dd += __shfl_xor(dd, off, 64);
  }
  if (c == 0) {
    a_src[(size_t)n * NHEAD + hh] = ds;
    a_dst[(size_t)n * NHEAD + hh] = dd;
  }
}

// ---------------------------------------------------------------------------
// Per-edge logits, written directly in CSR order via ipos.
// ---------------------------------------------------------------------------
__global__ __launch_bounds__(256) void edge_logits_kernel(
    const float* __restrict__ edge_attr, const int* __restrict__ row,
    const int* __restrict__ col, const int* __restrict__ ipos,
    const float* __restrict__ a_src, const float* __restrict__ a_dst,
    const float* __restrict__ Wc, const float* __restrict__ bc, int lsel,
    float* __restrict__ alpha4c, float* __restrict__ ae4c, int E) {
  __shared__ float sWc[60];
  __shared__ float sbc[12];
  int t = threadIdx.x;
  if (t < 60) sWc[t] = Wc[t];
  if (t < 12) sbc[t] = bc[t];
  __syncthreads();
  int e = blockIdx.x * 256 + t;
  if (e >= E) return;
  int r = row[e], c = col[e], slot = ipos[e];
  float ea[5];
#pragma unroll
  for (int k = 0; k < 5; ++k) ea[k] = edge_attr[(size_t)e * 5 + k];
  float al[NHEAD], av[NHEAD];
#pragma unroll
  for (int hh = 0; hh < NHEAD; ++hh) {
    int lh = lsel * NHEAD + hh;
    float s = sbc[lh];
#pragma unroll
    for (int k = 0; k < 5; ++k) s += ea[k] * sWc[k * 12 + lh];
    av[hh] = s;
    float lg = a_src[(size_t)r * NHEAD + hh] + a_dst[(size_t)c * NHEAD + hh] + s;
    al[hh] = (lg >= 0.f) ? lg : NEG_SLOPE * lg;
  }
  *(float4*)(alpha4c + (size_t)slot * 4) = make_float4(al[0], al[1], al[2], al[3]);
  *(float4*)(ae4c + (size_t)slot * 4) = make_float4(av[0], av[1], av[2], av[3]);
}

// ---------------------------------------------------------------------------
// Per-node softmax stats: 1 wave per node. Converts alpha4c in place to
// exp(a - m); stores per-node inv-sum (nis) and unnormalized self weight.
// Lane layout: hh = lane&3, slot group j = lane>>2 (16 slots per pass).
// ---------------------------------------------------------------------------
__global__ __launch_bounds__(64) void softmax_stats_kernel(
    const int* __restrict__ row_start, float* __restrict__ alpha4c,
    const float* __restrict__ ae4c, const float* __restrict__ a_src,
    const float* __restrict__ a_dst, float* __restrict__ nis,
    float* __restrict__ nselfe, int N) {
  int n = blockIdx.x;
  int lane = threadIdx.x;
  int hh = lane & 3, j = lane >> 2;
  int s = row_start[n], e = row_start[n + 1];

  float mx = -3e38f, aes = 0.f;
  for (int i = s + j; i < e; i += 16) {
    float a = alpha4c[(size_t)i * 4 + hh];
    float v = ae4c[(size_t)i * 4 + hh];
    mx = fmaxf(mx, a);
    aes += v;
  }
#pragma unroll
  for (int off = 4; off < 64; off <<= 1) {
    mx = fmaxf(mx, __shfl_xor(mx, off, 64));
    aes += __shfl_xor(aes, off, 64);
  }
  float dinv = (e > s) ? 1.0f / (float)(e - s) : 1.0f;
  float base = a_src[(size_t)n * 4 + hh] + a_dst[(size_t)n * 4 + hh];
  float lg = base + aes * dinv;
  float sl = (lg >= 0.f) ? lg : NEG_SLOPE * lg;
  float m = fmaxf(mx, sl);

  float sm = 0.f;
  for (int i = s + j; i < e; i += 16) {
    float a = alpha4c[(size_t)i * 4 + hh];
    float ex = __expf(a - m);
    alpha4c[(size_t)i * 4 + hh] = ex;  // in place: each lane owns its element
    sm += ex;
  }
#pragma unroll
  for (int off = 4; off < 64; off <<= 1) sm += __shfl_xor(sm, off, 64);
  float self_e = __expf(sl - m);
  if (lane < 4) {
    nis[(size_t)n * 4 + hh] = 1.0f / (sm + self_e + 1e-16f);
    nselfe[(size_t)n * 4 + hh] = self_e;
  }
}

// ---------------------------------------------------------------------------
// Per-node gather-sum. No index chains: rowc/weights are CSR-contiguous.
// Unroll x4 for 4 independent gathers in flight. Epilogue: *is, bias, BN, ReLU.
// ---------------------------------------------------------------------------
__global__ __launch_bounds__(256) void aggregate_kernel(
    const float* __restrict__ xh, const float* __restrict__ alpha4c,
    const int* __restrict__ rowc, const int* __restrict__ row_start,
    const float* __restrict__ nis, const float* __restrict__ nselfe,
    const float* __restrict__ cb, const float* __restrict__ gm,
    const float* __restrict__ bt, float inv_std, float* __restrict__ hout,
    int N) {
  int n = blockIdx.x;
  int tid = threadIdx.x;
  int hh = tid >> 6;
  int s = row_start[n], e = row_start[n + 1];

  float acc = nselfe[(size_t)n * 4 + hh] * xh[(size_t)n * HD + tid];
  int i = s;
  for (; i + 4 <= e; i += 4) {
    int r0 = rowc[i], r1 = rowc[i + 1], r2 = rowc[i + 2], r3 = rowc[i + 3];
    float w0 = alpha4c[(size_t)i * 4 + hh];
    float w1 = alpha4c[(size_t)(i + 1) * 4 + hh];
    float w2 = alpha4c[(size_t)(i + 2) * 4 + hh];
    float w3 = alpha4c[(size_t)(i + 3) * 4 + hh];
    float x0 = xh[(size_t)r0 * HD + tid];
    float x1 = xh[(size_t)r1 * HD + tid];
    float x2 = xh[(size_t)r2 * HD + tid];
    float x3 = xh[(size_t)r3 * HD + tid];
    acc += w0 * x0 + w1 * x1 + w2 * x2 + w3 * x3;
  }
  for (; i < e; ++i) {
    acc += alpha4c[(size_t)i * 4 + hh] * xh[(size_t)rowc[i] * HD + tid];
  }
  float v = acc * nis[(size_t)n * 4 + hh] + cb[tid];
  v = v * inv_std * gm[tid] + bt[tid];
  hout[(size_t)n * HD + tid] = fmaxf(v, 0.f);
}

// ---------------------------------------------------------------------------
// Global mean pool over sorted batch ids. One block per graph.
// ---------------------------------------------------------------------------
__global__ __launch_bounds__(256) void pool_kernel(
    const float* __restrict__ h, const int* __restrict__ batch,
    float* __restrict__ out, int N) {
  int g = blockIdx.x;
  int tid = threadIdx.x;
  __shared__ int s_lo, s_hi;
  if (tid == 0) {
    int lo = 0, hi = N;
    while (lo < hi) { int mid = (lo + hi) >> 1; if (batch[mid] < g) lo = mid + 1; else hi = mid; }
    s_lo = lo;
    lo = 0; hi = N;
    while (lo < hi) { int mid = (lo + hi) >> 1; if (batch[mid] < g + 1) lo = mid + 1; else hi = mid; }
    s_hi = lo;
  }
  __syncthreads();
  int lo = s_lo, hi = s_hi;
  float acc = 0.f;
  for (int n = lo; n < hi; ++n) acc += h[(size_t)n * HD + tid];
  int cnt = hi - lo;
  out[(size_t)g * HD + tid] = acc / (float)(cnt > 0 ? cnt : 1);
}

// ---------------------------------------------------------------------------
extern "C" void kernel_launch(void* const* d_in, const int* in_sizes, int n_in,
                              void* d_out, int out_size, void* d_ws, size_t ws_size,
                              hipStream_t stream) {
  const float* x = (const float*)d_in[0];
  const int* ei = (const int*)d_in[1];
  const float* edge_attr = (const float*)d_in[2];
  const int* batch = (const int*)d_in[3];
  const float* Wn = (const float*)d_in[4];
  const float* bn_b = (const float*)d_in[5];
  const float* We = (const float*)d_in[6];
  const float* be_b = (const float*)d_in[7];
  const float* lin_w = (const float*)d_in[8];
  const float* att_src = (const float*)d_in[9];
  const float* att_dst = (const float*)d_in[10];
  const float* lin_edge_w = (const float*)d_in[11];
  const float* att_edge = (const float*)d_in[12];
  const float* conv_bias = (const float*)d_in[13];
  const float* gamma = (const float*)d_in[14];
  const float* beta = (const float*)d_in[15];

  const int N = in_sizes[3];
  const int E = in_sizes[1] / 2;
  const int G = out_size / HD;
  const int* row = ei;
  const int* col = ei + E;

  char* ws = (char*)d_ws;
  size_t off = 0;
  auto alloc = [&](size_t bytes) -> char* {
    char* p = ws + off;
    off += (bytes + 255) & ~(size_t)255;
    return p;
  };
  float* h = (float*)alloc((size_t)N * HD * 4);
  float* xh = (float*)alloc((size_t)N * HD * 4);
  float* a_src = (float*)alloc((size_t)N * NHEAD * 4);
  float* a_dst = (float*)alloc((size_t)N * NHEAD * 4);
  float* alpha4c = (float*)alloc((size_t)E * NHEAD * 4);
  float* ae4c = (float*)alloc((size_t)E * NHEAD * 4);
  float* nis = (float*)alloc((size_t)N * NHEAD * 4);
  float* nselfe = (float*)alloc((size_t)N * NHEAD * 4);
  int* deg = (int*)alloc((size_t)N * 4);
  int* row_start = (int*)alloc((size_t)(N + 1) * 4);
  int* cursor = (int*)alloc((size_t)N * 4);
  int* rowc = (int*)alloc((size_t)E * 4);
  int* ipos = (int*)alloc((size_t)E * 4);
  int* tsum = (int*)alloc(4096);
  int* toff = (int*)alloc(4096);
  float* Wc = (float*)alloc(64 * 4);
  float* bc = (float*)alloc(16 * 4);

  hipMemsetAsync(deg, 0, (size_t)N * 4, stream);
  hipMemsetAsync(cursor, 0, (size_t)N * 4, stream);

  node_embed_kernel<<<N, 256, 0, stream>>>(x, Wn, bn_b, h, N);
  precompute_wc_kernel<<<1, 256, 0, stream>>>(lin_edge_w, att_edge, We, be_b, Wc, bc);
  count_deg_kernel<<<(E + 255) / 256, 256, 0, stream>>>(col, deg, E);
  int T = (N + 255) / 256;
  tile_sums_kernel<<<T, 256, 0, stream>>>(deg, tsum, N);
  scan_tsums_kernel<<<1, 64, 0, stream>>>(tsum, toff, T);
  scan_local_kernel<<<T, 256, 0, stream>>>(deg, toff, row_start, N, E);
  scatter_csr_kernel<<<(E + 255) / 256, 256, 0, stream>>>(row, col, row_start,
                                                          cursor, rowc, ipos, E);

  const float inv_std = 1.0f / sqrtf(1.0f + 1e-5f);
  for (int l = 0; l < NLAYER; ++l) {
    dim3 gg((N + 63) / 64, HD / 64);
    sgemm_kernel<<<gg, 256, 0, stream>>>(h, lin_w + (size_t)l * HD * HD, xh, N);
    attn_coef_kernel<<<N, 256, 0, stream>>>(xh, att_src + l * HD, att_dst + l * HD,
                                            a_src, a_dst, N);
    edge_logits_kernel<<<(E + 255) / 256, 256, 0, stream>>>(
        edge_attr, row, col, ipos, a_src, a_dst, Wc, bc, l, alpha4c, ae4c, E);
    softmax_stats_kernel<<<N, 64, 0, stream>>>(row_start, alpha4c, ae4c, a_src,
                                               a_dst, nis, nselfe, N);
    aggregate_kernel<<<N, 256, 0, stream>>>(
        xh, alpha4c, rowc, row_start, nis, nselfe,
        conv_bias + l * HD, gamma + l * HD, beta + l * HD, inv_std, h, N);
  }
  pool_kernel<<<G, 256, 0, stream>>>(h, batch, (float*)d_out, N);
}

// Round 4
// 992.994 us; speedup vs baseline: 1.6926x; 1.1593x over previous
//
#include <hip/hip_runtime.h>
#include <hip/hip_fp16.h>
#include <math.h>

#define HD 256
#define NHEAD 4
#define CH 64
#define NLAYER 3
#define NEG_SLOPE 0.2f

// ---------------------------------------------------------------------------
// h0 = x @ Wn + bn_b      (x: [N,9], Wn: [9,256])
// ---------------------------------------------------------------------------
__global__ __launch_bounds__(256) void node_embed_kernel(
    const float* __restrict__ x, const float* __restrict__ Wn,
    const float* __restrict__ bn_b, float* __restrict__ h, int N) {
  int n = blockIdx.x;
  int c = threadIdx.x;
  __shared__ float xs[9];
  if (c < 9) xs[c] = x[(size_t)n * 9 + c];
  __syncthreads();
  float v = bn_b[c];
#pragma unroll
  for (int k = 0; k < 9; ++k) v += xs[k] * Wn[k * HD + c];
  h[(size_t)n * HD + c] = v;
}

// ---------------------------------------------------------------------------
// Fold edge path: Wc[5][12] = We @ w_eff,  bc[12] = be_b @ w_eff
// ---------------------------------------------------------------------------
__global__ __launch_bounds__(256) void precompute_wc_kernel(
    const float* __restrict__ lin_edge_w, const float* __restrict__ att_edge,
    const float* __restrict__ We, const float* __restrict__ be_b,
    float* __restrict__ Wc, float* __restrict__ bc) {
  __shared__ float weff[256][12];
  int j = threadIdx.x;
#pragma unroll
  for (int l = 0; l < NLAYER; ++l) {
#pragma unroll
    for (int hh = 0; hh < NHEAD; ++hh) {
      float s = 0.f;
      const float* lw = lin_edge_w + (size_t)l * HD * HD + (size_t)j * HD + hh * CH;
      const float* ae = att_edge + l * HD + hh * CH;
      for (int c = 0; c < CH; ++c) s += lw[c] * ae[c];
      weff[j][l * NHEAD + hh] = s;
    }
  }
  __syncthreads();
  if (j < 60) {
    int k = j / 12, lh = j % 12;
    float s = 0.f;
    for (int t = 0; t < 256; ++t) s += We[k * HD + t] * weff[t][lh];
    Wc[k * 12 + lh] = s;
  } else if (j < 72) {
    int lh = j - 60;
    float s = 0.f;
    for (int t = 0; t < 256; ++t) s += be_b[t] * weff[t][lh];
    bc[lh] = s;
  }
}

// ---------------------------------------------------------------------------
// CSR build by destination (col)
// ---------------------------------------------------------------------------
__global__ __launch_bounds__(256) void count_deg_kernel(
    const int* __restrict__ col, int* __restrict__ deg, int E) {
  int e = blockIdx.x * 256 + threadIdx.x;
  if (e < E) atomicAdd(&deg[col[e]], 1);
}

__global__ __launch_bounds__(256) void tile_sums_kernel(
    const int* __restrict__ deg, int* __restrict__ tsum, int N) {
  __shared__ int red[256];
  int i = blockIdx.x * 256 + threadIdx.x;
  red[threadIdx.x] = (i < N) ? deg[i] : 0;
  __syncthreads();
  for (int off = 128; off > 0; off >>= 1) {
    if (threadIdx.x < off) red[threadIdx.x] += red[threadIdx.x + off];
    __syncthreads();
  }
  if (threadIdx.x == 0) tsum[blockIdx.x] = red[0];
}

__global__ __launch_bounds__(64) void scan_tsums_kernel(
    const int* __restrict__ tsum, int* __restrict__ toff, int T) {
  int lane = threadIdx.x;
  int carry = 0;
  for (int base = 0; base < T; base += 64) {
    int i = base + lane;
    int orig = (i < T) ? tsum[i] : 0;
    int v = orig;
#pragma unroll
    for (int off = 1; off < 64; off <<= 1) {
      int t = __shfl_up(v, off, 64);
      if (lane >= off) v += t;
    }
    if (i < T) toff[i] = carry + v - orig;
    carry += __shfl(v, 63, 64);
  }
}

__global__ __launch_bounds__(256) void scan_local_kernel(
    const int* __restrict__ deg, const int* __restrict__ toff,
    int* __restrict__ row_start, int N, int E) {
  __shared__ int buf[256];
  int i = blockIdx.x * 256 + threadIdx.x;
  int v = (i < N) ? deg[i] : 0;
  buf[threadIdx.x] = v;
  __syncthreads();
  for (int off = 1; off < 256; off <<= 1) {
    int t = (threadIdx.x >= off) ? buf[threadIdx.x - off] : 0;
    __syncthreads();
    buf[threadIdx.x] += t;
    __syncthreads();
  }
  if (i < N) row_start[i] = toff[blockIdx.x] + buf[threadIdx.x] - v;
  if (blockIdx.x == 0 && threadIdx.x == 0) row_start[N] = E;
}

__global__ __launch_bounds__(256) void scatter_csr_kernel(
    const int* __restrict__ row, const int* __restrict__ col,
    const int* __restrict__ row_start, int* __restrict__ cursor,
    int* __restrict__ rowc, int* __restrict__ ipos, int E) {
  int e = blockIdx.x * 256 + threadIdx.x;
  if (e < E) {
    int c = col[e];
    int p = atomicAdd(&cursor[c], 1);
    int slot = row_start[c] + p;
    rowc[slot] = row[e];
    ipos[e] = slot;
  }
}

// ---------------------------------------------------------------------------
// fp32 SGEMM fused: xh_h[M,256](fp16) = A[M,256] @ B[256,256];
// epilogue also computes a_src/a_dst (per-head dot with att vectors).
// Each 64-col tile (bn) is exactly head hh = bn/64's channel range.
// ---------------------------------------------------------------------------
__global__ __launch_bounds__(256) void sgemm_fused_kernel(
    const float* __restrict__ A, const float* __restrict__ B,
    const float* __restrict__ att_s, const float* __restrict__ att_d,
    __half* __restrict__ xh_h, float* __restrict__ a_src,
    float* __restrict__ a_dst, int M) {
  __shared__ float As[16][68];
  __shared__ float Bs[16][64];
  const int tid = threadIdx.x;
  const int bm = blockIdx.x * 64;
  const int bn = blockIdx.y * 64;
  const int hh = bn >> 6;
  const int tx = tid & 15, ty = tid >> 4;
  const int arow = tid >> 2, acol = (tid & 3) << 2;
  const int brow = tid >> 4, bcol = (tid & 15) << 2;
  const bool avalid = (bm + arow) < M;
  const float* Aptr = A + (size_t)(bm + arow) * HD + acol;
  const float* Bptr = B + (size_t)brow * HD + bn + bcol;
  float acc[4][4] = {};
  for (int k0 = 0; k0 < HD; k0 += 16) {
    float4 av = avalid ? *(const float4*)(Aptr + k0) : make_float4(0.f, 0.f, 0.f, 0.f);
    float4 bv = *(const float4*)(Bptr + (size_t)k0 * HD);
    __syncthreads();
    As[acol + 0][arow] = av.x;
    As[acol + 1][arow] = av.y;
    As[acol + 2][arow] = av.z;
    As[acol + 3][arow] = av.w;
    *(float4*)&Bs[brow][bcol] = bv;
    __syncthreads();
#pragma unroll
    for (int k = 0; k < 16; ++k) {
      float4 a = *(const float4*)&As[k][ty * 4];
      float4 b = *(const float4*)&Bs[k][tx * 4];
      acc[0][0] += a.x * b.x; acc[0][1] += a.x * b.y; acc[0][2] += a.x * b.z; acc[0][3] += a.x * b.w;
      acc[1][0] += a.y * b.x; acc[1][1] += a.y * b.y; acc[1][2] += a.y * b.z; acc[1][3] += a.y * b.w;
      acc[2][0] += a.z * b.x; acc[2][1] += a.z * b.y; acc[2][2] += a.z * b.z; acc[2][3] += a.z * b.w;
      acc[3][0] += a.w * b.x; acc[3][1] += a.w * b.y; acc[3][2] += a.w * b.z; acc[3][3] += a.w * b.w;
    }
  }
  // att vector slice for this column tile (4 channels per thread)
  float as0 = att_s[bn + tx * 4 + 0], as1 = att_s[bn + tx * 4 + 1];
  float as2 = att_s[bn + tx * 4 + 2], as3 = att_s[bn + tx * 4 + 3];
  float ad0 = att_d[bn + tx * 4 + 0], ad1 = att_d[bn + tx * 4 + 1];
  float ad2 = att_d[bn + tx * 4 + 2], ad3 = att_d[bn + tx * 4 + 3];
#pragma unroll
  for (int i = 0; i < 4; ++i) {
    int r = bm + ty * 4 + i;
    float ps = acc[i][0] * as0 + acc[i][1] * as1 + acc[i][2] * as2 + acc[i][3] * as3;
    float pd = acc[i][0] * ad0 + acc[i][1] * ad1 + acc[i][2] * ad2 + acc[i][3] * ad3;
#pragma unroll
    for (int off = 1; off < 16; off <<= 1) {
      ps += __shfl_xor(ps, off, 64);
      pd += __shfl_xor(pd, off, 64);
    }
    if (r < M) {
      __half2 p0 = __floats2half2_rn(acc[i][0], acc[i][1]);
      __half2 p1 = __floats2half2_rn(acc[i][2], acc[i][3]);
      __half2* dst = (__half2*)(xh_h + (size_t)r * HD + bn + tx * 4);
      dst[0] = p0;
      dst[1] = p1;
      if (tx == 0) {
        a_src[(size_t)r * NHEAD + hh] = ps;
        a_dst[(size_t)r * NHEAD + hh] = pd;
      }
    }
  }
}

// ---------------------------------------------------------------------------
// Per-edge logits, written directly in CSR order via ipos.
// ---------------------------------------------------------------------------
__global__ __launch_bounds__(256) void edge_logits_kernel(
    const float* __restrict__ edge_attr, const int* __restrict__ row,
    const int* __restrict__ col, const int* __restrict__ ipos,
    const float* __restrict__ a_src, const float* __restrict__ a_dst,
    const float* __restrict__ Wc, const float* __restrict__ bc, int lsel,
    float* __restrict__ alpha4c, float* __restrict__ ae4c, int E) {
  __shared__ float sWc[60];
  __shared__ float sbc[12];
  int t = threadIdx.x;
  if (t < 60) sWc[t] = Wc[t];
  if (t < 12) sbc[t] = bc[t];
  __syncthreads();
  int e = blockIdx.x * 256 + t;
  if (e >= E) return;
  int r = row[e], c = col[e], slot = ipos[e];
  float ea[5];
#pragma unroll
  for (int k = 0; k < 5; ++k) ea[k] = edge_attr[(size_t)e * 5 + k];
  float al[NHEAD], av[NHEAD];
#pragma unroll
  for (int hh = 0; hh < NHEAD; ++hh) {
    int lh = lsel * NHEAD + hh;
    float s = sbc[lh];
#pragma unroll
    for (int k = 0; k < 5; ++k) s += ea[k] * sWc[k * 12 + lh];
    av[hh] = s;
    float lg = a_src[(size_t)r * NHEAD + hh] + a_dst[(size_t)c * NHEAD + hh] + s;
    al[hh] = (lg >= 0.f) ? lg : NEG_SLOPE * lg;
  }
  *(float4*)(alpha4c + (size_t)slot * 4) = make_float4(al[0], al[1], al[2], al[3]);
  *(float4*)(ae4c + (size_t)slot * 4) = make_float4(av[0], av[1], av[2], av[3]);
}

// ---------------------------------------------------------------------------
// Per-node softmax stats: 1 wave per node. Converts alpha4c in place to
// exp(a - m); stores per-node inv-sum (nis) and unnormalized self weight.
// ---------------------------------------------------------------------------
__global__ __launch_bounds__(64) void softmax_stats_kernel(
    const int* __restrict__ row_start, float* __restrict__ alpha4c,
    const float* __restrict__ ae4c, const float* __restrict__ a_src,
    const float* __restrict__ a_dst, float* __restrict__ nis,
    float* __restrict__ nselfe, int N) {
  int n = blockIdx.x;
  int lane = threadIdx.x;
  int hh = lane & 3, j = lane >> 2;
  int s = row_start[n], e = row_start[n + 1];

  float mx = -3e38f, aes = 0.f;
  for (int i = s + j; i < e; i += 16) {
    float a = alpha4c[(size_t)i * 4 + hh];
    float v = ae4c[(size_t)i * 4 + hh];
    mx = fmaxf(mx, a);
    aes += v;
  }
#pragma unroll
  for (int off = 4; off < 64; off <<= 1) {
    mx = fmaxf(mx, __shfl_xor(mx, off, 64));
    aes += __shfl_xor(aes, off, 64);
  }
  float dinv = (e > s) ? 1.0f / (float)(e - s) : 1.0f;
  float base = a_src[(size_t)n * 4 + hh] + a_dst[(size_t)n * 4 + hh];
  float lg = base + aes * dinv;
  float sl = (lg >= 0.f) ? lg : NEG_SLOPE * lg;
  float m = fmaxf(mx, sl);

  float sm = 0.f;
  for (int i = s + j; i < e; i += 16) {
    float a = alpha4c[(size_t)i * 4 + hh];
    float ex = __expf(a - m);
    alpha4c[(size_t)i * 4 + hh] = ex;
    sm += ex;
  }
#pragma unroll
  for (int off = 4; off < 64; off <<= 1) sm += __shfl_xor(sm, off, 64);
  float self_e = __expf(sl - m);
  if (lane < 4) {
    nis[(size_t)n * 4 + hh] = 1.0f / (sm + self_e + 1e-16f);
    nselfe[(size_t)n * 4 + hh] = self_e;
  }
}

// ---------------------------------------------------------------------------
// Per-node gather-sum over fp16 xh. CSR-contiguous weights, x4 unroll.
// Epilogue: *nis, +bias, BN(eval), ReLU.
// ---------------------------------------------------------------------------
__global__ __launch_bounds__(256) void aggregate_kernel(
    const __half* __restrict__ xh_h, const float* __restrict__ alpha4c,
    const int* __restrict__ rowc, const int* __restrict__ row_start,
    const float* __restrict__ nis, const float* __restrict__ nselfe,
    const float* __restrict__ cb, const float* __restrict__ gm,
    const float* __restrict__ bt, float inv_std, float* __restrict__ hout,
    int N) {
  int n = blockIdx.x;
  int tid = threadIdx.x;
  int hh = tid >> 6;
  int s = row_start[n], e = row_start[n + 1];

  float acc = nselfe[(size_t)n * 4 + hh] * __half2float(xh_h[(size_t)n * HD + tid]);
  int i = s;
  for (; i + 4 <= e; i += 4) {
    int r0 = rowc[i], r1 = rowc[i + 1], r2 = rowc[i + 2], r3 = rowc[i + 3];
    float w0 = alpha4c[(size_t)i * 4 + hh];
    float w1 = alpha4c[(size_t)(i + 1) * 4 + hh];
    float w2 = alpha4c[(size_t)(i + 2) * 4 + hh];
    float w3 = alpha4c[(size_t)(i + 3) * 4 + hh];
    float x0 = __half2float(xh_h[(size_t)r0 * HD + tid]);
    float x1 = __half2float(xh_h[(size_t)r1 * HD + tid]);
    float x2 = __half2float(xh_h[(size_t)r2 * HD + tid]);
    float x3 = __half2float(xh_h[(size_t)r3 * HD + tid]);
    acc += w0 * x0 + w1 * x1 + w2 * x2 + w3 * x3;
  }
  for (; i < e; ++i) {
    acc += alpha4c[(size_t)i * 4 + hh] * __half2float(xh_h[(size_t)rowc[i] * HD + tid]);
  }
  float v = acc * nis[(size_t)n * 4 + hh] + cb[tid];
  v = v * inv_std * gm[tid] + bt[tid];
  hout[(size_t)n * HD + tid] = fmaxf(v, 0.f);
}

// ---------------------------------------------------------------------------
// Global mean pool over sorted batch ids. One block per graph.
// ---------------------------------------------------------------------------
__global__ __launch_bounds__(256) void pool_kernel(
    const float* __restrict__ h, const int* __restrict__ batch,
    float* __restrict__ out, int N) {
  int g = blockIdx.x;
  int tid = threadIdx.x;
  __shared__ int s_lo, s_hi;
  if (tid == 0) {
    int lo = 0, hi = N;
    while (lo < hi) { int mid = (lo + hi) >> 1; if (batch[mid] < g) lo = mid + 1; else hi = mid; }
    s_lo = lo;
    lo = 0; hi = N;
    while (lo < hi) { int mid = (lo + hi) >> 1; if (batch[mid] < g + 1) lo = mid + 1; else hi = mid; }
    s_hi = lo;
  }
  __syncthreads();
  int lo = s_lo, hi = s_hi;
  float acc = 0.f;
  for (int n = lo; n < hi; ++n) acc += h[(size_t)n * HD + tid];
  int cnt = hi - lo;
  out[(size_t)g * HD + tid] = acc / (float)(cnt > 0 ? cnt : 1);
}

// ---------------------------------------------------------------------------
extern "C" void kernel_launch(void* const* d_in, const int* in_sizes, int n_in,
                              void* d_out, int out_size, void* d_ws, size_t ws_size,
                              hipStream_t stream) {
  const float* x = (const float*)d_in[0];
  const int* ei = (const int*)d_in[1];
  const float* edge_attr = (const float*)d_in[2];
  const int* batch = (const int*)d_in[3];
  const float* Wn = (const float*)d_in[4];
  const float* bn_b = (const float*)d_in[5];
  const float* We = (const float*)d_in[6];
  const float* be_b = (const float*)d_in[7];
  const float* lin_w = (const float*)d_in[8];
  const float* att_src = (const float*)d_in[9];
  const float* att_dst = (const float*)d_in[10];
  const float* lin_edge_w = (const float*)d_in[11];
  const float* att_edge = (const float*)d_in[12];
  const float* conv_bias = (const float*)d_in[13];
  const float* gamma = (const float*)d_in[14];
  const float* beta = (const float*)d_in[15];

  const int N = in_sizes[3];
  const int E = in_sizes[1] / 2;
  const int G = out_size / HD;
  const int* row = ei;
  const int* col = ei + E;

  char* ws = (char*)d_ws;
  size_t off = 0;
  auto alloc = [&](size_t bytes) -> char* {
    char* p = ws + off;
    off += (bytes + 255) & ~(size_t)255;
    return p;
  };
  float* h = (float*)alloc((size_t)N * HD * 4);
  __half* xh_h = (__half*)alloc((size_t)N * HD * 2);
  float* a_src = (float*)alloc((size_t)N * NHEAD * 4);
  float* a_dst = (float*)alloc((size_t)N * NHEAD * 4);
  float* alpha4c = (float*)alloc((size_t)E * NHEAD * 4);
  float* ae4c = (float*)alloc((size_t)E * NHEAD * 4);
  float* nis = (float*)alloc((size_t)N * NHEAD * 4);
  float* nselfe = (float*)alloc((size_t)N * NHEAD * 4);
  int* deg = (int*)alloc((size_t)N * 4);
  int* row_start = (int*)alloc((size_t)(N + 1) * 4);
  int* cursor = (int*)alloc((size_t)N * 4);
  int* rowc = (int*)alloc((size_t)E * 4);
  int* ipos = (int*)alloc((size_t)E * 4);
  int* tsum = (int*)alloc(4096);
  int* toff = (int*)alloc(4096);
  float* Wc = (float*)alloc(64 * 4);
  float* bc = (float*)alloc(16 * 4);

  hipMemsetAsync(deg, 0, (size_t)N * 4, stream);
  hipMemsetAsync(cursor, 0, (size_t)N * 4, stream);

  node_embed_kernel<<<N, 256, 0, stream>>>(x, Wn, bn_b, h, N);
  precompute_wc_kernel<<<1, 256, 0, stream>>>(lin_edge_w, att_edge, We, be_b, Wc, bc);
  count_deg_kernel<<<(E + 255) / 256, 256, 0, stream>>>(col, deg, E);
  int T = (N + 255) / 256;
  tile_sums_kernel<<<T, 256, 0, stream>>>(deg, tsum, N);
  scan_tsums_kernel<<<1, 64, 0, stream>>>(tsum, toff, T);
  scan_local_kernel<<<T, 256, 0, stream>>>(deg, toff, row_start, N, E);
  scatter_csr_kernel<<<(E + 255) / 256, 256, 0, stream>>>(row, col, row_start,
                                                          cursor, rowc, ipos, E);

  const float inv_std = 1.0f / sqrtf(1.0f + 1e-5f);
  for (int l = 0; l < NLAYER; ++l) {
    dim3 gg((N + 63) / 64, HD / 64);
    sgemm_fused_kernel<<<gg, 256, 0, stream>>>(
        h, lin_w + (size_t)l * HD * HD, att_src + l * HD, att_dst + l * HD,
        xh_h, a_src, a_dst, N);
    edge_logits_kernel<<<(E + 255) / 256, 256, 0, stream>>>(
        edge_attr, row, col, ipos, a_src, a_dst, Wc, bc, l, alpha4c, ae4c, E);
    softmax_stats_kernel<<<N, 64, 0, stream>>>(row_start, alpha4c, ae4c, a_src,
                                               a_dst, nis, nselfe, N);
    aggregate_kernel<<<N, 256, 0, stream>>>(
        xh_h, alpha4c, rowc, row_start, nis, nselfe,
        conv_bias + l * HD, gamma + l * HD, beta + l * HD, inv_std, h, N);
  }
  pool_kernel<<<G, 256, 0, stream>>>(h, batch, (float*)d_out, N);
}

// Round 5
// 907.550 us; speedup vs baseline: 1.8520x; 1.0941x over previous
//
#include <hip/hip_runtime.h>
#include <hip/hip_fp16.h>
#include <math.h>

#define HD 256
#define NHEAD 4
#define CH 64
#define NLAYER 3
#define NEG_SLOPE 0.2f

typedef __attribute__((ext_vector_type(8))) _Float16 half8;
typedef __attribute__((ext_vector_type(4))) float float4v;

// ---------------------------------------------------------------------------
// h0 = x @ Wn + bn_b      (x: [N,9], Wn: [9,256])
// ---------------------------------------------------------------------------
__global__ __launch_bounds__(256) void node_embed_kernel(
    const float* __restrict__ x, const float* __restrict__ Wn,
    const float* __restrict__ bn_b, float* __restrict__ h, int N) {
  int n = blockIdx.x;
  int c = threadIdx.x;
  __shared__ float xs[9];
  if (c < 9) xs[c] = x[(size_t)n * 9 + c];
  __syncthreads();
  float v = bn_b[c];
#pragma unroll
  for (int k = 0; k < 9; ++k) v += xs[k] * Wn[k * HD + c];
  h[(size_t)n * HD + c] = v;
}

// ---------------------------------------------------------------------------
// Fold edge path: Wc[5][12] = We @ w_eff,  bc[12] = be_b @ w_eff
// ---------------------------------------------------------------------------
__global__ __launch_bounds__(256) void precompute_wc_kernel(
    const float* __restrict__ lin_edge_w, const float* __restrict__ att_edge,
    const float* __restrict__ We, const float* __restrict__ be_b,
    float* __restrict__ Wc, float* __restrict__ bc) {
  __shared__ float weff[256][12];
  int j = threadIdx.x;
#pragma unroll
  for (int l = 0; l < NLAYER; ++l) {
#pragma unroll
    for (int hh = 0; hh < NHEAD; ++hh) {
      float s = 0.f;
      const float* lw = lin_edge_w + (size_t)l * HD * HD + (size_t)j * HD + hh * CH;
      const float* ae = att_edge + l * HD + hh * CH;
      for (int c = 0; c < CH; ++c) s += lw[c] * ae[c];
      weff[j][l * NHEAD + hh] = s;
    }
  }
  __syncthreads();
  if (j < 60) {
    int k = j / 12, lh = j % 12;
    float s = 0.f;
    for (int t = 0; t < 256; ++t) s += We[k * HD + t] * weff[t][lh];
    Wc[k * 12 + lh] = s;
  } else if (j < 72) {
    int lh = j - 60;
    float s = 0.f;
    for (int t = 0; t < 256; ++t) s += be_b[t] * weff[t][lh];
    bc[lh] = s;
  }
}

// ---------------------------------------------------------------------------
// Repack lin_w into MFMA B-fragment order, split fp16 hi/lo.
// Fragment for (l, kt, nt): lane, j -> B[kt*32 + (lane>>4)*8 + j][nt*16 + (lane&15)]
// Stored at Bf[(((l*8+kt)*16+nt)*64 + lane)*8 + j]
// ---------------------------------------------------------------------------
__global__ __launch_bounds__(64) void conv_bfrag_kernel(
    const float* __restrict__ lin_w, _Float16* __restrict__ Bf_hi,
    _Float16* __restrict__ Bf_lo) {
  int bid = blockIdx.x;            // l*128 + kt*16 + nt
  int l = bid >> 7;
  int kt = (bid >> 4) & 7, nt = bid & 15;
  int lane = threadIdx.x;
  const float* B = lin_w + (size_t)l * HD * HD;
  size_t base = ((size_t)bid * 64 + lane) * 8;
  int k0 = kt * 32 + (lane >> 4) * 8;
  int n = nt * 16 + (lane & 15);
#pragma unroll
  for (int j = 0; j < 8; ++j) {
    float v = B[(size_t)(k0 + j) * HD + n];
    _Float16 hi = (_Float16)v;
    _Float16 lo = (_Float16)(v - (float)hi);
    Bf_hi[base + j] = hi;
    Bf_lo[base + j] = lo;
  }
}

// ---------------------------------------------------------------------------
// CSR build by destination (col)
// ---------------------------------------------------------------------------
__global__ __launch_bounds__(256) void count_deg_kernel(
    const int* __restrict__ col, int* __restrict__ deg, int E) {
  int e = blockIdx.x * 256 + threadIdx.x;
  if (e < E) atomicAdd(&deg[col[e]], 1);
}

__global__ __launch_bounds__(256) void tile_sums_kernel(
    const int* __restrict__ deg, int* __restrict__ tsum, int N) {
  __shared__ int red[256];
  int i = blockIdx.x * 256 + threadIdx.x;
  red[threadIdx.x] = (i < N) ? deg[i] : 0;
  __syncthreads();
  for (int off = 128; off > 0; off >>= 1) {
    if (threadIdx.x < off) red[threadIdx.x] += red[threadIdx.x + off];
    __syncthreads();
  }
  if (threadIdx.x == 0) tsum[blockIdx.x] = red[0];
}

__global__ __launch_bounds__(64) void scan_tsums_kernel(
    const int* __restrict__ tsum, int* __restrict__ toff, int T) {
  int lane = threadIdx.x;
  int carry = 0;
  for (int base = 0; base < T; base += 64) {
    int i = base + lane;
    int orig = (i < T) ? tsum[i] : 0;
    int v = orig;
#pragma unroll
    for (int off = 1; off < 64; off <<= 1) {
      int t = __shfl_up(v, off, 64);
      if (lane >= off) v += t;
    }
    if (i < T) toff[i] = carry + v - orig;
    carry += __shfl(v, 63, 64);
  }
}

__global__ __launch_bounds__(256) void scan_local_kernel(
    const int* __restrict__ deg, const int* __restrict__ toff,
    int* __restrict__ row_start, int N, int E) {
  __shared__ int buf[256];
  int i = blockIdx.x * 256 + threadIdx.x;
  int v = (i < N) ? deg[i] : 0;
  buf[threadIdx.x] = v;
  __syncthreads();
  for (int off = 1; off < 256; off <<= 1) {
    int t = (threadIdx.x >= off) ? buf[threadIdx.x - off] : 0;
    __syncthreads();
    buf[threadIdx.x] += t;
    __syncthreads();
  }
  if (i < N) row_start[i] = toff[blockIdx.x] + buf[threadIdx.x] - v;
  if (blockIdx.x == 0 && threadIdx.x == 0) row_start[N] = E;
}

__global__ __launch_bounds__(256) void scatter_csr_kernel(
    const int* __restrict__ row, const int* __restrict__ col,
    const int* __restrict__ row_start, int* __restrict__ cursor,
    int* __restrict__ rowc, int* __restrict__ ipos, int E) {
  int e = blockIdx.x * 256 + threadIdx.x;
  if (e < E) {
    int c = col[e];
    int p = atomicAdd(&cursor[c], 1);
    int slot = row_start[c] + p;
    rowc[slot] = row[e];
    ipos[e] = slot;
  }
}

// ---------------------------------------------------------------------------
// MFMA split-fp16 GEMM, fused epilogue (fp16 xh store + a_src/a_dst).
// Block = 64 rows, 4 waves (wave = 16 rows). Full 256-col output per block.
// A·B ~= Ahi·Bhi + Alo·Bhi + Ahi·Blo (error ~2^-22 relative).
// ---------------------------------------------------------------------------
__global__ __launch_bounds__(256) void mfma_gemm_fused_kernel(
    const float* __restrict__ A, const _Float16* __restrict__ Bf_hi,
    const _Float16* __restrict__ Bf_lo, const float* __restrict__ att_s,
    const float* __restrict__ att_d, __half* __restrict__ xh_h,
    float* __restrict__ a_src, float* __restrict__ a_dst, int N) {
  const int tid = threadIdx.x;
  const int wave = tid >> 6, lane = tid & 63;
  const int m = lane & 15, quad = lane >> 4;
  const int rowbase = blockIdx.x * 64 + wave * 16;
  const int arow = rowbase + m;
  const int arowc = (arow < N) ? arow : (N - 1);

  float4v acc[16];
#pragma unroll
  for (int nt = 0; nt < 16; ++nt) acc[nt] = (float4v){0.f, 0.f, 0.f, 0.f};

  for (int kt = 0; kt < 8; ++kt) {
    const float* ap = A + (size_t)arowc * HD + kt * 32 + quad * 8;
    float4 av0 = *(const float4*)(ap);
    float4 av1 = *(const float4*)(ap + 4);
    float af[8] = {av0.x, av0.y, av0.z, av0.w, av1.x, av1.y, av1.z, av1.w};
    half8 ahi, alo;
#pragma unroll
    for (int j = 0; j < 8; ++j) {
      _Float16 hi = (_Float16)af[j];
      ahi[j] = hi;
      alo[j] = (_Float16)(af[j] - (float)hi);
    }
    const _Float16* bh = Bf_hi + (((size_t)kt * 16) * 64 + lane) * 8;
    const _Float16* bl = Bf_lo + (((size_t)kt * 16) * 64 + lane) * 8;
#pragma unroll
    for (int nt = 0; nt < 16; ++nt) {
      half8 bhi = *(const half8*)(bh + (size_t)nt * 64 * 8);
      half8 blo = *(const half8*)(bl + (size_t)nt * 64 * 8);
      acc[nt] = __builtin_amdgcn_mfma_f32_16x16x32_f16(ahi, bhi, acc[nt], 0, 0, 0);
      acc[nt] = __builtin_amdgcn_mfma_f32_16x16x32_f16(alo, bhi, acc[nt], 0, 0, 0);
      acc[nt] = __builtin_amdgcn_mfma_f32_16x16x32_f16(ahi, blo, acc[nt], 0, 0, 0);
    }
  }

  // epilogue: C/D layout row = rowbase + quad*4 + reg, col = nt*16 + m
  float ats[16], atd[16];
#pragma unroll
  for (int nt = 0; nt < 16; ++nt) {
    ats[nt] = att_s[nt * 16 + m];
    atd[nt] = att_d[nt * 16 + m];
  }
#pragma unroll
  for (int r = 0; r < 4; ++r) {
    int orow = rowbase + quad * 4 + r;
    bool valid = orow < N;
    if (valid) {
#pragma unroll
      for (int nt = 0; nt < 16; ++nt)
        xh_h[(size_t)orow * HD + nt * 16 + m] = __float2half(acc[nt][r]);
    }
#pragma unroll
    for (int hh = 0; hh < NHEAD; ++hh) {
      float ps = 0.f, pd = 0.f;
#pragma unroll
      for (int q = 0; q < 4; ++q) {
        int nt = hh * 4 + q;
        ps += acc[nt][r] * ats[nt];
        pd += acc[nt][r] * atd[nt];
      }
#pragma unroll
      for (int off = 1; off < 16; off <<= 1) {
        ps += __shfl_xor(ps, off, 64);
        pd += __shfl_xor(pd, off, 64);
      }
      if (valid && m == 0) {
        a_src[(size_t)orow * NHEAD + hh] = ps;
        a_dst[(size_t)orow * NHEAD + hh] = pd;
      }
    }
  }
}

// ---------------------------------------------------------------------------
// Per-edge logits, written directly in CSR order via ipos.
// ---------------------------------------------------------------------------
__global__ __launch_bounds__(256) void edge_logits_kernel(
    const float* __restrict__ edge_attr, const int* __restrict__ row,
    const int* __restrict__ col, const int* __restrict__ ipos,
    const float* __restrict__ a_src, const float* __restrict__ a_dst,
    const float* __restrict__ Wc, const float* __restrict__ bc, int lsel,
    float* __restrict__ alpha4c, float* __restrict__ ae4c, int E) {
  __shared__ float sWc[60];
  __shared__ float sbc[12];
  int t = threadIdx.x;
  if (t < 60) sWc[t] = Wc[t];
  if (t < 12) sbc[t] = bc[t];
  __syncthreads();
  int e = blockIdx.x * 256 + t;
  if (e >= E) return;
  int r = row[e], c = col[e], slot = ipos[e];
  float ea[5];
#pragma unroll
  for (int k = 0; k < 5; ++k) ea[k] = edge_attr[(size_t)e * 5 + k];
  float al[NHEAD], av[NHEAD];
#pragma unroll
  for (int hh = 0; hh < NHEAD; ++hh) {
    int lh = lsel * NHEAD + hh;
    float s = sbc[lh];
#pragma unroll
    for (int k = 0; k < 5; ++k) s += ea[k] * sWc[k * 12 + lh];
    av[hh] = s;
    float lg = a_src[(size_t)r * NHEAD + hh] + a_dst[(size_t)c * NHEAD + hh] + s;
    al[hh] = (lg >= 0.f) ? lg : NEG_SLOPE * lg;
  }
  *(float4*)(alpha4c + (size_t)slot * 4) = make_float4(al[0], al[1], al[2], al[3]);
  *(float4*)(ae4c + (size_t)slot * 4) = make_float4(av[0], av[1], av[2], av[3]);
}

// ---------------------------------------------------------------------------
// Per-node softmax stats: 1 wave per node; alpha4c -> exp(a-m) in place.
// ---------------------------------------------------------------------------
__global__ __launch_bounds__(64) void softmax_stats_kernel(
    const int* __restrict__ row_start, float* __restrict__ alpha4c,
    const float* __restrict__ ae4c, const float* __restrict__ a_src,
    const float* __restrict__ a_dst, float* __restrict__ nis,
    float* __restrict__ nselfe, int N) {
  int n = blockIdx.x;
  int lane = threadIdx.x;
  int hh = lane & 3, j = lane >> 2;
  int s = row_start[n], e = row_start[n + 1];

  float mx = -3e38f, aes = 0.f;
  for (int i = s + j; i < e; i += 16) {
    float a = alpha4c[(size_t)i * 4 + hh];
    float v = ae4c[(size_t)i * 4 + hh];
    mx = fmaxf(mx, a);
    aes += v;
  }
#pragma unroll
  for (int off = 4; off < 64; off <<= 1) {
    mx = fmaxf(mx, __shfl_xor(mx, off, 64));
    aes += __shfl_xor(aes, off, 64);
  }
  float dinv = (e > s) ? 1.0f / (float)(e - s) : 1.0f;
  float base = a_src[(size_t)n * 4 + hh] + a_dst[(size_t)n * 4 + hh];
  float lg = base + aes * dinv;
  float sl = (lg >= 0.f) ? lg : NEG_SLOPE * lg;
  float m = fmaxf(mx, sl);

  float sm = 0.f;
  for (int i = s + j; i < e; i += 16) {
    float a = alpha4c[(size_t)i * 4 + hh];
    float ex = __expf(a - m);
    alpha4c[(size_t)i * 4 + hh] = ex;
    sm += ex;
  }
#pragma unroll
  for (int off = 4; off < 64; off <<= 1) sm += __shfl_xor(sm, off, 64);
  float self_e = __expf(sl - m);
  if (lane < 4) {
    nis[(size_t)n * 4 + hh] = 1.0f / (sm + self_e + 1e-16f);
    nselfe[(size_t)n * 4 + hh] = self_e;
  }
}

// ---------------------------------------------------------------------------
// Per-node gather-sum over fp16 xh. CSR-contiguous weights, x4 unroll.
// ---------------------------------------------------------------------------
__global__ __launch_bounds__(256) void aggregate_kernel(
    const __half* __restrict__ xh_h, const float* __restrict__ alpha4c,
    const int* __restrict__ rowc, const int* __restrict__ row_start,
    const float* __restrict__ nis, const float* __restrict__ nselfe,
    const float* __restrict__ cb, const float* __restrict__ gm,
    const float* __restrict__ bt, float inv_std, float* __restrict__ hout,
    int N) {
  int n = blockIdx.x;
  int tid = threadIdx.x;
  int hh = tid >> 6;
  int s = row_start[n], e = row_start[n + 1];

  float acc = nselfe[(size_t)n * 4 + hh] * __half2float(xh_h[(size_t)n * HD + tid]);
  int i = s;
  for (; i + 4 <= e; i += 4) {
    int r0 = rowc[i], r1 = rowc[i + 1], r2 = rowc[i + 2], r3 = rowc[i + 3];
    float w0 = alpha4c[(size_t)i * 4 + hh];
    float w1 = alpha4c[(size_t)(i + 1) * 4 + hh];
    float w2 = alpha4c[(size_t)(i + 2) * 4 + hh];
    float w3 = alpha4c[(size_t)(i + 3) * 4 + hh];
    float x0 = __half2float(xh_h[(size_t)r0 * HD + tid]);
    float x1 = __half2float(xh_h[(size_t)r1 * HD + tid]);
    float x2 = __half2float(xh_h[(size_t)r2 * HD + tid]);
    float x3 = __half2float(xh_h[(size_t)r3 * HD + tid]);
    acc += w0 * x0 + w1 * x1 + w2 * x2 + w3 * x3;
  }
  for (; i < e; ++i) {
    acc += alpha4c[(size_t)i * 4 + hh] * __half2float(xh_h[(size_t)rowc[i] * HD + tid]);
  }
  float v = acc * nis[(size_t)n * 4 + hh] + cb[tid];
  v = v * inv_std * gm[tid] + bt[tid];
  hout[(size_t)n * HD + tid] = fmaxf(v, 0.f);
}

// ---------------------------------------------------------------------------
// Global mean pool over sorted batch ids. One block per graph.
// ---------------------------------------------------------------------------
__global__ __launch_bounds__(256) void pool_kernel(
    const float* __restrict__ h, const int* __restrict__ batch,
    float* __restrict__ out, int N) {
  int g = blockIdx.x;
  int tid = threadIdx.x;
  __shared__ int s_lo, s_hi;
  if (tid == 0) {
    int lo = 0, hi = N;
    while (lo < hi) { int mid = (lo + hi) >> 1; if (batch[mid] < g) lo = mid + 1; else hi = mid; }
    s_lo = lo;
    lo = 0; hi = N;
    while (lo < hi) { int mid = (lo + hi) >> 1; if (batch[mid] < g + 1) lo = mid + 1; else hi = mid; }
    s_hi = lo;
  }
  __syncthreads();
  int lo = s_lo, hi = s_hi;
  float acc = 0.f;
  for (int n = lo; n < hi; ++n) acc += h[(size_t)n * HD + tid];
  int cnt = hi - lo;
  out[(size_t)g * HD + tid] = acc / (float)(cnt > 0 ? cnt : 1);
}

// ---------------------------------------------------------------------------
extern "C" void kernel_launch(void* const* d_in, const int* in_sizes, int n_in,
                              void* d_out, int out_size, void* d_ws, size_t ws_size,
                              hipStream_t stream) {
  const float* x = (const float*)d_in[0];
  const int* ei = (const int*)d_in[1];
  const float* edge_attr = (const float*)d_in[2];
  const int* batch = (const int*)d_in[3];
  const float* Wn = (const float*)d_in[4];
  const float* bn_b = (const float*)d_in[5];
  const float* We = (const float*)d_in[6];
  const float* be_b = (const float*)d_in[7];
  const float* lin_w = (const float*)d_in[8];
  const float* att_src = (const float*)d_in[9];
  const float* att_dst = (const float*)d_in[10];
  const float* lin_edge_w = (const float*)d_in[11];
  const float* att_edge = (const float*)d_in[12];
  const float* conv_bias = (const float*)d_in[13];
  const float* gamma = (const float*)d_in[14];
  const float* beta = (const float*)d_in[15];

  const int N = in_sizes[3];
  const int E = in_sizes[1] / 2;
  const int G = out_size / HD;
  const int* row = ei;
  const int* col = ei + E;

  char* ws = (char*)d_ws;
  size_t off = 0;
  auto alloc = [&](size_t bytes) -> char* {
    char* p = ws + off;
    off += (bytes + 255) & ~(size_t)255;
    return p;
  };
  float* h = (float*)alloc((size_t)N * HD * 4);
  __half* xh_h = (__half*)alloc((size_t)N * HD * 2);
  float* a_src = (float*)alloc((size_t)N * NHEAD * 4);
  float* a_dst = (float*)alloc((size_t)N * NHEAD * 4);
  float* alpha4c = (float*)alloc((size_t)E * NHEAD * 4);
  float* ae4c = (float*)alloc((size_t)E * NHEAD * 4);
  float* nis = (float*)alloc((size_t)N * NHEAD * 4);
  float* nselfe = (float*)alloc((size_t)N * NHEAD * 4);
  int* deg = (int*)alloc((size_t)N * 4);
  int* row_start = (int*)alloc((size_t)(N + 1) * 4);
  int* cursor = (int*)alloc((size_t)N * 4);
  int* rowc = (int*)alloc((size_t)E * 4);
  int* ipos = (int*)alloc((size_t)E * 4);
  int* tsum = (int*)alloc(4096);
  int* toff = (int*)alloc(4096);
  float* Wc = (float*)alloc(64 * 4);
  float* bc = (float*)alloc(16 * 4);
  _Float16* Bf_hi = (_Float16*)alloc((size_t)NLAYER * HD * HD * 2);
  _Float16* Bf_lo = (_Float16*)alloc((size_t)NLAYER * HD * HD * 2);

  hipMemsetAsync(deg, 0, (size_t)N * 4, stream);
  hipMemsetAsync(cursor, 0, (size_t)N * 4, stream);

  node_embed_kernel<<<N, 256, 0, stream>>>(x, Wn, bn_b, h, N);
  precompute_wc_kernel<<<1, 256, 0, stream>>>(lin_edge_w, att_edge, We, be_b, Wc, bc);
  conv_bfrag_kernel<<<NLAYER * 128, 64, 0, stream>>>(lin_w, Bf_hi, Bf_lo);
  count_deg_kernel<<<(E + 255) / 256, 256, 0, stream>>>(col, deg, E);
  int T = (N + 255) / 256;
  tile_sums_kernel<<<T, 256, 0, stream>>>(deg, tsum, N);
  scan_tsums_kernel<<<1, 64, 0, stream>>>(tsum, toff, T);
  scan_local_kernel<<<T, 256, 0, stream>>>(deg, toff, row_start, N, E);
  scatter_csr_kernel<<<(E + 255) / 256, 256, 0, stream>>>(row, col, row_start,
                                                          cursor, rowc, ipos, E);

  const float inv_std = 1.0f / sqrtf(1.0f + 1e-5f);
  for (int l = 0; l < NLAYER; ++l) {
    mfma_gemm_fused_kernel<<<(N + 63) / 64, 256, 0, stream>>>(
        h, Bf_hi + (size_t)l * HD * HD, Bf_lo + (size_t)l * HD * HD,
        att_src + l * HD, att_dst + l * HD, xh_h, a_src, a_dst, N);
    edge_logits_kernel<<<(E + 255) / 256, 256, 0, stream>>>(
        edge_attr, row, col, ipos, a_src, a_dst, Wc, bc, l, alpha4c, ae4c, E);
    softmax_stats_kernel<<<N, 64, 0, stream>>>(row_start, alpha4c, ae4c, a_src,
                                               a_dst, nis, nselfe, N);
    aggregate_kernel<<<N, 256, 0, stream>>>(
        xh_h, alpha4c, rowc, row_start, nis, nselfe,
        conv_bias + l * HD, gamma + l * HD, beta + l * HD, inv_std, h, N);
  }
  pool_kernel<<<G, 256, 0, stream>>>(h, batch, (float*)d_out, N);
}

// Round 6
// 829.348 us; speedup vs baseline: 2.0266x; 1.0943x over previous
//
#include <hip/hip_runtime.h>
#include <hip/hip_fp16.h>
#include <math.h>

#define HD 256
#define NHEAD 4
#define CH 64
#define NLAYER 3
#define NEG_SLOPE 0.2f

typedef __attribute__((ext_vector_type(8))) _Float16 half8;
typedef __attribute__((ext_vector_type(4))) float float4v;

// ---------------------------------------------------------------------------
// h0 = x @ Wn + bn_b      (x: [N,9], Wn: [9,256])
// ---------------------------------------------------------------------------
__global__ __launch_bounds__(256) void node_embed_kernel(
    const float* __restrict__ x, const float* __restrict__ Wn,
    const float* __restrict__ bn_b, float* __restrict__ h, int N) {
  int n = blockIdx.x;
  int c = threadIdx.x;
  __shared__ float xs[9];
  if (c < 9) xs[c] = x[(size_t)n * 9 + c];
  __syncthreads();
  float v = bn_b[c];
#pragma unroll
  for (int k = 0; k < 9; ++k) v += xs[k] * Wn[k * HD + c];
  h[(size_t)n * HD + c] = v;
}

// ---------------------------------------------------------------------------
// Fold edge path: Wc[5][12] = We @ w_eff,  bc[12] = be_b @ w_eff
// ---------------------------------------------------------------------------
__global__ __launch_bounds__(256) void precompute_wc_kernel(
    const float* __restrict__ lin_edge_w, const float* __restrict__ att_edge,
    const float* __restrict__ We, const float* __restrict__ be_b,
    float* __restrict__ Wc, float* __restrict__ bc) {
  __shared__ float weff[256][12];
  int j = threadIdx.x;
#pragma unroll
  for (int l = 0; l < NLAYER; ++l) {
#pragma unroll
    for (int hh = 0; hh < NHEAD; ++hh) {
      float s = 0.f;
      const float* lw = lin_edge_w + (size_t)l * HD * HD + (size_t)j * HD + hh * CH;
      const float* ae = att_edge + l * HD + hh * CH;
      for (int c = 0; c < CH; ++c) s += lw[c] * ae[c];
      weff[j][l * NHEAD + hh] = s;
    }
  }
  __syncthreads();
  if (j < 60) {
    int k = j / 12, lh = j % 12;
    float s = 0.f;
    for (int t = 0; t < 256; ++t) s += We[k * HD + t] * weff[t][lh];
    Wc[k * 12 + lh] = s;
  } else if (j < 72) {
    int lh = j - 60;
    float s = 0.f;
    for (int t = 0; t < 256; ++t) s += be_b[t] * weff[t][lh];
    bc[lh] = s;
  }
}

// ---------------------------------------------------------------------------
// Repack lin_w into MFMA B-fragment order, split fp16 hi/lo.
// ---------------------------------------------------------------------------
__global__ __launch_bounds__(64) void conv_bfrag_kernel(
    const float* __restrict__ lin_w, _Float16* __restrict__ Bf_hi,
    _Float16* __restrict__ Bf_lo) {
  int bid = blockIdx.x;            // l*128 + kt*16 + nt
  int l = bid >> 7;
  int kt = (bid >> 4) & 7, nt = bid & 15;
  int lane = threadIdx.x;
  const float* B = lin_w + (size_t)l * HD * HD;
  size_t base = ((size_t)bid * 64 + lane) * 8;
  int k0 = kt * 32 + (lane >> 4) * 8;
  int n = nt * 16 + (lane & 15);
#pragma unroll
  for (int j = 0; j < 8; ++j) {
    float v = B[(size_t)(k0 + j) * HD + n];
    _Float16 hi = (_Float16)v;
    _Float16 lo = (_Float16)(v - (float)hi);
    Bf_hi[base + j] = hi;
    Bf_lo[base + j] = lo;
  }
}

// ---------------------------------------------------------------------------
// CSR build by destination (col)
// ---------------------------------------------------------------------------
__global__ __launch_bounds__(256) void count_deg_kernel(
    const int* __restrict__ col, int* __restrict__ deg, int E) {
  int e = blockIdx.x * 256 + threadIdx.x;
  if (e < E) atomicAdd(&deg[col[e]], 1);
}

__global__ __launch_bounds__(256) void tile_sums_kernel(
    const int* __restrict__ deg, int* __restrict__ tsum, int N) {
  __shared__ int red[256];
  int i = blockIdx.x * 256 + threadIdx.x;
  red[threadIdx.x] = (i < N) ? deg[i] : 0;
  __syncthreads();
  for (int off = 128; off > 0; off >>= 1) {
    if (threadIdx.x < off) red[threadIdx.x] += red[threadIdx.x + off];
    __syncthreads();
  }
  if (threadIdx.x == 0) tsum[blockIdx.x] = red[0];
}

__global__ __launch_bounds__(64) void scan_tsums_kernel(
    const int* __restrict__ tsum, int* __restrict__ toff, int T) {
  int lane = threadIdx.x;
  int carry = 0;
  for (int base = 0; base < T; base += 64) {
    int i = base + lane;
    int orig = (i < T) ? tsum[i] : 0;
    int v = orig;
#pragma unroll
    for (int off = 1; off < 64; off <<= 1) {
      int t = __shfl_up(v, off, 64);
      if (lane >= off) v += t;
    }
    if (i < T) toff[i] = carry + v - orig;
    carry += __shfl(v, 63, 64);
  }
}

__global__ __launch_bounds__(256) void scan_local_kernel(
    const int* __restrict__ deg, const int* __restrict__ toff,
    int* __restrict__ row_start, int N, int E) {
  __shared__ int buf[256];
  int i = blockIdx.x * 256 + threadIdx.x;
  int v = (i < N) ? deg[i] : 0;
  buf[threadIdx.x] = v;
  __syncthreads();
  for (int off = 1; off < 256; off <<= 1) {
    int t = (threadIdx.x >= off) ? buf[threadIdx.x - off] : 0;
    __syncthreads();
    buf[threadIdx.x] += t;
    __syncthreads();
  }
  if (i < N) row_start[i] = toff[blockIdx.x] + buf[threadIdx.x] - v;
  if (blockIdx.x == 0 && threadIdx.x == 0) row_start[N] = E;
}

__global__ __launch_bounds__(256) void scatter_csr_kernel(
    const int* __restrict__ row, const int* __restrict__ col,
    const int* __restrict__ row_start, int* __restrict__ cursor,
    int* __restrict__ rowc, int* __restrict__ ipos, int E) {
  int e = blockIdx.x * 256 + threadIdx.x;
  if (e < E) {
    int c = col[e];
    int p = atomicAdd(&cursor[c], 1);
    int slot = row_start[c] + p;
    rowc[slot] = row[e];
    ipos[e] = slot;
  }
}

// ---------------------------------------------------------------------------
// MFMA split-fp16 GEMM, fused epilogue (fp16 xh store + a_src/a_dst).
// ---------------------------------------------------------------------------
__global__ __launch_bounds__(256) void mfma_gemm_fused_kernel(
    const float* __restrict__ A, const _Float16* __restrict__ Bf_hi,
    const _Float16* __restrict__ Bf_lo, const float* __restrict__ att_s,
    const float* __restrict__ att_d, __half* __restrict__ xh_h,
    float* __restrict__ a_src, float* __restrict__ a_dst, int N) {
  const int tid = threadIdx.x;
  const int wave = tid >> 6, lane = tid & 63;
  const int m = lane & 15, quad = lane >> 4;
  const int rowbase = blockIdx.x * 64 + wave * 16;
  const int arow = rowbase + m;
  const int arowc = (arow < N) ? arow : (N - 1);

  float4v acc[16];
#pragma unroll
  for (int nt = 0; nt < 16; ++nt) acc[nt] = (float4v){0.f, 0.f, 0.f, 0.f};

  for (int kt = 0; kt < 8; ++kt) {
    const float* ap = A + (size_t)arowc * HD + kt * 32 + quad * 8;
    float4 av0 = *(const float4*)(ap);
    float4 av1 = *(const float4*)(ap + 4);
    float af[8] = {av0.x, av0.y, av0.z, av0.w, av1.x, av1.y, av1.z, av1.w};
    half8 ahi, alo;
#pragma unroll
    for (int j = 0; j < 8; ++j) {
      _Float16 hi = (_Float16)af[j];
      ahi[j] = hi;
      alo[j] = (_Float16)(af[j] - (float)hi);
    }
    const _Float16* bh = Bf_hi + (((size_t)kt * 16) * 64 + lane) * 8;
    const _Float16* bl = Bf_lo + (((size_t)kt * 16) * 64 + lane) * 8;
#pragma unroll
    for (int nt = 0; nt < 16; ++nt) {
      half8 bhi = *(const half8*)(bh + (size_t)nt * 64 * 8);
      half8 blo = *(const half8*)(bl + (size_t)nt * 64 * 8);
      acc[nt] = __builtin_amdgcn_mfma_f32_16x16x32_f16(ahi, bhi, acc[nt], 0, 0, 0);
      acc[nt] = __builtin_amdgcn_mfma_f32_16x16x32_f16(alo, bhi, acc[nt], 0, 0, 0);
      acc[nt] = __builtin_amdgcn_mfma_f32_16x16x32_f16(ahi, blo, acc[nt], 0, 0, 0);
    }
  }

  float ats[16], atd[16];
#pragma unroll
  for (int nt = 0; nt < 16; ++nt) {
    ats[nt] = att_s[nt * 16 + m];
    atd[nt] = att_d[nt * 16 + m];
  }
#pragma unroll
  for (int r = 0; r < 4; ++r) {
    int orow = rowbase + quad * 4 + r;
    bool valid = orow < N;
    if (valid) {
#pragma unroll
      for (int nt = 0; nt < 16; ++nt)
        xh_h[(size_t)orow * HD + nt * 16 + m] = __float2half(acc[nt][r]);
    }
#pragma unroll
    for (int hh = 0; hh < NHEAD; ++hh) {
      float ps = 0.f, pd = 0.f;
#pragma unroll
      for (int q = 0; q < 4; ++q) {
        int nt = hh * 4 + q;
        ps += acc[nt][r] * ats[nt];
        pd += acc[nt][r] * atd[nt];
      }
#pragma unroll
      for (int off = 1; off < 16; off <<= 1) {
        ps += __shfl_xor(ps, off, 64);
        pd += __shfl_xor(pd, off, 64);
      }
      if (valid && m == 0) {
        a_src[(size_t)orow * NHEAD + hh] = ps;
        a_dst[(size_t)orow * NHEAD + hh] = pd;
      }
    }
  }
}

// ---------------------------------------------------------------------------
// Per-edge logits, written directly in CSR order via ipos.
// ---------------------------------------------------------------------------
__global__ __launch_bounds__(256) void edge_logits_kernel(
    const float* __restrict__ edge_attr, const int* __restrict__ row,
    const int* __restrict__ col, const int* __restrict__ ipos,
    const float* __restrict__ a_src, const float* __restrict__ a_dst,
    const float* __restrict__ Wc, const float* __restrict__ bc, int lsel,
    float* __restrict__ alpha4c, float* __restrict__ ae4c, int E) {
  __shared__ float sWc[60];
  __shared__ float sbc[12];
  int t = threadIdx.x;
  if (t < 60) sWc[t] = Wc[t];
  if (t < 12) sbc[t] = bc[t];
  __syncthreads();
  int e = blockIdx.x * 256 + t;
  if (e >= E) return;
  int r = row[e], c = col[e], slot = ipos[e];
  float ea[5];
#pragma unroll
  for (int k = 0; k < 5; ++k) ea[k] = edge_attr[(size_t)e * 5 + k];
  float al[NHEAD], av[NHEAD];
#pragma unroll
  for (int hh = 0; hh < NHEAD; ++hh) {
    int lh = lsel * NHEAD + hh;
    float s = sbc[lh];
#pragma unroll
    for (int k = 0; k < 5; ++k) s += ea[k] * sWc[k * 12 + lh];
    av[hh] = s;
    float lg = a_src[(size_t)r * NHEAD + hh] + a_dst[(size_t)c * NHEAD + hh] + s;
    al[hh] = (lg >= 0.f) ? lg : NEG_SLOPE * lg;
  }
  *(float4*)(alpha4c + (size_t)slot * 4) = make_float4(al[0], al[1], al[2], al[3]);
  *(float4*)(ae4c + (size_t)slot * 4) = make_float4(av[0], av[1], av[2], av[3]);
}

// ---------------------------------------------------------------------------
// Per-node softmax stats: 1 wave per node; alpha4c -> exp(a-m) in place.
// ---------------------------------------------------------------------------
__global__ __launch_bounds__(64) void softmax_stats_kernel(
    const int* __restrict__ row_start, float* __restrict__ alpha4c,
    const float* __restrict__ ae4c, const float* __restrict__ a_src,
    const float* __restrict__ a_dst, float* __restrict__ nis,
    float* __restrict__ nselfe, int N) {
  int n = blockIdx.x;
  int lane = threadIdx.x;
  int hh = lane & 3, j = lane >> 2;
  int s = row_start[n], e = row_start[n + 1];

  float mx = -3e38f, aes = 0.f;
  for (int i = s + j; i < e; i += 16) {
    float a = alpha4c[(size_t)i * 4 + hh];
    float v = ae4c[(size_t)i * 4 + hh];
    mx = fmaxf(mx, a);
    aes += v;
  }
#pragma unroll
  for (int off = 4; off < 64; off <<= 1) {
    mx = fmaxf(mx, __shfl_xor(mx, off, 64));
    aes += __shfl_xor(aes, off, 64);
  }
  float dinv = (e > s) ? 1.0f / (float)(e - s) : 1.0f;
  float base = a_src[(size_t)n * 4 + hh] + a_dst[(size_t)n * 4 + hh];
  float lg = base + aes * dinv;
  float sl = (lg >= 0.f) ? lg : NEG_SLOPE * lg;
  float m = fmaxf(mx, sl);

  float sm = 0.f;
  for (int i = s + j; i < e; i += 16) {
    float a = alpha4c[(size_t)i * 4 + hh];
    float ex = __expf(a - m);
    alpha4c[(size_t)i * 4 + hh] = ex;
    sm += ex;
  }
#pragma unroll
  for (int off = 4; off < 64; off <<= 1) sm += __shfl_xor(sm, off, 64);
  float self_e = __expf(sl - m);
  if (lane < 4) {
    nis[(size_t)n * 4 + hh] = 1.0f / (sm + self_e + 1e-16f);
    nselfe[(size_t)n * 4 + hh] = self_e;
  }
}

// ---------------------------------------------------------------------------
// Per-node gather-sum over fp16 xh. 2 nodes/block, thread = half2 channel
// pair (4B loads), 8-edge unroll -> 32 B in flight per thread.
// ---------------------------------------------------------------------------
__global__ __launch_bounds__(256) void aggregate_kernel(
    const __half* __restrict__ xh_h, const float* __restrict__ alpha4c,
    const int* __restrict__ rowc, const int* __restrict__ row_start,
    const float* __restrict__ nis, const float* __restrict__ nselfe,
    const float* __restrict__ cb, const float* __restrict__ gm,
    const float* __restrict__ bt, float inv_std, float* __restrict__ hout,
    int N) {
  int tid = threadIdx.x;
  int n = blockIdx.x * 2 + (tid >> 7);
  if (n >= N) return;
  int t = tid & 127;      // half2 index within row
  int ch = t * 2;
  int hh = ch >> 6;
  int s = row_start[n], e = row_start[n + 1];
  const __half2* xh2 = (const __half2*)xh_h;

  float2 self = __half22float2(xh2[(size_t)n * 128 + t]);
  float se = nselfe[(size_t)n * 4 + hh];
  float ax = se * self.x, ay = se * self.y;

  int i = s;
  for (; i + 8 <= e; i += 8) {
    int r[8];
    float w[8];
    float2 xv[8];
#pragma unroll
    for (int u = 0; u < 8; ++u) {
      r[u] = rowc[i + u];
      w[u] = alpha4c[(size_t)(i + u) * 4 + hh];
    }
#pragma unroll
    for (int u = 0; u < 8; ++u) xv[u] = __half22float2(xh2[(size_t)r[u] * 128 + t]);
#pragma unroll
    for (int u = 0; u < 8; ++u) {
      ax += w[u] * xv[u].x;
      ay += w[u] * xv[u].y;
    }
  }
  for (; i + 4 <= e; i += 4) {
    int r[4];
    float w[4];
    float2 xv[4];
#pragma unroll
    for (int u = 0; u < 4; ++u) {
      r[u] = rowc[i + u];
      w[u] = alpha4c[(size_t)(i + u) * 4 + hh];
    }
#pragma unroll
    for (int u = 0; u < 4; ++u) xv[u] = __half22float2(xh2[(size_t)r[u] * 128 + t]);
#pragma unroll
    for (int u = 0; u < 4; ++u) {
      ax += w[u] * xv[u].x;
      ay += w[u] * xv[u].y;
    }
  }
  for (; i < e; ++i) {
    float w = alpha4c[(size_t)i * 4 + hh];
    float2 xv = __half22float2(xh2[(size_t)rowc[i] * 128 + t]);
    ax += w * xv.x;
    ay += w * xv.y;
  }
  float is = nis[(size_t)n * 4 + hh];
  float vx = ax * is + cb[ch];
  float vy = ay * is + cb[ch + 1];
  vx = vx * inv_std * gm[ch] + bt[ch];
  vy = vy * inv_std * gm[ch + 1] + bt[ch + 1];
  float2 outv = make_float2(fmaxf(vx, 0.f), fmaxf(vy, 0.f));
  *(float2*)&hout[(size_t)n * HD + ch] = outv;
}

// ---------------------------------------------------------------------------
// Global mean pool over sorted batch ids. One block per graph.
// ---------------------------------------------------------------------------
__global__ __launch_bounds__(256) void pool_kernel(
    const float* __restrict__ h, const int* __restrict__ batch,
    float* __restrict__ out, int N) {
  int g = blockIdx.x;
  int tid = threadIdx.x;
  __shared__ int s_lo, s_hi;
  if (tid == 0) {
    int lo = 0, hi = N;
    while (lo < hi) { int mid = (lo + hi) >> 1; if (batch[mid] < g) lo = mid + 1; else hi = mid; }
    s_lo = lo;
    lo = 0; hi = N;
    while (lo < hi) { int mid = (lo + hi) >> 1; if (batch[mid] < g + 1) lo = mid + 1; else hi = mid; }
    s_hi = lo;
  }
  __syncthreads();
  int lo = s_lo, hi = s_hi;
  float acc = 0.f;
  for (int n = lo; n < hi; ++n) acc += h[(size_t)n * HD + tid];
  int cnt = hi - lo;
  out[(size_t)g * HD + tid] = acc / (float)(cnt > 0 ? cnt : 1);
}

// ---------------------------------------------------------------------------
extern "C" void kernel_launch(void* const* d_in, const int* in_sizes, int n_in,
                              void* d_out, int out_size, void* d_ws, size_t ws_size,
                              hipStream_t stream) {
  const float* x = (const float*)d_in[0];
  const int* ei = (const int*)d_in[1];
  const float* edge_attr = (const float*)d_in[2];
  const int* batch = (const int*)d_in[3];
  const float* Wn = (const float*)d_in[4];
  const float* bn_b = (const float*)d_in[5];
  const float* We = (const float*)d_in[6];
  const float* be_b = (const float*)d_in[7];
  const float* lin_w = (const float*)d_in[8];
  const float* att_src = (const float*)d_in[9];
  const float* att_dst = (const float*)d_in[10];
  const float* lin_edge_w = (const float*)d_in[11];
  const float* att_edge = (const float*)d_in[12];
  const float* conv_bias = (const float*)d_in[13];
  const float* gamma = (const float*)d_in[14];
  const float* beta = (const float*)d_in[15];

  const int N = in_sizes[3];
  const int E = in_sizes[1] / 2;
  const int G = out_size / HD;
  const int* row = ei;
  const int* col = ei + E;

  char* ws = (char*)d_ws;
  size_t off = 0;
  auto alloc = [&](size_t bytes) -> char* {
    char* p = ws + off;
    off += (bytes + 255) & ~(size_t)255;
    return p;
  };
  float* h = (float*)alloc((size_t)N * HD * 4);
  __half* xh_h = (__half*)alloc((size_t)N * HD * 2);
  float* a_src = (float*)alloc((size_t)N * NHEAD * 4);
  float* a_dst = (float*)alloc((size_t)N * NHEAD * 4);
  float* alpha4c = (float*)alloc((size_t)E * NHEAD * 4);
  float* ae4c = (float*)alloc((size_t)E * NHEAD * 4);
  float* nis = (float*)alloc((size_t)N * NHEAD * 4);
  float* nselfe = (float*)alloc((size_t)N * NHEAD * 4);
  int* deg = (int*)alloc((size_t)N * 4);
  int* row_start = (int*)alloc((size_t)(N + 1) * 4);
  int* cursor = (int*)alloc((size_t)N * 4);
  int* rowc = (int*)alloc((size_t)E * 4);
  int* ipos = (int*)alloc((size_t)E * 4);
  int* tsum = (int*)alloc(4096);
  int* toff = (int*)alloc(4096);
  float* Wc = (float*)alloc(64 * 4);
  float* bc = (float*)alloc(16 * 4);
  _Float16* Bf_hi = (_Float16*)alloc((size_t)NLAYER * HD * HD * 2);
  _Float16* Bf_lo = (_Float16*)alloc((size_t)NLAYER * HD * HD * 2);

  hipMemsetAsync(deg, 0, (size_t)N * 4, stream);
  hipMemsetAsync(cursor, 0, (size_t)N * 4, stream);

  node_embed_kernel<<<N, 256, 0, stream>>>(x, Wn, bn_b, h, N);
  precompute_wc_kernel<<<1, 256, 0, stream>>>(lin_edge_w, att_edge, We, be_b, Wc, bc);
  conv_bfrag_kernel<<<NLAYER * 128, 64, 0, stream>>>(lin_w, Bf_hi, Bf_lo);
  count_deg_kernel<<<(E + 255) / 256, 256, 0, stream>>>(col, deg, E);
  int T = (N + 255) / 256;
  tile_sums_kernel<<<T, 256, 0, stream>>>(deg, tsum, N);
  scan_tsums_kernel<<<1, 64, 0, stream>>>(tsum, toff, T);
  scan_local_kernel<<<T, 256, 0, stream>>>(deg, toff, row_start, N, E);
  scatter_csr_kernel<<<(E + 255) / 256, 256, 0, stream>>>(row, col, row_start,
                                                          cursor, rowc, ipos, E);

  const float inv_std = 1.0f / sqrtf(1.0f + 1e-5f);
  for (int l = 0; l < NLAYER; ++l) {
    mfma_gemm_fused_kernel<<<(N + 63) / 64, 256, 0, stream>>>(
        h, Bf_hi + (size_t)l * HD * HD, Bf_lo + (size_t)l * HD * HD,
        att_src + l * HD, att_dst + l * HD, xh_h, a_src, a_dst, N);
    edge_logits_kernel<<<(E + 255) / 256, 256, 0, stream>>>(
        edge_attr, row, col, ipos, a_src, a_dst, Wc, bc, l, alpha4c, ae4c, E);
    softmax_stats_kernel<<<N, 64, 0, stream>>>(row_start, alpha4c, ae4c, a_src,
                                               a_dst, nis, nselfe, N);
    aggregate_kernel<<<(N + 1) / 2, 256, 0, stream>>>(
        xh_h, alpha4c, rowc, row_start, nis, nselfe,
        conv_bias + l * HD, gamma + l * HD, beta + l * HD, inv_std, h, N);
  }
  pool_kernel<<<G, 256, 0, stream>>>(h, batch, (float*)d_out, N);
}

// Round 7
// 777.502 us; speedup vs baseline: 2.1617x; 1.0667x over previous
//
#include <hip/hip_runtime.h>
#include <hip/hip_fp16.h>
#include <math.h>

#define HD 256
#define NHEAD 4
#define CH 64
#define NLAYER 3
#define NEG_SLOPE 0.2f

typedef __attribute__((ext_vector_type(8))) _Float16 half8;
typedef __attribute__((ext_vector_type(4))) float float4v;

// ---------------------------------------------------------------------------
// h0 = x @ Wn + bn_b      (x: [N,9], Wn: [9,256])
// ---------------------------------------------------------------------------
__global__ __launch_bounds__(256) void node_embed_kernel(
    const float* __restrict__ x, const float* __restrict__ Wn,
    const float* __restrict__ bn_b, float* __restrict__ h, int N) {
  int n = blockIdx.x;
  int c = threadIdx.x;
  __shared__ float xs[9];
  if (c < 9) xs[c] = x[(size_t)n * 9 + c];
  __syncthreads();
  float v = bn_b[c];
#pragma unroll
  for (int k = 0; k < 9; ++k) v += xs[k] * Wn[k * HD + c];
  h[(size_t)n * HD + c] = v;
}

// ---------------------------------------------------------------------------
// Fold edge path: Wc[5][12] = We @ w_eff,  bc[12] = be_b @ w_eff
// ---------------------------------------------------------------------------
__global__ __launch_bounds__(256) void precompute_wc_kernel(
    const float* __restrict__ lin_edge_w, const float* __restrict__ att_edge,
    const float* __restrict__ We, const float* __restrict__ be_b,
    float* __restrict__ Wc, float* __restrict__ bc) {
  __shared__ float weff[256][12];
  int j = threadIdx.x;
#pragma unroll
  for (int l = 0; l < NLAYER; ++l) {
#pragma unroll
    for (int hh = 0; hh < NHEAD; ++hh) {
      float s = 0.f;
      const float* lw = lin_edge_w + (size_t)l * HD * HD + (size_t)j * HD + hh * CH;
      const float* ae = att_edge + l * HD + hh * CH;
      for (int c = 0; c < CH; ++c) s += lw[c] * ae[c];
      weff[j][l * NHEAD + hh] = s;
    }
  }
  __syncthreads();
  if (j < 60) {
    int k = j / 12, lh = j % 12;
    float s = 0.f;
    for (int t = 0; t < 256; ++t) s += We[k * HD + t] * weff[t][lh];
    Wc[k * 12 + lh] = s;
  } else if (j < 72) {
    int lh = j - 60;
    float s = 0.f;
    for (int t = 0; t < 256; ++t) s += be_b[t] * weff[t][lh];
    bc[lh] = s;
  }
}

// ---------------------------------------------------------------------------
// Repack lin_w into MFMA B-fragment order, split fp16 hi/lo.
// INTERLEAVED col map: fragment (l,kt,nt), lane -> B[kt*32+(lane>>4)*8+j][(lane&15)*16+nt]
// so that in the epilogue each lane owns 16 CONSECUTIVE output cols.
// ---------------------------------------------------------------------------
__global__ __launch_bounds__(64) void conv_bfrag_kernel(
    const float* __restrict__ lin_w, _Float16* __restrict__ Bf_hi,
    _Float16* __restrict__ Bf_lo) {
  int bid = blockIdx.x;            // l*128 + kt*16 + nt
  int l = bid >> 7;
  int kt = (bid >> 4) & 7, nt = bid & 15;
  int lane = threadIdx.x;
  const float* B = lin_w + (size_t)l * HD * HD;
  size_t base = ((size_t)bid * 64 + lane) * 8;
  int k0 = kt * 32 + (lane >> 4) * 8;
  int n = (lane & 15) * 16 + nt;
#pragma unroll
  for (int j = 0; j < 8; ++j) {
    float v = B[(size_t)(k0 + j) * HD + n];
    _Float16 hi = (_Float16)v;
    _Float16 lo = (_Float16)(v - (float)hi);
    Bf_hi[base + j] = hi;
    Bf_lo[base + j] = lo;
  }
}

// ---------------------------------------------------------------------------
// CSR build by destination (col)
// ---------------------------------------------------------------------------
__global__ __launch_bounds__(256) void count_deg_kernel(
    const int* __restrict__ col, int* __restrict__ deg, int E) {
  int e = blockIdx.x * 256 + threadIdx.x;
  if (e < E) atomicAdd(&deg[col[e]], 1);
}

__global__ __launch_bounds__(256) void tile_sums_kernel(
    const int* __restrict__ deg, int* __restrict__ tsum, int N) {
  __shared__ int red[256];
  int i = blockIdx.x * 256 + threadIdx.x;
  red[threadIdx.x] = (i < N) ? deg[i] : 0;
  __syncthreads();
  for (int off = 128; off > 0; off >>= 1) {
    if (threadIdx.x < off) red[threadIdx.x] += red[threadIdx.x + off];
    __syncthreads();
  }
  if (threadIdx.x == 0) tsum[blockIdx.x] = red[0];
}

__global__ __launch_bounds__(64) void scan_tsums_kernel(
    const int* __restrict__ tsum, int* __restrict__ toff, int T) {
  int lane = threadIdx.x;
  int carry = 0;
  for (int base = 0; base < T; base += 64) {
    int i = base + lane;
    int orig = (i < T) ? tsum[i] : 0;
    int v = orig;
#pragma unroll
    for (int off = 1; off < 64; off <<= 1) {
      int t = __shfl_up(v, off, 64);
      if (lane >= off) v += t;
    }
    if (i < T) toff[i] = carry + v - orig;
    carry += __shfl(v, 63, 64);
  }
}

__global__ __launch_bounds__(256) void scan_local_kernel(
    const int* __restrict__ deg, const int* __restrict__ toff,
    int* __restrict__ row_start, int N, int E) {
  __shared__ int buf[256];
  int i = blockIdx.x * 256 + threadIdx.x;
  int v = (i < N) ? deg[i] : 0;
  buf[threadIdx.x] = v;
  __syncthreads();
  for (int off = 1; off < 256; off <<= 1) {
    int t = (threadIdx.x >= off) ? buf[threadIdx.x - off] : 0;
    __syncthreads();
    buf[threadIdx.x] += t;
    __syncthreads();
  }
  if (i < N) row_start[i] = toff[blockIdx.x] + buf[threadIdx.x] - v;
  if (blockIdx.x == 0 && threadIdx.x == 0) row_start[N] = E;
}

__global__ __launch_bounds__(256) void scatter_csr_kernel(
    const int* __restrict__ row, const int* __restrict__ col,
    const int* __restrict__ row_start, int* __restrict__ cursor,
    int* __restrict__ rowc, int* __restrict__ ipos, int E) {
  int e = blockIdx.x * 256 + threadIdx.x;
  if (e < E) {
    int c = col[e];
    int p = atomicAdd(&cursor[c], 1);
    int slot = row_start[c] + p;
    rowc[slot] = row[e];
    ipos[e] = slot;
  }
}

// ---------------------------------------------------------------------------
// Once per launch: a_e for ALL 3 layers, written in CSR order.
// ae4c_all[l][slot][4] = edge_attr[e] @ Wc[:,l*4+h] + bc[l*4+h]
// ---------------------------------------------------------------------------
__global__ __launch_bounds__(256) void edge_ae_kernel(
    const float* __restrict__ edge_attr, const int* __restrict__ ipos,
    const float* __restrict__ Wc, const float* __restrict__ bc,
    float* __restrict__ ae4c_all, int E) {
  __shared__ float sWc[60];
  __shared__ float sbc[12];
  int t = threadIdx.x;
  if (t < 60) sWc[t] = Wc[t];
  if (t < 12) sbc[t] = bc[t];
  __syncthreads();
  int e = blockIdx.x * 256 + t;
  if (e >= E) return;
  int slot = ipos[e];
  float ea[5];
#pragma unroll
  for (int k = 0; k < 5; ++k) ea[k] = edge_attr[(size_t)e * 5 + k];
#pragma unroll
  for (int l = 0; l < NLAYER; ++l) {
    float av[NHEAD];
#pragma unroll
    for (int hh = 0; hh < NHEAD; ++hh) {
      int lh = l * NHEAD + hh;
      float s = sbc[lh];
#pragma unroll
      for (int k = 0; k < 5; ++k) s += ea[k] * sWc[k * 12 + lh];
      av[hh] = s;
    }
    *(float4*)(ae4c_all + ((size_t)l * E + slot) * 4) =
        make_float4(av[0], av[1], av[2], av[3]);
  }
}

// ---------------------------------------------------------------------------
// MFMA split-fp16 GEMM, fused epilogue. Interleaved col map: lane (quad,m)
// holds cols m*16..m*16+15 (all in head m>>2) -> half8 x2 coalesced stores,
// 2-shuffle segmented head reduction for a_src/a_dst.
// ---------------------------------------------------------------------------
__global__ __launch_bounds__(256) void mfma_gemm_fused_kernel(
    const float* __restrict__ A, const _Float16* __restrict__ Bf_hi,
    const _Float16* __restrict__ Bf_lo, const float* __restrict__ att_s,
    const float* __restrict__ att_d, __half* __restrict__ xh_h,
    float* __restrict__ a_src, float* __restrict__ a_dst, int N) {
  const int tid = threadIdx.x;
  const int wave = tid >> 6, lane = tid & 63;
  const int m = lane & 15, quad = lane >> 4;
  const int rowbase = blockIdx.x * 64 + wave * 16;
  const int arow = rowbase + m;
  const int arowc = (arow < N) ? arow : (N - 1);

  float4v acc[16];
#pragma unroll
  for (int nt = 0; nt < 16; ++nt) acc[nt] = (float4v){0.f, 0.f, 0.f, 0.f};

  for (int kt = 0; kt < 8; ++kt) {
    const float* ap = A + (size_t)arowc * HD + kt * 32 + quad * 8;
    float4 av0 = *(const float4*)(ap);
    float4 av1 = *(const float4*)(ap + 4);
    float af[8] = {av0.x, av0.y, av0.z, av0.w, av1.x, av1.y, av1.z, av1.w};
    half8 ahi, alo;
#pragma unroll
    for (int j = 0; j < 8; ++j) {
      _Float16 hi = (_Float16)af[j];
      ahi[j] = hi;
      alo[j] = (_Float16)(af[j] - (float)hi);
    }
    const _Float16* bh = Bf_hi + (((size_t)kt * 16) * 64 + lane) * 8;
    const _Float16* bl = Bf_lo + (((size_t)kt * 16) * 64 + lane) * 8;
#pragma unroll
    for (int nt = 0; nt < 16; ++nt) {
      half8 bhi = *(const half8*)(bh + (size_t)nt * 64 * 8);
      half8 blo = *(const half8*)(bl + (size_t)nt * 64 * 8);
      acc[nt] = __builtin_amdgcn_mfma_f32_16x16x32_f16(ahi, bhi, acc[nt], 0, 0, 0);
      acc[nt] = __builtin_amdgcn_mfma_f32_16x16x32_f16(alo, bhi, acc[nt], 0, 0, 0);
      acc[nt] = __builtin_amdgcn_mfma_f32_16x16x32_f16(ahi, blo, acc[nt], 0, 0, 0);
    }
  }

  // lane's 16 cols are m*16 .. m*16+15, all in head hh = m>>2
  const int hh = m >> 2;
  float ats[16], atd[16];
#pragma unroll
  for (int nt = 0; nt < 16; ++nt) {
    ats[nt] = att_s[m * 16 + nt];
    atd[nt] = att_d[m * 16 + nt];
  }
  _Float16* xf = (_Float16*)xh_h;
#pragma unroll
  for (int r = 0; r < 4; ++r) {
    int orow = rowbase + quad * 4 + r;
    bool valid = orow < N;
    float ps = 0.f, pd = 0.f;
    half8 h0, h1;
#pragma unroll
    for (int nt = 0; nt < 8; ++nt) {
      h0[nt] = (_Float16)acc[nt][r];
      h1[nt] = (_Float16)acc[nt + 8][r];
      ps += acc[nt][r] * ats[nt] + acc[nt + 8][r] * ats[nt + 8];
      pd += acc[nt][r] * atd[nt] + acc[nt + 8][r] * atd[nt + 8];
    }
    if (valid) {
      _Float16* dst = xf + (size_t)orow * HD + m * 16;
      *(half8*)dst = h0;
      *(half8*)(dst + 8) = h1;
    }
    // segmented reduce over m within aligned groups of 4 (same head)
    ps += __shfl_xor(ps, 1, 64);
    ps += __shfl_xor(ps, 2, 64);
    pd += __shfl_xor(pd, 1, 64);
    pd += __shfl_xor(pd, 2, 64);
    if (valid && (m & 3) == 0) {
      a_src[(size_t)orow * NHEAD + hh] = ps;
      a_dst[(size_t)orow * NHEAD + hh] = pd;
    }
  }
}

// ---------------------------------------------------------------------------
// Per-node softmax stats, now computing logits inline (edge_logits folded in).
// 1 wave/node. hh = lane&3, slot group j = lane>>2.
// Pass1: logit = a_src[rowc[i]] + a_dst[n] + ae -> leaky -> alpha4c, max, ae-sum.
// Pass2: alpha4c -> exp(a-m) in place, sum; nis/nselfe out.
// ---------------------------------------------------------------------------
__global__ __launch_bounds__(64) void softmax_stats_kernel(
    const int* __restrict__ row_start, const int* __restrict__ rowc,
    const float* __restrict__ ae4c_l, const float* __restrict__ a_src,
    const float* __restrict__ a_dst, float* __restrict__ alpha4c,
    float* __restrict__ nis, float* __restrict__ nselfe, int N) {
  int n = blockIdx.x;
  int lane = threadIdx.x;
  int hh = lane & 3, j = lane >> 2;
  int s = row_start[n], e = row_start[n + 1];
  float based = a_dst[(size_t)n * 4 + hh];

  float mx = -3e38f, aes = 0.f;
  for (int i = s + j; i < e; i += 16) {
    int r = rowc[i];
    float ae = ae4c_l[(size_t)i * 4 + hh];
    float lg = a_src[(size_t)r * 4 + hh] + based + ae;
    lg = (lg >= 0.f) ? lg : NEG_SLOPE * lg;
    alpha4c[(size_t)i * 4 + hh] = lg;
    mx = fmaxf(mx, lg);
    aes += ae;
  }
#pragma unroll
  for (int off = 4; off < 64; off <<= 1) {
    mx = fmaxf(mx, __shfl_xor(mx, off, 64));
    aes += __shfl_xor(aes, off, 64);
  }
  float dinv = (e > s) ? 1.0f / (float)(e - s) : 1.0f;
  float base = a_src[(size_t)n * 4 + hh] + based;
  float lg = base + aes * dinv;
  float sl = (lg >= 0.f) ? lg : NEG_SLOPE * lg;
  float m = fmaxf(mx, sl);

  float sm = 0.f;
  for (int i = s + j; i < e; i += 16) {
    float a = alpha4c[(size_t)i * 4 + hh];
    float ex = __expf(a - m);
    alpha4c[(size_t)i * 4 + hh] = ex;
    sm += ex;
  }
#pragma unroll
  for (int off = 4; off < 64; off <<= 1) sm += __shfl_xor(sm, off, 64);
  float self_e = __expf(sl - m);
  if (lane < 4) {
    nis[(size_t)n * 4 + hh] = 1.0f / (sm + self_e + 1e-16f);
    nselfe[(size_t)n * 4 + hh] = self_e;
  }
}

// ---------------------------------------------------------------------------
// Per-node gather-sum over fp16 xh. 2 nodes/block, thread = half2 channel
// pair (4B loads), 8-edge unroll -> 32 B in flight per thread.
// ---------------------------------------------------------------------------
__global__ __launch_bounds__(256) void aggregate_kernel(
    const __half* __restrict__ xh_h, const float* __restrict__ alpha4c,
    const int* __restrict__ rowc, const int* __restrict__ row_start,
    const float* __restrict__ nis, const float* __restrict__ nselfe,
    const float* __restrict__ cb, const float* __restrict__ gm,
    const float* __restrict__ bt, float inv_std, float* __restrict__ hout,
    int N) {
  int tid = threadIdx.x;
  int n = blockIdx.x * 2 + (tid >> 7);
  if (n >= N) return;
  int t = tid & 127;      // half2 index within row
  int ch = t * 2;
  int hh = ch >> 6;
  int s = row_start[n], e = row_start[n + 1];
  const __half2* xh2 = (const __half2*)xh_h;

  float2 self = __half22float2(xh2[(size_t)n * 128 + t]);
  float se = nselfe[(size_t)n * 4 + hh];
  float ax = se * self.x, ay = se * self.y;

  int i = s;
  for (; i + 8 <= e; i += 8) {
    int r[8];
    float w[8];
    float2 xv[8];
#pragma unroll
    for (int u = 0; u < 8; ++u) {
      r[u] = rowc[i + u];
      w[u] = alpha4c[(size_t)(i + u) * 4 + hh];
    }
#pragma unroll
    for (int u = 0; u < 8; ++u) xv[u] = __half22float2(xh2[(size_t)r[u] * 128 + t]);
#pragma unroll
    for (int u = 0; u < 8; ++u) {
      ax += w[u] * xv[u].x;
      ay += w[u] * xv[u].y;
    }
  }
  for (; i + 4 <= e; i += 4) {
    int r[4];
    float w[4];
    float2 xv[4];
#pragma unroll
    for (int u = 0; u < 4; ++u) {
      r[u] = rowc[i + u];
      w[u] = alpha4c[(size_t)(i + u) * 4 + hh];
    }
#pragma unroll
    for (int u = 0; u < 4; ++u) xv[u] = __half22float2(xh2[(size_t)r[u] * 128 + t]);
#pragma unroll
    for (int u = 0; u < 4; ++u) {
      ax += w[u] * xv[u].x;
      ay += w[u] * xv[u].y;
    }
  }
  for (; i < e; ++i) {
    float w = alpha4c[(size_t)i * 4 + hh];
    float2 xv = __half22float2(xh2[(size_t)rowc[i] * 128 + t]);
    ax += w * xv.x;
    ay += w * xv.y;
  }
  float is = nis[(size_t)n * 4 + hh];
  float vx = ax * is + cb[ch];
  float vy = ay * is + cb[ch + 1];
  vx = vx * inv_std * gm[ch] + bt[ch];
  vy = vy * inv_std * gm[ch + 1] + bt[ch + 1];
  float2 outv = make_float2(fmaxf(vx, 0.f), fmaxf(vy, 0.f));
  *(float2*)&hout[(size_t)n * HD + ch] = outv;
}

// ---------------------------------------------------------------------------
// Global mean pool over sorted batch ids. One block per graph.
// ---------------------------------------------------------------------------
__global__ __launch_bounds__(256) void pool_kernel(
    const float* __restrict__ h, const int* __restrict__ batch,
    float* __restrict__ out, int N) {
  int g = blockIdx.x;
  int tid = threadIdx.x;
  __shared__ int s_lo, s_hi;
  if (tid == 0) {
    int lo = 0, hi = N;
    while (lo < hi) { int mid = (lo + hi) >> 1; if (batch[mid] < g) lo = mid + 1; else hi = mid; }
    s_lo = lo;
    lo = 0; hi = N;
    while (lo < hi) { int mid = (lo + hi) >> 1; if (batch[mid] < g + 1) lo = mid + 1; else hi = mid; }
    s_hi = lo;
  }
  __syncthreads();
  int lo = s_lo, hi = s_hi;
  float acc = 0.f;
  for (int n = lo; n < hi; ++n) acc += h[(size_t)n * HD + tid];
  int cnt = hi - lo;
  out[(size_t)g * HD + tid] = acc / (float)(cnt > 0 ? cnt : 1);
}

// ---------------------------------------------------------------------------
extern "C" void kernel_launch(void* const* d_in, const int* in_sizes, int n_in,
                              void* d_out, int out_size, void* d_ws, size_t ws_size,
                              hipStream_t stream) {
  const float* x = (const float*)d_in[0];
  const int* ei = (const int*)d_in[1];
  const float* edge_attr = (const float*)d_in[2];
  const int* batch = (const int*)d_in[3];
  const float* Wn = (const float*)d_in[4];
  const float* bn_b = (const float*)d_in[5];
  const float* We = (const float*)d_in[6];
  const float* be_b = (const float*)d_in[7];
  const float* lin_w = (const float*)d_in[8];
  const float* att_src = (const float*)d_in[9];
  const float* att_dst = (const float*)d_in[10];
  const float* lin_edge_w = (const float*)d_in[11];
  const float* att_edge = (const float*)d_in[12];
  const float* conv_bias = (const float*)d_in[13];
  const float* gamma = (const float*)d_in[14];
  const float* beta = (const float*)d_in[15];

  const int N = in_sizes[3];
  const int E = in_sizes[1] / 2;
  const int G = out_size / HD;
  const int* row = ei;
  const int* col = ei + E;

  char* ws = (char*)d_ws;
  size_t off = 0;
  auto alloc = [&](size_t bytes) -> char* {
    char* p = ws + off;
    off += (bytes + 255) & ~(size_t)255;
    return p;
  };
  float* h = (float*)alloc((size_t)N * HD * 4);
  __half* xh_h = (__half*)alloc((size_t)N * HD * 2);
  float* a_src = (float*)alloc((size_t)N * NHEAD * 4);
  float* a_dst = (float*)alloc((size_t)N * NHEAD * 4);
  float* alpha4c = (float*)alloc((size_t)E * NHEAD * 4);
  float* ae4c_all = (float*)alloc((size_t)NLAYER * E * NHEAD * 4);
  float* nis = (float*)alloc((size_t)N * NHEAD * 4);
  float* nselfe = (float*)alloc((size_t)N * NHEAD * 4);
  int* deg = (int*)alloc((size_t)N * 4);
  int* row_start = (int*)alloc((size_t)(N + 1) * 4);
  int* cursor = (int*)alloc((size_t)N * 4);
  int* rowc = (int*)alloc((size_t)E * 4);
  int* ipos = (int*)alloc((size_t)E * 4);
  int* tsum = (int*)alloc(4096);
  int* toff = (int*)alloc(4096);
  float* Wc = (float*)alloc(64 * 4);
  float* bc = (float*)alloc(16 * 4);
  _Float16* Bf_hi = (_Float16*)alloc((size_t)NLAYER * HD * HD * 2);
  _Float16* Bf_lo = (_Float16*)alloc((size_t)NLAYER * HD * HD * 2);

  hipMemsetAsync(deg, 0, (size_t)N * 4, stream);
  hipMemsetAsync(cursor, 0, (size_t)N * 4, stream);

  node_embed_kernel<<<N, 256, 0, stream>>>(x, Wn, bn_b, h, N);
  precompute_wc_kernel<<<1, 256, 0, stream>>>(lin_edge_w, att_edge, We, be_b, Wc, bc);
  conv_bfrag_kernel<<<NLAYER * 128, 64, 0, stream>>>(lin_w, Bf_hi, Bf_lo);
  count_deg_kernel<<<(E + 255) / 256, 256, 0, stream>>>(col, deg, E);
  int T = (N + 255) / 256;
  tile_sums_kernel<<<T, 256, 0, stream>>>(deg, tsum, N);
  scan_tsums_kernel<<<1, 64, 0, stream>>>(tsum, toff, T);
  scan_local_kernel<<<T, 256, 0, stream>>>(deg, toff, row_start, N, E);
  scatter_csr_kernel<<<(E + 255) / 256, 256, 0, stream>>>(row, col, row_start,
                                                          cursor, rowc, ipos, E);
  edge_ae_kernel<<<(E + 255) / 256, 256, 0, stream>>>(edge_attr, ipos, Wc, bc,
                                                      ae4c_all, E);

  const float inv_std = 1.0f / sqrtf(1.0f + 1e-5f);
  for (int l = 0; l < NLAYER; ++l) {
    mfma_gemm_fused_kernel<<<(N + 63) / 64, 256, 0, stream>>>(
        h, Bf_hi + (size_t)l * HD * HD, Bf_lo + (size_t)l * HD * HD,
        att_src + l * HD, att_dst + l * HD, xh_h, a_src, a_dst, N);
    softmax_stats_kernel<<<N, 64, 0, stream>>>(
        row_start, rowc, ae4c_all + (size_t)l * E * NHEAD, a_src, a_dst,
        alpha4c, nis, nselfe, N);
    aggregate_kernel<<<(N + 1) / 2, 256, 0, stream>>>(
        xh_h, alpha4c, rowc, row_start, nis, nselfe,
        conv_bias + l * HD, gamma + l * HD, beta + l * HD, inv_std, h, N);
  }
  pool_kernel<<<G, 256, 0, stream>>>(h, batch, (float*)d_out, N);
}

// Round 8
// 701.962 us; speedup vs baseline: 2.3944x; 1.1076x over previous
//
#include <hip/hip_runtime.h>
#include <hip/hip_fp16.h>
#include <math.h>

#define HD 256
#define NHEAD 4
#define CH 64
#define NLAYER 3
#define NEG_SLOPE 0.2f

typedef __attribute__((ext_vector_type(8))) _Float16 half8;
typedef __attribute__((ext_vector_type(4))) _Float16 half4v;
typedef __attribute__((ext_vector_type(4))) float float4v;

// ---------------------------------------------------------------------------
// h0 = x @ Wn + bn_b      (x: [N,9], Wn: [9,256])
// ---------------------------------------------------------------------------
__global__ __launch_bounds__(256) void node_embed_kernel(
    const float* __restrict__ x, const float* __restrict__ Wn,
    const float* __restrict__ bn_b, float* __restrict__ h, int N) {
  int n = blockIdx.x;
  int c = threadIdx.x;
  __shared__ float xs[9];
  if (c < 9) xs[c] = x[(size_t)n * 9 + c];
  __syncthreads();
  float v = bn_b[c];
#pragma unroll
  for (int k = 0; k < 9; ++k) v += xs[k] * Wn[k * HD + c];
  h[(size_t)n * HD + c] = v;
}

// ---------------------------------------------------------------------------
// Fold edge path: Wc[5][12] = We @ w_eff,  bc[12] = be_b @ w_eff
// ---------------------------------------------------------------------------
__global__ __launch_bounds__(256) void precompute_wc_kernel(
    const float* __restrict__ lin_edge_w, const float* __restrict__ att_edge,
    const float* __restrict__ We, const float* __restrict__ be_b,
    float* __restrict__ Wc, float* __restrict__ bc) {
  __shared__ float weff[256][12];
  int j = threadIdx.x;
#pragma unroll
  for (int l = 0; l < NLAYER; ++l) {
#pragma unroll
    for (int hh = 0; hh < NHEAD; ++hh) {
      float s = 0.f;
      const float* lw = lin_edge_w + (size_t)l * HD * HD + (size_t)j * HD + hh * CH;
      const float* ae = att_edge + l * HD + hh * CH;
      for (int c = 0; c < CH; ++c) s += lw[c] * ae[c];
      weff[j][l * NHEAD + hh] = s;
    }
  }
  __syncthreads();
  if (j < 60) {
    int k = j / 12, lh = j % 12;
    float s = 0.f;
    for (int t = 0; t < 256; ++t) s += We[k * HD + t] * weff[t][lh];
    Wc[k * 12 + lh] = s;
  } else if (j < 72) {
    int lh = j - 60;
    float s = 0.f;
    for (int t = 0; t < 256; ++t) s += be_b[t] * weff[t][lh];
    bc[lh] = s;
  }
}

// ---------------------------------------------------------------------------
// Repack lin_w into MFMA B-fragment order, split fp16 hi/lo.
// Interleaved col map: fragment (l,kt,nt), lane -> B[kt*32+(lane>>4)*8+j][(lane&15)*16+nt]
// ---------------------------------------------------------------------------
__global__ __launch_bounds__(64) void conv_bfrag_kernel(
    const float* __restrict__ lin_w, _Float16* __restrict__ Bf_hi,
    _Float16* __restrict__ Bf_lo) {
  int bid = blockIdx.x;            // l*128 + kt*16 + nt
  int l = bid >> 7;
  int kt = (bid >> 4) & 7, nt = bid & 15;
  int lane = threadIdx.x;
  const float* B = lin_w + (size_t)l * HD * HD;
  size_t base = ((size_t)bid * 64 + lane) * 8;
  int k0 = kt * 32 + (lane >> 4) * 8;
  int n = (lane & 15) * 16 + nt;
#pragma unroll
  for (int j = 0; j < 8; ++j) {
    float v = B[(size_t)(k0 + j) * HD + n];
    _Float16 hi = (_Float16)v;
    _Float16 lo = (_Float16)(v - (float)hi);
    Bf_hi[base + j] = hi;
    Bf_lo[base + j] = lo;
  }
}

// ---------------------------------------------------------------------------
// CSR build by destination (col)
// ---------------------------------------------------------------------------
__global__ __launch_bounds__(256) void count_deg_kernel(
    const int* __restrict__ col, int* __restrict__ deg, int E) {
  int e = blockIdx.x * 256 + threadIdx.x;
  if (e < E) atomicAdd(&deg[col[e]], 1);
}

__global__ __launch_bounds__(256) void tile_sums_kernel(
    const int* __restrict__ deg, int* __restrict__ tsum, int N) {
  __shared__ int red[256];
  int i = blockIdx.x * 256 + threadIdx.x;
  red[threadIdx.x] = (i < N) ? deg[i] : 0;
  __syncthreads();
  for (int off = 128; off > 0; off >>= 1) {
    if (threadIdx.x < off) red[threadIdx.x] += red[threadIdx.x + off];
    __syncthreads();
  }
  if (threadIdx.x == 0) tsum[blockIdx.x] = red[0];
}

__global__ __launch_bounds__(64) void scan_tsums_kernel(
    const int* __restrict__ tsum, int* __restrict__ toff, int T) {
  int lane = threadIdx.x;
  int carry = 0;
  for (int base = 0; base < T; base += 64) {
    int i = base + lane;
    int orig = (i < T) ? tsum[i] : 0;
    int v = orig;
#pragma unroll
    for (int off = 1; off < 64; off <<= 1) {
      int t = __shfl_up(v, off, 64);
      if (lane >= off) v += t;
    }
    if (i < T) toff[i] = carry + v - orig;
    carry += __shfl(v, 63, 64);
  }
}

__global__ __launch_bounds__(256) void scan_local_kernel(
    const int* __restrict__ deg, const int* __restrict__ toff,
    int* __restrict__ row_start, int N, int E) {
  __shared__ int buf[256];
  int i = blockIdx.x * 256 + threadIdx.x;
  int v = (i < N) ? deg[i] : 0;
  buf[threadIdx.x] = v;
  __syncthreads();
  for (int off = 1; off < 256; off <<= 1) {
    int t = (threadIdx.x >= off) ? buf[threadIdx.x - off] : 0;
    __syncthreads();
    buf[threadIdx.x] += t;
    __syncthreads();
  }
  if (i < N) row_start[i] = toff[blockIdx.x] + buf[threadIdx.x] - v;
  if (blockIdx.x == 0 && threadIdx.x == 0) row_start[N] = E;
}

__global__ __launch_bounds__(256) void scatter_csr_kernel(
    const int* __restrict__ row, const int* __restrict__ col,
    const int* __restrict__ row_start, int* __restrict__ cursor,
    int* __restrict__ rowc, int* __restrict__ ipos, int E) {
  int e = blockIdx.x * 256 + threadIdx.x;
  if (e < E) {
    int c = col[e];
    int p = atomicAdd(&cursor[c], 1);
    int slot = row_start[c] + p;
    rowc[slot] = row[e];
    ipos[e] = slot;
  }
}

// ---------------------------------------------------------------------------
// Once per launch: a_e for ALL 3 layers, written in CSR order.
// ---------------------------------------------------------------------------
__global__ __launch_bounds__(256) void edge_ae_kernel(
    const float* __restrict__ edge_attr, const int* __restrict__ ipos,
    const float* __restrict__ Wc, const float* __restrict__ bc,
    float* __restrict__ ae4c_all, int E) {
  __shared__ float sWc[60];
  __shared__ float sbc[12];
  int t = threadIdx.x;
  if (t < 60) sWc[t] = Wc[t];
  if (t < 12) sbc[t] = bc[t];
  __syncthreads();
  int e = blockIdx.x * 256 + t;
  if (e >= E) return;
  int slot = ipos[e];
  float ea[5];
#pragma unroll
  for (int k = 0; k < 5; ++k) ea[k] = edge_attr[(size_t)e * 5 + k];
#pragma unroll
  for (int l = 0; l < NLAYER; ++l) {
    float av[NHEAD];
#pragma unroll
    for (int hh = 0; hh < NHEAD; ++hh) {
      int lh = l * NHEAD + hh;
      float s = sbc[lh];
#pragma unroll
      for (int k = 0; k < 5; ++k) s += ea[k] * sWc[k * 12 + lh];
      av[hh] = s;
    }
    *(float4*)(ae4c_all + ((size_t)l * E + slot) * 4) =
        make_float4(av[0], av[1], av[2], av[3]);
  }
}

// ---------------------------------------------------------------------------
// MFMA split-fp16 GEMM, fused epilogue. Per-kt B fragments staged in LDS
// (32 KB), shared by all 4 waves -> 4x less L2 B-traffic per block.
// ---------------------------------------------------------------------------
__global__ __launch_bounds__(256) void mfma_gemm_fused_kernel(
    const float* __restrict__ A, const _Float16* __restrict__ Bf_hi,
    const _Float16* __restrict__ Bf_lo, const float* __restrict__ att_s,
    const float* __restrict__ att_d, __half* __restrict__ xh_h,
    float* __restrict__ a_src, float* __restrict__ a_dst, int N) {
  __shared__ _Float16 sBh[8192];  // 16 KB: kt-slice of Bf_hi (16 nt x 512)
  __shared__ _Float16 sBl[8192];  // 16 KB: kt-slice of Bf_lo
  const int tid = threadIdx.x;
  const int wave = tid >> 6, lane = tid & 63;
  const int m = lane & 15, quad = lane >> 4;
  const int rowbase = blockIdx.x * 64 + wave * 16;
  const int arow = rowbase + m;
  const int arowc = (arow < N) ? arow : (N - 1);

  float4v acc[16];
#pragma unroll
  for (int nt = 0; nt < 16; ++nt) acc[nt] = (float4v){0.f, 0.f, 0.f, 0.f};

  for (int kt = 0; kt < 8; ++kt) {
    __syncthreads();  // previous iteration's LDS reads done
    {
      const float4* gh = (const float4*)(Bf_hi + (size_t)kt * 8192);
      const float4* gl = (const float4*)(Bf_lo + (size_t)kt * 8192);
      float4* dh = (float4*)sBh;
      float4* dl = (float4*)sBl;
#pragma unroll
      for (int u = 0; u < 4; ++u) {
        dh[tid + u * 256] = gh[tid + u * 256];
        dl[tid + u * 256] = gl[tid + u * 256];
      }
    }
    const float* ap = A + (size_t)arowc * HD + kt * 32 + quad * 8;
    float4 av0 = *(const float4*)(ap);
    float4 av1 = *(const float4*)(ap + 4);
    float af[8] = {av0.x, av0.y, av0.z, av0.w, av1.x, av1.y, av1.z, av1.w};
    half8 ahi, alo;
#pragma unroll
    for (int j = 0; j < 8; ++j) {
      _Float16 hi = (_Float16)af[j];
      ahi[j] = hi;
      alo[j] = (_Float16)(af[j] - (float)hi);
    }
    __syncthreads();  // staging complete
#pragma unroll
    for (int nt = 0; nt < 16; ++nt) {
      half8 bhi = *(const half8*)&sBh[nt * 512 + lane * 8];
      half8 blo = *(const half8*)&sBl[nt * 512 + lane * 8];
      acc[nt] = __builtin_amdgcn_mfma_f32_16x16x32_f16(ahi, bhi, acc[nt], 0, 0, 0);
      acc[nt] = __builtin_amdgcn_mfma_f32_16x16x32_f16(alo, bhi, acc[nt], 0, 0, 0);
      acc[nt] = __builtin_amdgcn_mfma_f32_16x16x32_f16(ahi, blo, acc[nt], 0, 0, 0);
    }
  }

  // lane's 16 cols are m*16 .. m*16+15, all in head hh = m>>2
  const int hh = m >> 2;
  float ats[16], atd[16];
#pragma unroll
  for (int nt = 0; nt < 16; ++nt) {
    ats[nt] = att_s[m * 16 + nt];
    atd[nt] = att_d[m * 16 + nt];
  }
  _Float16* xf = (_Float16*)xh_h;
#pragma unroll
  for (int r = 0; r < 4; ++r) {
    int orow = rowbase + quad * 4 + r;
    bool valid = orow < N;
    float ps = 0.f, pd = 0.f;
    half8 h0, h1;
#pragma unroll
    for (int nt = 0; nt < 8; ++nt) {
      h0[nt] = (_Float16)acc[nt][r];
      h1[nt] = (_Float16)acc[nt + 8][r];
      ps += acc[nt][r] * ats[nt] + acc[nt + 8][r] * ats[nt + 8];
      pd += acc[nt][r] * atd[nt] + acc[nt + 8][r] * atd[nt + 8];
    }
    if (valid) {
      _Float16* dst = xf + (size_t)orow * HD + m * 16;
      *(half8*)dst = h0;
      *(half8*)(dst + 8) = h1;
    }
    ps += __shfl_xor(ps, 1, 64);
    ps += __shfl_xor(ps, 2, 64);
    pd += __shfl_xor(pd, 1, 64);
    pd += __shfl_xor(pd, 2, 64);
    if (valid && (m & 3) == 0) {
      a_src[(size_t)orow * NHEAD + hh] = ps;
      a_dst[(size_t)orow * NHEAD + hh] = pd;
    }
  }
}

// ---------------------------------------------------------------------------
// Per-node softmax stats with inline logits. 1 wave/node.
// ---------------------------------------------------------------------------
__global__ __launch_bounds__(64) void softmax_stats_kernel(
    const int* __restrict__ row_start, const int* __restrict__ rowc,
    const float* __restrict__ ae4c_l, const float* __restrict__ a_src,
    const float* __restrict__ a_dst, float* __restrict__ alpha4c,
    float* __restrict__ nis, float* __restrict__ nselfe, int N) {
  int n = blockIdx.x;
  int lane = threadIdx.x;
  int hh = lane & 3, j = lane >> 2;
  int s = row_start[n], e = row_start[n + 1];
  float based = a_dst[(size_t)n * 4 + hh];

  float mx = -3e38f, aes = 0.f;
  for (int i = s + j; i < e; i += 16) {
    int r = rowc[i];
    float ae = ae4c_l[(size_t)i * 4 + hh];
    float lg = a_src[(size_t)r * 4 + hh] + based + ae;
    lg = (lg >= 0.f) ? lg : NEG_SLOPE * lg;
    alpha4c[(size_t)i * 4 + hh] = lg;
    mx = fmaxf(mx, lg);
    aes += ae;
  }
#pragma unroll
  for (int off = 4; off < 64; off <<= 1) {
    mx = fmaxf(mx, __shfl_xor(mx, off, 64));
    aes += __shfl_xor(aes, off, 64);
  }
  float dinv = (e > s) ? 1.0f / (float)(e - s) : 1.0f;
  float base = a_src[(size_t)n * 4 + hh] + based;
  float lg = base + aes * dinv;
  float sl = (lg >= 0.f) ? lg : NEG_SLOPE * lg;
  float m = fmaxf(mx, sl);

  float sm = 0.f;
  for (int i = s + j; i < e; i += 16) {
    float a = alpha4c[(size_t)i * 4 + hh];
    float ex = __expf(a - m);
    alpha4c[(size_t)i * 4 + hh] = ex;
    sm += ex;
  }
#pragma unroll
  for (int off = 4; off < 64; off <<= 1) sm += __shfl_xor(sm, off, 64);
  float self_e = __expf(sl - m);
  if (lane < 4) {
    nis[(size_t)n * 4 + hh] = 1.0f / (sm + self_e + 1e-16f);
    nselfe[(size_t)n * 4 + hh] = self_e;
  }
}

// ---------------------------------------------------------------------------
// Per-node gather-sum over fp16 xh. 1 wave/node, thread = 4 channels
// (half4 8B loads), 8-edge unroll -> 64 B in flight per thread.
// ---------------------------------------------------------------------------
__global__ __launch_bounds__(256) void aggregate_kernel(
    const __half* __restrict__ xh_h, const float* __restrict__ alpha4c,
    const int* __restrict__ rowc, const int* __restrict__ row_start,
    const float* __restrict__ nis, const float* __restrict__ nselfe,
    const float* __restrict__ cb, const float* __restrict__ gm,
    const float* __restrict__ bt, float inv_std, float* __restrict__ hout,
    int N) {
  int tid = threadIdx.x;
  int n = blockIdx.x * 4 + (tid >> 6);
  if (n >= N) return;
  int t = tid & 63;
  int ch = t * 4;
  int hh = t >> 4;
  int s = row_start[n], e = row_start[n + 1];
  const half4v* xh4 = (const half4v*)xh_h;  // row stride 64

  half4v sv = xh4[n * 64 + t];
  float se = nselfe[n * 4 + hh];
  float a0 = se * (float)sv[0], a1 = se * (float)sv[1];
  float a2 = se * (float)sv[2], a3 = se * (float)sv[3];

  int i = s;
  for (; i + 8 <= e; i += 8) {
    int r[8];
    float w[8];
    half4v xv[8];
#pragma unroll
    for (int u = 0; u < 8; ++u) {
      r[u] = rowc[i + u];
      w[u] = alpha4c[(i + u) * 4 + hh];
    }
#pragma unroll
    for (int u = 0; u < 8; ++u) xv[u] = xh4[r[u] * 64 + t];
#pragma unroll
    for (int u = 0; u < 8; ++u) {
      a0 += w[u] * (float)xv[u][0];
      a1 += w[u] * (float)xv[u][1];
      a2 += w[u] * (float)xv[u][2];
      a3 += w[u] * (float)xv[u][3];
    }
  }
  for (; i < e; ++i) {
    float w = alpha4c[i * 4 + hh];
    half4v xv = xh4[rowc[i] * 64 + t];
    a0 += w * (float)xv[0];
    a1 += w * (float)xv[1];
    a2 += w * (float)xv[2];
    a3 += w * (float)xv[3];
  }
  float is = nis[n * 4 + hh];
  float4 outv;
  outv.x = fmaxf((a0 * is + cb[ch + 0]) * inv_std * gm[ch + 0] + bt[ch + 0], 0.f);
  outv.y = fmaxf((a1 * is + cb[ch + 1]) * inv_std * gm[ch + 1] + bt[ch + 1], 0.f);
  outv.z = fmaxf((a2 * is + cb[ch + 2]) * inv_std * gm[ch + 2] + bt[ch + 2], 0.f);
  outv.w = fmaxf((a3 * is + cb[ch + 3]) * inv_std * gm[ch + 3] + bt[ch + 3], 0.f);
  *(float4*)&hout[(size_t)n * HD + ch] = outv;
}

// ---------------------------------------------------------------------------
// Global mean pool over sorted batch ids. One block per graph.
// ---------------------------------------------------------------------------
__global__ __launch_bounds__(256) void pool_kernel(
    const float* __restrict__ h, const int* __restrict__ batch,
    float* __restrict__ out, int N) {
  int g = blockIdx.x;
  int tid = threadIdx.x;
  __shared__ int s_lo, s_hi;
  if (tid == 0) {
    int lo = 0, hi = N;
    while (lo < hi) { int mid = (lo + hi) >> 1; if (batch[mid] < g) lo = mid + 1; else hi = mid; }
    s_lo = lo;
    lo = 0; hi = N;
    while (lo < hi) { int mid = (lo + hi) >> 1; if (batch[mid] < g + 1) lo = mid + 1; else hi = mid; }
    s_hi = lo;
  }
  __syncthreads();
  int lo = s_lo, hi = s_hi;
  float acc = 0.f;
  for (int n = lo; n < hi; ++n) acc += h[(size_t)n * HD + tid];
  int cnt = hi - lo;
  out[(size_t)g * HD + tid] = acc / (float)(cnt > 0 ? cnt : 1);
}

// ---------------------------------------------------------------------------
extern "C" void kernel_launch(void* const* d_in, const int* in_sizes, int n_in,
                              void* d_out, int out_size, void* d_ws, size_t ws_size,
                              hipStream_t stream) {
  const float* x = (const float*)d_in[0];
  const int* ei = (const int*)d_in[1];
  const float* edge_attr = (const float*)d_in[2];
  const int* batch = (const int*)d_in[3];
  const float* Wn = (const float*)d_in[4];
  const float* bn_b = (const float*)d_in[5];
  const float* We = (const float*)d_in[6];
  const float* be_b = (const float*)d_in[7];
  const float* lin_w = (const float*)d_in[8];
  const float* att_src = (const float*)d_in[9];
  const float* att_dst = (const float*)d_in[10];
  const float* lin_edge_w = (const float*)d_in[11];
  const float* att_edge = (const float*)d_in[12];
  const float* conv_bias = (const float*)d_in[13];
  const float* gamma = (const float*)d_in[14];
  const float* beta = (const float*)d_in[15];

  const int N = in_sizes[3];
  const int E = in_sizes[1] / 2;
  const int G = out_size / HD;
  const int* row = ei;
  const int* col = ei + E;

  char* ws = (char*)d_ws;
  size_t off = 0;
  auto alloc = [&](size_t bytes) -> char* {
    char* p = ws + off;
    off += (bytes + 255) & ~(size_t)255;
    return p;
  };
  float* h = (float*)alloc((size_t)N * HD * 4);
  __half* xh_h = (__half*)alloc((size_t)N * HD * 2);
  float* a_src = (float*)alloc((size_t)N * NHEAD * 4);
  float* a_dst = (float*)alloc((size_t)N * NHEAD * 4);
  float* alpha4c = (float*)alloc((size_t)E * NHEAD * 4);
  float* ae4c_all = (float*)alloc((size_t)NLAYER * E * NHEAD * 4);
  float* nis = (float*)alloc((size_t)N * NHEAD * 4);
  float* nselfe = (float*)alloc((size_t)N * NHEAD * 4);
  int* deg = (int*)alloc((size_t)N * 4);
  int* row_start = (int*)alloc((size_t)(N + 1) * 4);
  int* cursor = (int*)alloc((size_t)N * 4);
  int* rowc = (int*)alloc((size_t)E * 4);
  int* ipos = (int*)alloc((size_t)E * 4);
  int* tsum = (int*)alloc(4096);
  int* toff = (int*)alloc(4096);
  float* Wc = (float*)alloc(64 * 4);
  float* bc = (float*)alloc(16 * 4);
  _Float16* Bf_hi = (_Float16*)alloc((size_t)NLAYER * HD * HD * 2);
  _Float16* Bf_lo = (_Float16*)alloc((size_t)NLAYER * HD * HD * 2);

  hipMemsetAsync(deg, 0, (size_t)N * 4, stream);
  hipMemsetAsync(cursor, 0, (size_t)N * 4, stream);

  node_embed_kernel<<<N, 256, 0, stream>>>(x, Wn, bn_b, h, N);
  precompute_wc_kernel<<<1, 256, 0, stream>>>(lin_edge_w, att_edge, We, be_b, Wc, bc);
  conv_bfrag_kernel<<<NLAYER * 128, 64, 0, stream>>>(lin_w, Bf_hi, Bf_lo);
  count_deg_kernel<<<(E + 255) / 256, 256, 0, stream>>>(col, deg, E);
  int T = (N + 255) / 256;
  tile_sums_kernel<<<T, 256, 0, stream>>>(deg, tsum, N);
  scan_tsums_kernel<<<1, 64, 0, stream>>>(tsum, toff, T);
  scan_local_kernel<<<T, 256, 0, stream>>>(deg, toff, row_start, N, E);
  scatter_csr_kernel<<<(E + 255) / 256, 256, 0, stream>>>(row, col, row_start,
                                                          cursor, rowc, ipos, E);
  edge_ae_kernel<<<(E + 255) / 256, 256, 0, stream>>>(edge_attr, ipos, Wc, bc,
                                                      ae4c_all, E);

  const float inv_std = 1.0f / sqrtf(1.0f + 1e-5f);
  for (int l = 0; l < NLAYER; ++l) {
    mfma_gemm_fused_kernel<<<(N + 63) / 64, 256, 0, stream>>>(
        h, Bf_hi + (size_t)l * HD * HD, Bf_lo + (size_t)l * HD * HD,
        att_src + l * HD, att_dst + l * HD, xh_h, a_src, a_dst, N);
    softmax_stats_kernel<<<N, 64, 0, stream>>>(
        row_start, rowc, ae4c_all + (size_t)l * E * NHEAD, a_src, a_dst,
        alpha4c, nis, nselfe, N);
    aggregate_kernel<<<(N + 3) / 4, 256, 0, stream>>>(
        xh_h, alpha4c, rowc, row_start, nis, nselfe,
        conv_bias + l * HD, gamma + l * HD, beta + l * HD, inv_std, h, N);
  }
  pool_kernel<<<G, 256, 0, stream>>>(h, batch, (float*)d_out, N);
}

// Round 9
// 676.585 us; speedup vs baseline: 2.4842x; 1.0375x over previous
//
#include <hip/hip_runtime.h>
#include <hip/hip_fp16.h>
#include <math.h>

#define HD 256
#define NHEAD 4
#define CH 64
#define NLAYER 3
#define NEG_SLOPE 0.2f

typedef __attribute__((ext_vector_type(8))) _Float16 half8;
typedef __attribute__((ext_vector_type(4))) _Float16 half4v;
typedef __attribute__((ext_vector_type(4))) float float4v;

// ---------------------------------------------------------------------------
// h0 = x @ Wn + bn_b      (x: [N,9], Wn: [9,256])
// ---------------------------------------------------------------------------
__global__ __launch_bounds__(256) void node_embed_kernel(
    const float* __restrict__ x, const float* __restrict__ Wn,
    const float* __restrict__ bn_b, float* __restrict__ h, int N) {
  int n = blockIdx.x;
  int c = threadIdx.x;
  __shared__ float xs[9];
  if (c < 9) xs[c] = x[(size_t)n * 9 + c];
  __syncthreads();
  float v = bn_b[c];
#pragma unroll
  for (int k = 0; k < 9; ++k) v += xs[k] * Wn[k * HD + c];
  h[(size_t)n * HD + c] = v;
}

// ---------------------------------------------------------------------------
// Fold edge path: Wc[5][12] = We @ w_eff,  bc[12] = be_b @ w_eff
// ---------------------------------------------------------------------------
__global__ __launch_bounds__(256) void precompute_wc_kernel(
    const float* __restrict__ lin_edge_w, const float* __restrict__ att_edge,
    const float* __restrict__ We, const float* __restrict__ be_b,
    float* __restrict__ Wc, float* __restrict__ bc) {
  __shared__ float weff[256][12];
  int j = threadIdx.x;
#pragma unroll
  for (int l = 0; l < NLAYER; ++l) {
#pragma unroll
    for (int hh = 0; hh < NHEAD; ++hh) {
      float s = 0.f;
      const float* lw = lin_edge_w + (size_t)l * HD * HD + (size_t)j * HD + hh * CH;
      const float* ae = att_edge + l * HD + hh * CH;
      for (int c = 0; c < CH; ++c) s += lw[c] * ae[c];
      weff[j][l * NHEAD + hh] = s;
    }
  }
  __syncthreads();
  if (j < 60) {
    int k = j / 12, lh = j % 12;
    float s = 0.f;
    for (int t = 0; t < 256; ++t) s += We[k * HD + t] * weff[t][lh];
    Wc[k * 12 + lh] = s;
  } else if (j < 72) {
    int lh = j - 60;
    float s = 0.f;
    for (int t = 0; t < 256; ++t) s += be_b[t] * weff[t][lh];
    bc[lh] = s;
  }
}

// ---------------------------------------------------------------------------
// Repack lin_w into MFMA B-fragment order, split fp16 hi/lo.
// Interleaved col map: fragment (l,kt,nt), lane -> B[kt*32+(lane>>4)*8+j][(lane&15)*16+nt]
// ---------------------------------------------------------------------------
__global__ __launch_bounds__(64) void conv_bfrag_kernel(
    const float* __restrict__ lin_w, _Float16* __restrict__ Bf_hi,
    _Float16* __restrict__ Bf_lo) {
  int bid = blockIdx.x;            // l*128 + kt*16 + nt
  int l = bid >> 7;
  int kt = (bid >> 4) & 7, nt = bid & 15;
  int lane = threadIdx.x;
  const float* B = lin_w + (size_t)l * HD * HD;
  size_t base = ((size_t)bid * 64 + lane) * 8;
  int k0 = kt * 32 + (lane >> 4) * 8;
  int n = (lane & 15) * 16 + nt;
#pragma unroll
  for (int j = 0; j < 8; ++j) {
    float v = B[(size_t)(k0 + j) * HD + n];
    _Float16 hi = (_Float16)v;
    _Float16 lo = (_Float16)(v - (float)hi);
    Bf_hi[base + j] = hi;
    Bf_lo[base + j] = lo;
  }
}

// ---------------------------------------------------------------------------
// CSR build by destination (col)
// ---------------------------------------------------------------------------
__global__ __launch_bounds__(256) void count_deg_kernel(
    const int* __restrict__ col, int* __restrict__ deg, int E) {
  int e = blockIdx.x * 256 + threadIdx.x;
  if (e < E) atomicAdd(&deg[col[e]], 1);
}

__global__ __launch_bounds__(256) void tile_sums_kernel(
    const int* __restrict__ deg, int* __restrict__ tsum, int N) {
  __shared__ int red[256];
  int i = blockIdx.x * 256 + threadIdx.x;
  red[threadIdx.x] = (i < N) ? deg[i] : 0;
  __syncthreads();
  for (int off = 128; off > 0; off >>= 1) {
    if (threadIdx.x < off) red[threadIdx.x] += red[threadIdx.x + off];
    __syncthreads();
  }
  if (threadIdx.x == 0) tsum[blockIdx.x] = red[0];
}

__global__ __launch_bounds__(64) void scan_tsums_kernel(
    const int* __restrict__ tsum, int* __restrict__ toff, int T) {
  int lane = threadIdx.x;
  int carry = 0;
  for (int base = 0; base < T; base += 64) {
    int i = base + lane;
    int orig = (i < T) ? tsum[i] : 0;
    int v = orig;
#pragma unroll
    for (int off = 1; off < 64; off <<= 1) {
      int t = __shfl_up(v, off, 64);
      if (lane >= off) v += t;
    }
    if (i < T) toff[i] = carry + v - orig;
    carry += __shfl(v, 63, 64);
  }
}

__global__ __launch_bounds__(256) void scan_local_kernel(
    const int* __restrict__ deg, const int* __restrict__ toff,
    int* __restrict__ row_start, int N, int E) {
  __shared__ int buf[256];
  int i = blockIdx.x * 256 + threadIdx.x;
  int v = (i < N) ? deg[i] : 0;
  buf[threadIdx.x] = v;
  __syncthreads();
  for (int off = 1; off < 256; off <<= 1) {
    int t = (threadIdx.x >= off) ? buf[threadIdx.x - off] : 0;
    __syncthreads();
    buf[threadIdx.x] += t;
    __syncthreads();
  }
  if (i < N) row_start[i] = toff[blockIdx.x] + buf[threadIdx.x] - v;
  if (blockIdx.x == 0 && threadIdx.x == 0) row_start[N] = E;
}

__global__ __launch_bounds__(256) void scatter_csr_kernel(
    const int* __restrict__ row, const int* __restrict__ col,
    const int* __restrict__ row_start, int* __restrict__ cursor,
    int* __restrict__ rowc, int* __restrict__ ipos, int E) {
  int e = blockIdx.x * 256 + threadIdx.x;
  if (e < E) {
    int c = col[e];
    int p = atomicAdd(&cursor[c], 1);
    int slot = row_start[c] + p;
    rowc[slot] = row[e];
    ipos[e] = slot;
  }
}

// ---------------------------------------------------------------------------
// Once per launch: a_e for ALL 3 layers, written in CSR order.
// ---------------------------------------------------------------------------
__global__ __launch_bounds__(256) void edge_ae_kernel(
    const float* __restrict__ edge_attr, const int* __restrict__ ipos,
    const float* __restrict__ Wc, const float* __restrict__ bc,
    float* __restrict__ ae4c_all, int E) {
  __shared__ float sWc[60];
  __shared__ float sbc[12];
  int t = threadIdx.x;
  if (t < 60) sWc[t] = Wc[t];
  if (t < 12) sbc[t] = bc[t];
  __syncthreads();
  int e = blockIdx.x * 256 + t;
  if (e >= E) return;
  int slot = ipos[e];
  float ea[5];
#pragma unroll
  for (int k = 0; k < 5; ++k) ea[k] = edge_attr[(size_t)e * 5 + k];
#pragma unroll
  for (int l = 0; l < NLAYER; ++l) {
    float av[NHEAD];
#pragma unroll
    for (int hh = 0; hh < NHEAD; ++hh) {
      int lh = l * NHEAD + hh;
      float s = sbc[lh];
#pragma unroll
      for (int k = 0; k < 5; ++k) s += ea[k] * sWc[k * 12 + lh];
      av[hh] = s;
    }
    *(float4*)(ae4c_all + ((size_t)l * E + slot) * 4) =
        make_float4(av[0], av[1], av[2], av[3]);
  }
}

// ---------------------------------------------------------------------------
// MFMA split-fp16 GEMM, fused epilogue; per-kt B staged in LDS (32 KB).
// ---------------------------------------------------------------------------
__global__ __launch_bounds__(256) void mfma_gemm_fused_kernel(
    const float* __restrict__ A, const _Float16* __restrict__ Bf_hi,
    const _Float16* __restrict__ Bf_lo, const float* __restrict__ att_s,
    const float* __restrict__ att_d, __half* __restrict__ xh_h,
    float* __restrict__ a_src, float* __restrict__ a_dst, int N) {
  __shared__ _Float16 sBh[8192];
  __shared__ _Float16 sBl[8192];
  const int tid = threadIdx.x;
  const int wave = tid >> 6, lane = tid & 63;
  const int m = lane & 15, quad = lane >> 4;
  const int rowbase = blockIdx.x * 64 + wave * 16;
  const int arow = rowbase + m;
  const int arowc = (arow < N) ? arow : (N - 1);

  float4v acc[16];
#pragma unroll
  for (int nt = 0; nt < 16; ++nt) acc[nt] = (float4v){0.f, 0.f, 0.f, 0.f};

  for (int kt = 0; kt < 8; ++kt) {
    __syncthreads();
    {
      const float4* gh = (const float4*)(Bf_hi + (size_t)kt * 8192);
      const float4* gl = (const float4*)(Bf_lo + (size_t)kt * 8192);
      float4* dh = (float4*)sBh;
      float4* dl = (float4*)sBl;
#pragma unroll
      for (int u = 0; u < 4; ++u) {
        dh[tid + u * 256] = gh[tid + u * 256];
        dl[tid + u * 256] = gl[tid + u * 256];
      }
    }
    const float* ap = A + (size_t)arowc * HD + kt * 32 + quad * 8;
    float4 av0 = *(const float4*)(ap);
    float4 av1 = *(const float4*)(ap + 4);
    float af[8] = {av0.x, av0.y, av0.z, av0.w, av1.x, av1.y, av1.z, av1.w};
    half8 ahi, alo;
#pragma unroll
    for (int j = 0; j < 8; ++j) {
      _Float16 hi = (_Float16)af[j];
      ahi[j] = hi;
      alo[j] = (_Float16)(af[j] - (float)hi);
    }
    __syncthreads();
#pragma unroll
    for (int nt = 0; nt < 16; ++nt) {
      half8 bhi = *(const half8*)&sBh[nt * 512 + lane * 8];
      half8 blo = *(const half8*)&sBl[nt * 512 + lane * 8];
      acc[nt] = __builtin_amdgcn_mfma_f32_16x16x32_f16(ahi, bhi, acc[nt], 0, 0, 0);
      acc[nt] = __builtin_amdgcn_mfma_f32_16x16x32_f16(alo, bhi, acc[nt], 0, 0, 0);
      acc[nt] = __builtin_amdgcn_mfma_f32_16x16x32_f16(ahi, blo, acc[nt], 0, 0, 0);
    }
  }

  const int hh = m >> 2;
  float ats[16], atd[16];
#pragma unroll
  for (int nt = 0; nt < 16; ++nt) {
    ats[nt] = att_s[m * 16 + nt];
    atd[nt] = att_d[m * 16 + nt];
  }
  _Float16* xf = (_Float16*)xh_h;
#pragma unroll
  for (int r = 0; r < 4; ++r) {
    int orow = rowbase + quad * 4 + r;
    bool valid = orow < N;
    float ps = 0.f, pd = 0.f;
    half8 h0, h1;
#pragma unroll
    for (int nt = 0; nt < 8; ++nt) {
      h0[nt] = (_Float16)acc[nt][r];
      h1[nt] = (_Float16)acc[nt + 8][r];
      ps += acc[nt][r] * ats[nt] + acc[nt + 8][r] * ats[nt + 8];
      pd += acc[nt][r] * atd[nt] + acc[nt + 8][r] * atd[nt + 8];
    }
    if (valid) {
      _Float16* dst = xf + (size_t)orow * HD + m * 16;
      *(half8*)dst = h0;
      *(half8*)(dst + 8) = h1;
    }
    ps += __shfl_xor(ps, 1, 64);
    ps += __shfl_xor(ps, 2, 64);
    pd += __shfl_xor(pd, 1, 64);
    pd += __shfl_xor(pd, 2, 64);
    if (valid && (m & 3) == 0) {
      a_src[(size_t)orow * NHEAD + hh] = ps;
      a_dst[(size_t)orow * NHEAD + hh] = pd;
    }
  }
}

// ---------------------------------------------------------------------------
// Fused softmax + gather-aggregate. 4 nodes/block, 1 wave/node.
// Pass 1 (online softmax, lane=(hh, j) over edges): running (m, s), ae-sum.
// Pass 2 (lane = 4 channels): recompute weight per edge in the gather's
// latency shadow; no alpha buffer ever materialized.
// ---------------------------------------------------------------------------
__global__ __launch_bounds__(256) void fused_aggregate_kernel(
    const __half* __restrict__ xh_h, const int* __restrict__ rowc,
    const int* __restrict__ row_start, const float* __restrict__ ae4c_l,
    const float* __restrict__ a_src, const float* __restrict__ a_dst,
    const float* __restrict__ cb, const float* __restrict__ gm,
    const float* __restrict__ bt, float inv_std, float* __restrict__ hout,
    int N) {
  int tid = threadIdx.x;
  int n = blockIdx.x * 4 + (tid >> 6);
  if (n >= N) return;
  int lane = tid & 63;
  int s = row_start[n], e = row_start[n + 1];

  // ---- pass 1: online softmax stats, lane handles head hh1, edges s+j, +16
  int hh1 = lane & 3, j = lane >> 2;
  float based1 = a_dst[n * 4 + hh1];
  float m = -3e38f, ssum = 0.f, aes = 0.f;
  for (int i = s + j; i < e; i += 16) {
    int r = rowc[i];
    float ae = ae4c_l[(size_t)i * 4 + hh1];
    float lg = a_src[r * 4 + hh1] + based1 + ae;
    lg = (lg >= 0.f) ? lg : NEG_SLOPE * lg;
    aes += ae;
    float mn = fmaxf(m, lg);
    ssum = ssum * __expf(m - mn) + __expf(lg - mn);
    m = mn;
  }
#pragma unroll
  for (int off = 4; off < 64; off <<= 1) {
    float m2 = __shfl_xor(m, off, 64);
    float s2 = __shfl_xor(ssum, off, 64);
    aes += __shfl_xor(aes, off, 64);
    float mn = fmaxf(m, m2);
    ssum = ssum * __expf(m - mn) + s2 * __expf(m2 - mn);
    m = mn;
  }
  float dinv = (e > s) ? 1.0f / (float)(e - s) : 1.0f;
  float sl = a_src[n * 4 + hh1] + based1 + aes * dinv;
  sl = (sl >= 0.f) ? sl : NEG_SLOPE * sl;
  float mfin = fmaxf(m, sl);
  float self_e = __expf(sl - mfin);
  float tot = ssum * __expf(m - mfin) + self_e;
  float is = 1.0f / (tot + 1e-16f);
  float selfw = self_e * is;

  // ---- redistribute per-head stats to channel-owner lanes
  int hh2 = lane >> 4;                      // head of my 4 channels
  float m_h = __shfl(mfin, hh2, 64);
  float is_h = __shfl(is, hh2, 64);
  float sw_h = __shfl(selfw, hh2, 64);
  float based2 = a_dst[n * 4 + hh2];

  // ---- pass 2: weighted gather
  int t = lane;                             // half4 index (4 ch/lane)
  int ch = t * 4;
  const half4v* xh4 = (const half4v*)xh_h;  // row stride 64

  half4v sv = xh4[n * 64 + t];
  float a0 = sw_h * (float)sv[0], a1 = sw_h * (float)sv[1];
  float a2 = sw_h * (float)sv[2], a3 = sw_h * (float)sv[3];

  int i = s;
  for (; i + 8 <= e; i += 8) {
    int r[8];
    float w[8];
    half4v xv[8];
#pragma unroll
    for (int u = 0; u < 8; ++u) {
      r[u] = rowc[i + u];
      float lg = a_src[r[u] * 4 + hh2] + based2 + ae4c_l[(size_t)(i + u) * 4 + hh2];
      lg = (lg >= 0.f) ? lg : NEG_SLOPE * lg;
      w[u] = __expf(lg - m_h) * is_h;
    }
#pragma unroll
    for (int u = 0; u < 8; ++u) xv[u] = xh4[r[u] * 64 + t];
#pragma unroll
    for (int u = 0; u < 8; ++u) {
      a0 += w[u] * (float)xv[u][0];
      a1 += w[u] * (float)xv[u][1];
      a2 += w[u] * (float)xv[u][2];
      a3 += w[u] * (float)xv[u][3];
    }
  }
  for (; i < e; ++i) {
    int r = rowc[i];
    float lg = a_src[r * 4 + hh2] + based2 + ae4c_l[(size_t)i * 4 + hh2];
    lg = (lg >= 0.f) ? lg : NEG_SLOPE * lg;
    float w = __expf(lg - m_h) * is_h;
    half4v xv = xh4[r * 64 + t];
    a0 += w * (float)xv[0];
    a1 += w * (float)xv[1];
    a2 += w * (float)xv[2];
    a3 += w * (float)xv[3];
  }
  float4 outv;
  outv.x = fmaxf((a0 + cb[ch + 0]) * inv_std * gm[ch + 0] + bt[ch + 0], 0.f);
  outv.y = fmaxf((a1 + cb[ch + 1]) * inv_std * gm[ch + 1] + bt[ch + 1], 0.f);
  outv.z = fmaxf((a2 + cb[ch + 2]) * inv_std * gm[ch + 2] + bt[ch + 2], 0.f);
  outv.w = fmaxf((a3 + cb[ch + 3]) * inv_std * gm[ch + 3] + bt[ch + 3], 0.f);
  *(float4*)&hout[(size_t)n * HD + ch] = outv;
}

// ---------------------------------------------------------------------------
// Global mean pool over sorted batch ids. One block per graph.
// ---------------------------------------------------------------------------
__global__ __launch_bounds__(256) void pool_kernel(
    const float* __restrict__ h, const int* __restrict__ batch,
    float* __restrict__ out, int N) {
  int g = blockIdx.x;
  int tid = threadIdx.x;
  __shared__ int s_lo, s_hi;
  if (tid == 0) {
    int lo = 0, hi = N;
    while (lo < hi) { int mid = (lo + hi) >> 1; if (batch[mid] < g) lo = mid + 1; else hi = mid; }
    s_lo = lo;
    lo = 0; hi = N;
    while (lo < hi) { int mid = (lo + hi) >> 1; if (batch[mid] < g + 1) lo = mid + 1; else hi = mid; }
    s_hi = lo;
  }
  __syncthreads();
  int lo = s_lo, hi = s_hi;
  float acc = 0.f;
  for (int n = lo; n < hi; ++n) acc += h[(size_t)n * HD + tid];
  int cnt = hi - lo;
  out[(size_t)g * HD + tid] = acc / (float)(cnt > 0 ? cnt : 1);
}

// ---------------------------------------------------------------------------
extern "C" void kernel_launch(void* const* d_in, const int* in_sizes, int n_in,
                              void* d_out, int out_size, void* d_ws, size_t ws_size,
                              hipStream_t stream) {
  const float* x = (const float*)d_in[0];
  const int* ei = (const int*)d_in[1];
  const float* edge_attr = (const float*)d_in[2];
  const int* batch = (const int*)d_in[3];
  const float* Wn = (const float*)d_in[4];
  const float* bn_b = (const float*)d_in[5];
  const float* We = (const float*)d_in[6];
  const float* be_b = (const float*)d_in[7];
  const float* lin_w = (const float*)d_in[8];
  const float* att_src = (const float*)d_in[9];
  const float* att_dst = (const float*)d_in[10];
  const float* lin_edge_w = (const float*)d_in[11];
  const float* att_edge = (const float*)d_in[12];
  const float* conv_bias = (const float*)d_in[13];
  const float* gamma = (const float*)d_in[14];
  const float* beta = (const float*)d_in[15];

  const int N = in_sizes[3];
  const int E = in_sizes[1] / 2;
  const int G = out_size / HD;
  const int* row = ei;
  const int* col = ei + E;

  char* ws = (char*)d_ws;
  size_t off = 0;
  auto alloc = [&](size_t bytes) -> char* {
    char* p = ws + off;
    off += (bytes + 255) & ~(size_t)255;
    return p;
  };
  float* h = (float*)alloc((size_t)N * HD * 4);
  __half* xh_h = (__half*)alloc((size_t)N * HD * 2);
  float* a_src = (float*)alloc((size_t)N * NHEAD * 4);
  float* a_dst = (float*)alloc((size_t)N * NHEAD * 4);
  float* ae4c_all = (float*)alloc((size_t)NLAYER * E * NHEAD * 4);
  int* deg = (int*)alloc((size_t)N * 4);
  int* row_start = (int*)alloc((size_t)(N + 1) * 4);
  int* cursor = (int*)alloc((size_t)N * 4);
  int* rowc = (int*)alloc((size_t)E * 4);
  int* ipos = (int*)alloc((size_t)E * 4);
  int* tsum = (int*)alloc(4096);
  int* toff = (int*)alloc(4096);
  float* Wc = (float*)alloc(64 * 4);
  float* bc = (float*)alloc(16 * 4);
  _Float16* Bf_hi = (_Float16*)alloc((size_t)NLAYER * HD * HD * 2);
  _Float16* Bf_lo = (_Float16*)alloc((size_t)NLAYER * HD * HD * 2);

  hipMemsetAsync(deg, 0, (size_t)N * 4, stream);
  hipMemsetAsync(cursor, 0, (size_t)N * 4, stream);

  node_embed_kernel<<<N, 256, 0, stream>>>(x, Wn, bn_b, h, N);
  precompute_wc_kernel<<<1, 256, 0, stream>>>(lin_edge_w, att_edge, We, be_b, Wc, bc);
  conv_bfrag_kernel<<<NLAYER * 128, 64, 0, stream>>>(lin_w, Bf_hi, Bf_lo);
  count_deg_kernel<<<(E + 255) / 256, 256, 0, stream>>>(col, deg, E);
  int T = (N + 255) / 256;
  tile_sums_kernel<<<T, 256, 0, stream>>>(deg, tsum, N);
  scan_tsums_kernel<<<1, 64, 0, stream>>>(tsum, toff, T);
  scan_local_kernel<<<T, 256, 0, stream>>>(deg, toff, row_start, N, E);
  scatter_csr_kernel<<<(E + 255) / 256, 256, 0, stream>>>(row, col, row_start,
                                                          cursor, rowc, ipos, E);
  edge_ae_kernel<<<(E + 255) / 256, 256, 0, stream>>>(edge_attr, ipos, Wc, bc,
                                                      ae4c_all, E);

  const float inv_std = 1.0f / sqrtf(1.0f + 1e-5f);
  for (int l = 0; l < NLAYER; ++l) {
    mfma_gemm_fused_kernel<<<(N + 63) / 64, 256, 0, stream>>>(
        h, Bf_hi + (size_t)l * HD * HD, Bf_lo + (size_t)l * HD * HD,
        att_src + l * HD, att_dst + l * HD, xh_h, a_src, a_dst, N);
    fused_aggregate_kernel<<<(N + 3) / 4, 256, 0, stream>>>(
        xh_h, rowc, row_start, ae4c_all + (size_t)l * E * NHEAD, a_src, a_dst,
        conv_bias + l * HD, gamma + l * HD, beta + l * HD, inv_std, h, N);
  }
  pool_kernel<<<G, 256, 0, stream>>>(h, batch, (float*)d_out, N);
}

// Round 10
// 619.537 us; speedup vs baseline: 2.7129x; 1.0921x over previous
//
#include <hip/hip_runtime.h>
#include <hip/hip_fp16.h>
#include <math.h>

#define HD 256
#define NHEAD 4
#define CH 64
#define NLAYER 3
#define NEG_SLOPE 0.2f

typedef __attribute__((ext_vector_type(8))) _Float16 half8;
typedef __attribute__((ext_vector_type(4))) _Float16 half4v;
typedef __attribute__((ext_vector_type(4))) float float4v;

// ---------------------------------------------------------------------------
// h0 = x @ Wn + bn_b      (x: [N,9], Wn: [9,256])
// ---------------------------------------------------------------------------
__global__ __launch_bounds__(256) void node_embed_kernel(
    const float* __restrict__ x, const float* __restrict__ Wn,
    const float* __restrict__ bn_b, float* __restrict__ h, int N) {
  int n = blockIdx.x;
  int c = threadIdx.x;
  __shared__ float xs[9];
  if (c < 9) xs[c] = x[(size_t)n * 9 + c];
  __syncthreads();
  float v = bn_b[c];
#pragma unroll
  for (int k = 0; k < 9; ++k) v += xs[k] * Wn[k * HD + c];
  h[(size_t)n * HD + c] = v;
}

// ---------------------------------------------------------------------------
// Fold edge path: Wc[5][12] = We @ w_eff,  bc[12] = be_b @ w_eff.
// Parallelized: 12 blocks, one per (layer, head).
// ---------------------------------------------------------------------------
__global__ __launch_bounds__(256) void precompute_wc_kernel(
    const float* __restrict__ lin_edge_w, const float* __restrict__ att_edge,
    const float* __restrict__ We, const float* __restrict__ be_b,
    float* __restrict__ Wc, float* __restrict__ bc) {
  int lh = blockIdx.x;           // 0..11 = l*4+hh
  int l = lh >> 2, hh = lh & 3;
  __shared__ float weff[256];
  int j = threadIdx.x;
  const float* lw = lin_edge_w + (size_t)l * HD * HD + (size_t)j * HD + hh * CH;
  const float* ae = att_edge + l * HD + hh * CH;
  float s = 0.f;
#pragma unroll 8
  for (int c = 0; c < CH; ++c) s += lw[c] * ae[c];
  weff[j] = s;
  __syncthreads();
  if (j < 5) {
    float acc = 0.f;
    for (int t = 0; t < 256; ++t) acc += We[j * HD + t] * weff[t];
    Wc[j * 12 + lh] = acc;
  } else if (j == 5) {
    float acc = 0.f;
    for (int t = 0; t < 256; ++t) acc += be_b[t] * weff[t];
    bc[lh] = acc;
  }
}

// ---------------------------------------------------------------------------
// Repack lin_w into MFMA B-fragment order, split fp16 hi/lo.
// Interleaved col map: fragment (l,kt,nt), lane -> B[kt*32+(lane>>4)*8+j][(lane&15)*16+nt]
// ---------------------------------------------------------------------------
__global__ __launch_bounds__(64) void conv_bfrag_kernel(
    const float* __restrict__ lin_w, _Float16* __restrict__ Bf_hi,
    _Float16* __restrict__ Bf_lo) {
  int bid = blockIdx.x;            // l*128 + kt*16 + nt
  int l = bid >> 7;
  int kt = (bid >> 4) & 7, nt = bid & 15;
  int lane = threadIdx.x;
  const float* B = lin_w + (size_t)l * HD * HD;
  size_t base = ((size_t)bid * 64 + lane) * 8;
  int k0 = kt * 32 + (lane >> 4) * 8;
  int n = (lane & 15) * 16 + nt;
#pragma unroll
  for (int j = 0; j < 8; ++j) {
    float v = B[(size_t)(k0 + j) * HD + n];
    _Float16 hi = (_Float16)v;
    _Float16 lo = (_Float16)(v - (float)hi);
    Bf_hi[base + j] = hi;
    Bf_lo[base + j] = lo;
  }
}

// ---------------------------------------------------------------------------
// CSR build by destination (col)
// ---------------------------------------------------------------------------
__global__ __launch_bounds__(256) void count_deg_kernel(
    const int* __restrict__ col, int* __restrict__ deg, int E) {
  int e = blockIdx.x * 256 + threadIdx.x;
  if (e < E) atomicAdd(&deg[col[e]], 1);
}

__global__ __launch_bounds__(256) void tile_sums_kernel(
    const int* __restrict__ deg, int* __restrict__ tsum, int N) {
  __shared__ int red[256];
  int i = blockIdx.x * 256 + threadIdx.x;
  red[threadIdx.x] = (i < N) ? deg[i] : 0;
  __syncthreads();
  for (int off = 128; off > 0; off >>= 1) {
    if (threadIdx.x < off) red[threadIdx.x] += red[threadIdx.x + off];
    __syncthreads();
  }
  if (threadIdx.x == 0) tsum[blockIdx.x] = red[0];
}

__global__ __launch_bounds__(64) void scan_tsums_kernel(
    const int* __restrict__ tsum, int* __restrict__ toff, int T) {
  int lane = threadIdx.x;
  int carry = 0;
  for (int base = 0; base < T; base += 64) {
    int i = base + lane;
    int orig = (i < T) ? tsum[i] : 0;
    int v = orig;
#pragma unroll
    for (int off = 1; off < 64; off <<= 1) {
      int t = __shfl_up(v, off, 64);
      if (lane >= off) v += t;
    }
    if (i < T) toff[i] = carry + v - orig;
    carry += __shfl(v, 63, 64);
  }
}

__global__ __launch_bounds__(256) void scan_local_kernel(
    const int* __restrict__ deg, const int* __restrict__ toff,
    int* __restrict__ row_start, int N, int E) {
  __shared__ int buf[256];
  int i = blockIdx.x * 256 + threadIdx.x;
  int v = (i < N) ? deg[i] : 0;
  buf[threadIdx.x] = v;
  __syncthreads();
  for (int off = 1; off < 256; off <<= 1) {
    int t = (threadIdx.x >= off) ? buf[threadIdx.x - off] : 0;
    __syncthreads();
    buf[threadIdx.x] += t;
    __syncthreads();
  }
  if (i < N) row_start[i] = toff[blockIdx.x] + buf[threadIdx.x] - v;
  if (blockIdx.x == 0 && threadIdx.x == 0) row_start[N] = E;
}

__global__ __launch_bounds__(256) void scatter_csr_kernel(
    const int* __restrict__ row, const int* __restrict__ col,
    const int* __restrict__ row_start, int* __restrict__ cursor,
    int* __restrict__ rowc, int* __restrict__ ipos, int E) {
  int e = blockIdx.x * 256 + threadIdx.x;
  if (e < E) {
    int c = col[e];
    int p = atomicAdd(&cursor[c], 1);
    int slot = row_start[c] + p;
    rowc[slot] = row[e];
    ipos[e] = slot;
  }
}

// ---------------------------------------------------------------------------
// Once per launch: a_e for ALL 3 layers, written in CSR order.
// ---------------------------------------------------------------------------
__global__ __launch_bounds__(256) void edge_ae_kernel(
    const float* __restrict__ edge_attr, const int* __restrict__ ipos,
    const float* __restrict__ Wc, const float* __restrict__ bc,
    float* __restrict__ ae4c_all, int E) {
  __shared__ float sWc[60];
  __shared__ float sbc[12];
  int t = threadIdx.x;
  if (t < 60) sWc[t] = Wc[t];
  if (t < 12) sbc[t] = bc[t];
  __syncthreads();
  int e = blockIdx.x * 256 + t;
  if (e >= E) return;
  int slot = ipos[e];
  float ea[5];
#pragma unroll
  for (int k = 0; k < 5; ++k) ea[k] = edge_attr[(size_t)e * 5 + k];
#pragma unroll
  for (int l = 0; l < NLAYER; ++l) {
    float av[NHEAD];
#pragma unroll
    for (int hh = 0; hh < NHEAD; ++hh) {
      int lh = l * NHEAD + hh;
      float s = sbc[lh];
#pragma unroll
      for (int k = 0; k < 5; ++k) s += ea[k] * sWc[k * 12 + lh];
      av[hh] = s;
    }
    *(float4*)(ae4c_all + ((size_t)l * E + slot) * 4) =
        make_float4(av[0], av[1], av[2], av[3]);
  }
}

// ---------------------------------------------------------------------------
// MFMA split-fp16 GEMM, fused epilogue; per-kt B staged in LDS (32 KB).
// ---------------------------------------------------------------------------
__global__ __launch_bounds__(256) void mfma_gemm_fused_kernel(
    const float* __restrict__ A, const _Float16* __restrict__ Bf_hi,
    const _Float16* __restrict__ Bf_lo, const float* __restrict__ att_s,
    const float* __restrict__ att_d, __half* __restrict__ xh_h,
    float* __restrict__ a_src, float* __restrict__ a_dst, int N) {
  __shared__ _Float16 sBh[8192];
  __shared__ _Float16 sBl[8192];
  const int tid = threadIdx.x;
  const int wave = tid >> 6, lane = tid & 63;
  const int m = lane & 15, quad = lane >> 4;
  const int rowbase = blockIdx.x * 64 + wave * 16;
  const int arow = rowbase + m;
  const int arowc = (arow < N) ? arow : (N - 1);

  float4v acc[16];
#pragma unroll
  for (int nt = 0; nt < 16; ++nt) acc[nt] = (float4v){0.f, 0.f, 0.f, 0.f};

  for (int kt = 0; kt < 8; ++kt) {
    __syncthreads();
    {
      const float4* gh = (const float4*)(Bf_hi + (size_t)kt * 8192);
      const float4* gl = (const float4*)(Bf_lo + (size_t)kt * 8192);
      float4* dh = (float4*)sBh;
      float4* dl = (float4*)sBl;
#pragma unroll
      for (int u = 0; u < 4; ++u) {
        dh[tid + u * 256] = gh[tid + u * 256];
        dl[tid + u * 256] = gl[tid + u * 256];
      }
    }
    const float* ap = A + (size_t)arowc * HD + kt * 32 + quad * 8;
    float4 av0 = *(const float4*)(ap);
    float4 av1 = *(const float4*)(ap + 4);
    float af[8] = {av0.x, av0.y, av0.z, av0.w, av1.x, av1.y, av1.z, av1.w};
    half8 ahi, alo;
#pragma unroll
    for (int j = 0; j < 8; ++j) {
      _Float16 hi = (_Float16)af[j];
      ahi[j] = hi;
      alo[j] = (_Float16)(af[j] - (float)hi);
    }
    __syncthreads();
#pragma unroll
    for (int nt = 0; nt < 16; ++nt) {
      half8 bhi = *(const half8*)&sBh[nt * 512 + lane * 8];
      half8 blo = *(const half8*)&sBl[nt * 512 + lane * 8];
      acc[nt] = __builtin_amdgcn_mfma_f32_16x16x32_f16(ahi, bhi, acc[nt], 0, 0, 0);
      acc[nt] = __builtin_amdgcn_mfma_f32_16x16x32_f16(alo, bhi, acc[nt], 0, 0, 0);
      acc[nt] = __builtin_amdgcn_mfma_f32_16x16x32_f16(ahi, blo, acc[nt], 0, 0, 0);
    }
  }

  const int hh = m >> 2;
  float ats[16], atd[16];
#pragma unroll
  for (int nt = 0; nt < 16; ++nt) {
    ats[nt] = att_s[m * 16 + nt];
    atd[nt] = att_d[m * 16 + nt];
  }
  _Float16* xf = (_Float16*)xh_h;
#pragma unroll
  for (int r = 0; r < 4; ++r) {
    int orow = rowbase + quad * 4 + r;
    bool valid = orow < N;
    float ps = 0.f, pd = 0.f;
    half8 h0, h1;
#pragma unroll
    for (int nt = 0; nt < 8; ++nt) {
      h0[nt] = (_Float16)acc[nt][r];
      h1[nt] = (_Float16)acc[nt + 8][r];
      ps += acc[nt][r] * ats[nt] + acc[nt + 8][r] * ats[nt + 8];
      pd += acc[nt][r] * atd[nt] + acc[nt + 8][r] * atd[nt + 8];
    }
    if (valid) {
      _Float16* dst = xf + (size_t)orow * HD + m * 16;
      *(half8*)dst = h0;
      *(half8*)(dst + 8) = h1;
    }
    ps += __shfl_xor(ps, 1, 64);
    ps += __shfl_xor(ps, 2, 64);
    pd += __shfl_xor(pd, 1, 64);
    pd += __shfl_xor(pd, 2, 64);
    if (valid && (m & 3) == 0) {
      a_src[(size_t)orow * NHEAD + hh] = ps;
      a_dst[(size_t)orow * NHEAD + hh] = pd;
    }
  }
}

// ---------------------------------------------------------------------------
// Fused softmax + gather-aggregate. 4 nodes/block, 1 wave/node.
// Pass 1: online softmax (lane = (head, j) over edges) -> per-head m, 1/sum.
// Pass 2: COOPERATIVE weights: lane (eidx=lane&15, head=lane>>4) computes one
// (edge,head) weight per 16-edge chunk; __shfl broadcasts (w, r) to the 16
// channel-lanes of that head. Out-of-range slots get w=0 (gather row 0,
// contributes nothing) -> uniform fully-unrolled inner loop, 16 gathers in
// flight, no redundant exp/VMEM.
// ---------------------------------------------------------------------------
__global__ __launch_bounds__(256) void fused_aggregate_kernel(
    const __half* __restrict__ xh_h, const int* __restrict__ rowc,
    const int* __restrict__ row_start, const float* __restrict__ ae4c_l,
    const float* __restrict__ a_src, const float* __restrict__ a_dst,
    const float* __restrict__ cb, const float* __restrict__ gm,
    const float* __restrict__ bt, float inv_std, float* __restrict__ hout,
    int N) {
  int tid = threadIdx.x;
  int n = blockIdx.x * 4 + (tid >> 6);
  if (n >= N) return;
  int lane = tid & 63;
  int s = row_start[n], e = row_start[n + 1];

  // ---- pass 1: online softmax stats, lane handles head hh1, edges s+j, +16
  int hh1 = lane & 3, j = lane >> 2;
  float based1 = a_dst[n * 4 + hh1];
  float m = -3e38f, ssum = 0.f, aes = 0.f;
  for (int i = s + j; i < e; i += 16) {
    int r = rowc[i];
    float ae = ae4c_l[(size_t)i * 4 + hh1];
    float lg = a_src[r * 4 + hh1] + based1 + ae;
    lg = (lg >= 0.f) ? lg : NEG_SLOPE * lg;
    aes += ae;
    float mn = fmaxf(m, lg);
    ssum = ssum * __expf(m - mn) + __expf(lg - mn);
    m = mn;
  }
#pragma unroll
  for (int off = 4; off < 64; off <<= 1) {
    float m2 = __shfl_xor(m, off, 64);
    float s2 = __shfl_xor(ssum, off, 64);
    aes += __shfl_xor(aes, off, 64);
    float mn = fmaxf(m, m2);
    ssum = ssum * __expf(m - mn) + s2 * __expf(m2 - mn);
    m = mn;
  }
  float dinv = (e > s) ? 1.0f / (float)(e - s) : 1.0f;
  float sl = a_src[n * 4 + hh1] + based1 + aes * dinv;
  sl = (sl >= 0.f) ? sl : NEG_SLOPE * sl;
  float mfin = fmaxf(m, sl);
  float self_e = __expf(sl - mfin);
  float tot = ssum * __expf(m - mfin) + self_e;
  float is = 1.0f / (tot + 1e-16f);
  float selfw = self_e * is;

  // ---- per-head stats to my lane (channel head == weight head == lane>>4)
  int hw = lane >> 4;
  float m_h = __shfl(mfin, hw, 64);
  float is_h = __shfl(is, hw, 64);
  float sw_h = __shfl(selfw, hw, 64);
  float based2 = a_dst[n * 4 + hw];

  int eidx = lane & 15;
  int t = lane;                             // half4 index (4 ch/lane)
  int ch = t * 4;
  const half4v* xh4 = (const half4v*)xh_h;  // row stride 64

  half4v sv = xh4[(size_t)n * 64 + t];
  float a0 = sw_h * (float)sv[0], a1 = sw_h * (float)sv[1];
  float a2 = sw_h * (float)sv[2], a3 = sw_h * (float)sv[3];

  const int base_src = lane & 48;
  for (int chunk = s; chunk < e; chunk += 16) {
    int myedge = chunk + eidx;
    int r_my = 0;
    float w_my = 0.f;
    if (myedge < e) {
      r_my = rowc[myedge];
      float lg = a_src[r_my * 4 + hw] + based2 + ae4c_l[(size_t)myedge * 4 + hw];
      lg = (lg >= 0.f) ? lg : NEG_SLOPE * lg;
      w_my = __expf(lg - m_h) * is_h;
    }
#pragma unroll
    for (int u = 0; u < 16; ++u) {
      float w = __shfl(w_my, base_src + u, 64);
      int ru = __shfl(r_my, base_src + u, 64);
      half4v xv = xh4[(size_t)ru * 64 + t];
      a0 += w * (float)xv[0];
      a1 += w * (float)xv[1];
      a2 += w * (float)xv[2];
      a3 += w * (float)xv[3];
    }
  }
  float4 outv;
  outv.x = fmaxf((a0 + cb[ch + 0]) * inv_std * gm[ch + 0] + bt[ch + 0], 0.f);
  outv.y = fmaxf((a1 + cb[ch + 1]) * inv_std * gm[ch + 1] + bt[ch + 1], 0.f);
  outv.z = fmaxf((a2 + cb[ch + 2]) * inv_std * gm[ch + 2] + bt[ch + 2], 0.f);
  outv.w = fmaxf((a3 + cb[ch + 3]) * inv_std * gm[ch + 3] + bt[ch + 3], 0.f);
  *(float4*)&hout[(size_t)n * HD + ch] = outv;
}

// ---------------------------------------------------------------------------
// Global mean pool over sorted batch ids. Grid (G, 2), 128 ch per block.
// ---------------------------------------------------------------------------
__global__ __launch_bounds__(128) void pool_kernel(
    const float* __restrict__ h, const int* __restrict__ batch,
    float* __restrict__ out, int N) {
  int g = blockIdx.x;
  int ch = blockIdx.y * 128 + threadIdx.x;
  __shared__ int s_lo, s_hi;
  if (threadIdx.x == 0) {
    int lo = 0, hi = N;
    while (lo < hi) { int mid = (lo + hi) >> 1; if (batch[mid] < g) lo = mid + 1; else hi = mid; }
    s_lo = lo;
    lo = 0; hi = N;
    while (lo < hi) { int mid = (lo + hi) >> 1; if (batch[mid] < g + 1) lo = mid + 1; else hi = mid; }
    s_hi = lo;
  }
  __syncthreads();
  int lo = s_lo, hi = s_hi;
  float acc = 0.f;
  for (int n = lo; n < hi; ++n) acc += h[(size_t)n * HD + ch];
  int cnt = hi - lo;
  out[(size_t)g * HD + ch] = acc / (float)(cnt > 0 ? cnt : 1);
}

// ---------------------------------------------------------------------------
extern "C" void kernel_launch(void* const* d_in, const int* in_sizes, int n_in,
                              void* d_out, int out_size, void* d_ws, size_t ws_size,
                              hipStream_t stream) {
  const float* x = (const float*)d_in[0];
  const int* ei = (const int*)d_in[1];
  const float* edge_attr = (const float*)d_in[2];
  const int* batch = (const int*)d_in[3];
  const float* Wn = (const float*)d_in[4];
  const float* bn_b = (const float*)d_in[5];
  const float* We = (const float*)d_in[6];
  const float* be_b = (const float*)d_in[7];
  const float* lin_w = (const float*)d_in[8];
  const float* att_src = (const float*)d_in[9];
  const float* att_dst = (const float*)d_in[10];
  const float* lin_edge_w = (const float*)d_in[11];
  const float* att_edge = (const float*)d_in[12];
  const float* conv_bias = (const float*)d_in[13];
  const float* gamma = (const float*)d_in[14];
  const float* beta = (const float*)d_in[15];

  const int N = in_sizes[3];
  const int E = in_sizes[1] / 2;
  const int G = out_size / HD;
  const int* row = ei;
  const int* col = ei + E;

  char* ws = (char*)d_ws;
  size_t off = 0;
  auto alloc = [&](size_t bytes) -> char* {
    char* p = ws + off;
    off += (bytes + 255) & ~(size_t)255;
    return p;
  };
  float* h = (float*)alloc((size_t)N * HD * 4);
  __half* xh_h = (__half*)alloc((size_t)N * HD * 2);
  float* a_src = (float*)alloc((size_t)N * NHEAD * 4);
  float* a_dst = (float*)alloc((size_t)N * NHEAD * 4);
  float* ae4c_all = (float*)alloc((size_t)NLAYER * E * NHEAD * 4);
  int* deg = (int*)alloc((size_t)N * 4);
  int* row_start = (int*)alloc((size_t)(N + 1) * 4);
  int* cursor = (int*)alloc((size_t)N * 4);
  int* rowc = (int*)alloc((size_t)E * 4);
  int* ipos = (int*)alloc((size_t)E * 4);
  int* tsum = (int*)alloc(4096);
  int* toff = (int*)alloc(4096);
  float* Wc = (float*)alloc(64 * 4);
  float* bc = (float*)alloc(16 * 4);
  _Float16* Bf_hi = (_Float16*)alloc((size_t)NLAYER * HD * HD * 2);
  _Float16* Bf_lo = (_Float16*)alloc((size_t)NLAYER * HD * HD * 2);

  hipMemsetAsync(deg, 0, (size_t)N * 4, stream);
  hipMemsetAsync(cursor, 0, (size_t)N * 4, stream);

  node_embed_kernel<<<N, 256, 0, stream>>>(x, Wn, bn_b, h, N);
  precompute_wc_kernel<<<12, 256, 0, stream>>>(lin_edge_w, att_edge, We, be_b, Wc, bc);
  conv_bfrag_kernel<<<NLAYER * 128, 64, 0, stream>>>(lin_w, Bf_hi, Bf_lo);
  count_deg_kernel<<<(E + 255) / 256, 256, 0, stream>>>(col, deg, E);
  int T = (N + 255) / 256;
  tile_sums_kernel<<<T, 256, 0, stream>>>(deg, tsum, N);
  scan_tsums_kernel<<<1, 64, 0, stream>>>(tsum, toff, T);
  scan_local_kernel<<<T, 256, 0, stream>>>(deg, toff, row_start, N, E);
  scatter_csr_kernel<<<(E + 255) / 256, 256, 0, stream>>>(row, col, row_start,
                                                          cursor, rowc, ipos, E);
  edge_ae_kernel<<<(E + 255) / 256, 256, 0, stream>>>(edge_attr, ipos, Wc, bc,
                                                      ae4c_all, E);

  const float inv_std = 1.0f / sqrtf(1.0f + 1e-5f);
  for (int l = 0; l < NLAYER; ++l) {
    mfma_gemm_fused_kernel<<<(N + 63) / 64, 256, 0, stream>>>(
        h, Bf_hi + (size_t)l * HD * HD, Bf_lo + (size_t)l * HD * HD,
        att_src + l * HD, att_dst + l * HD, xh_h, a_src, a_dst, N);
    fused_aggregate_kernel<<<(N + 3) / 4, 256, 0, stream>>>(
        xh_h, rowc, row_start, ae4c_all + (size_t)l * E * NHEAD, a_src, a_dst,
        conv_bias + l * HD, gamma + l * HD, beta + l * HD, inv_std, h, N);
  }
  dim3 pg(G, 2);
  pool_kernel<<<pg, 128, 0, stream>>>(h, batch, (float*)d_out, N);
}

// Round 11
// 574.380 us; speedup vs baseline: 2.9262x; 1.0786x over previous
//
#include <hip/hip_runtime.h>
#include <hip/hip_fp16.h>
#include <math.h>

#define HD 256
#define NHEAD 4
#define CH 64
#define NLAYER 3
#define NEG_SLOPE 0.2f

typedef __attribute__((ext_vector_type(8))) _Float16 half8;
typedef __attribute__((ext_vector_type(4))) _Float16 half4v;
typedef __attribute__((ext_vector_type(4))) float float4v;

// ---------------------------------------------------------------------------
// h0 = x @ Wn + bn_b      (x: [N,9], Wn: [9,256])
// ---------------------------------------------------------------------------
__global__ __launch_bounds__(256) void node_embed_kernel(
    const float* __restrict__ x, const float* __restrict__ Wn,
    const float* __restrict__ bn_b, float* __restrict__ h, int N) {
  int n = blockIdx.x;
  int c = threadIdx.x;
  __shared__ float xs[9];
  if (c < 9) xs[c] = x[(size_t)n * 9 + c];
  __syncthreads();
  float v = bn_b[c];
#pragma unroll
  for (int k = 0; k < 9; ++k) v += xs[k] * Wn[k * HD + c];
  h[(size_t)n * HD + c] = v;
}

// ---------------------------------------------------------------------------
// Fold edge path: Wc[5][12] = We @ w_eff,  bc[12] = be_b @ w_eff.
// 12 blocks, one per (layer, head).
// ---------------------------------------------------------------------------
__global__ __launch_bounds__(256) void precompute_wc_kernel(
    const float* __restrict__ lin_edge_w, const float* __restrict__ att_edge,
    const float* __restrict__ We, const float* __restrict__ be_b,
    float* __restrict__ Wc, float* __restrict__ bc) {
  int lh = blockIdx.x;           // 0..11 = l*4+hh
  int l = lh >> 2, hh = lh & 3;
  __shared__ float weff[256];
  int j = threadIdx.x;
  const float* lw = lin_edge_w + (size_t)l * HD * HD + (size_t)j * HD + hh * CH;
  const float* ae = att_edge + l * HD + hh * CH;
  float s = 0.f;
#pragma unroll 8
  for (int c = 0; c < CH; ++c) s += lw[c] * ae[c];
  weff[j] = s;
  __syncthreads();
  if (j < 5) {
    float acc = 0.f;
    for (int t = 0; t < 256; ++t) acc += We[j * HD + t] * weff[t];
    Wc[j * 12 + lh] = acc;
  } else if (j == 5) {
    float acc = 0.f;
    for (int t = 0; t < 256; ++t) acc += be_b[t] * weff[t];
    bc[lh] = acc;
  }
}

// ---------------------------------------------------------------------------
// Repack lin_w into MFMA B-fragment order, split fp16 hi/lo.
// Interleaved col map: fragment (l,kt,nt), lane -> B[kt*32+(lane>>4)*8+j][(lane&15)*16+nt]
// ---------------------------------------------------------------------------
__global__ __launch_bounds__(64) void conv_bfrag_kernel(
    const float* __restrict__ lin_w, _Float16* __restrict__ Bf_hi,
    _Float16* __restrict__ Bf_lo) {
  int bid = blockIdx.x;            // l*128 + kt*16 + nt
  int l = bid >> 7;
  int kt = (bid >> 4) & 7, nt = bid & 15;
  int lane = threadIdx.x;
  const float* B = lin_w + (size_t)l * HD * HD;
  size_t base = ((size_t)bid * 64 + lane) * 8;
  int k0 = kt * 32 + (lane >> 4) * 8;
  int n = (lane & 15) * 16 + nt;
#pragma unroll
  for (int j = 0; j < 8; ++j) {
    float v = B[(size_t)(k0 + j) * HD + n];
    _Float16 hi = (_Float16)v;
    _Float16 lo = (_Float16)(v - (float)hi);
    Bf_hi[base + j] = hi;
    Bf_lo[base + j] = lo;
  }
}

// ---------------------------------------------------------------------------
// CSR build by destination (col)
// ---------------------------------------------------------------------------
__global__ __launch_bounds__(256) void count_deg_kernel(
    const int* __restrict__ col, int* __restrict__ deg, int E) {
  int e = blockIdx.x * 256 + threadIdx.x;
  if (e < E) atomicAdd(&deg[col[e]], 1);
}

__global__ __launch_bounds__(256) void tile_sums_kernel(
    const int* __restrict__ deg, int* __restrict__ tsum, int N) {
  __shared__ int red[256];
  int i = blockIdx.x * 256 + threadIdx.x;
  red[threadIdx.x] = (i < N) ? deg[i] : 0;
  __syncthreads();
  for (int off = 128; off > 0; off >>= 1) {
    if (threadIdx.x < off) red[threadIdx.x] += red[threadIdx.x + off];
    __syncthreads();
  }
  if (threadIdx.x == 0) tsum[blockIdx.x] = red[0];
}

__global__ __launch_bounds__(64) void scan_tsums_kernel(
    const int* __restrict__ tsum, int* __restrict__ toff, int T) {
  int lane = threadIdx.x;
  int carry = 0;
  for (int base = 0; base < T; base += 64) {
    int i = base + lane;
    int orig = (i < T) ? tsum[i] : 0;
    int v = orig;
#pragma unroll
    for (int off = 1; off < 64; off <<= 1) {
      int t = __shfl_up(v, off, 64);
      if (lane >= off) v += t;
    }
    if (i < T) toff[i] = carry + v - orig;
    carry += __shfl(v, 63, 64);
  }
}

__global__ __launch_bounds__(256) void scan_local_kernel(
    const int* __restrict__ deg, const int* __restrict__ toff,
    int* __restrict__ row_start, int N, int E) {
  __shared__ int buf[256];
  int i = blockIdx.x * 256 + threadIdx.x;
  int v = (i < N) ? deg[i] : 0;
  buf[threadIdx.x] = v;
  __syncthreads();
  for (int off = 1; off < 256; off <<= 1) {
    int t = (threadIdx.x >= off) ? buf[threadIdx.x - off] : 0;
    __syncthreads();
    buf[threadIdx.x] += t;
    __syncthreads();
  }
  if (i < N) row_start[i] = toff[blockIdx.x] + buf[threadIdx.x] - v;
  if (blockIdx.x == 0 && threadIdx.x == 0) row_start[N] = E;
}

// ---------------------------------------------------------------------------
// CSR scatter + fused per-edge a_e for ALL 3 layers (edge_ae folded in;
// ipos eliminated — slot is in hand right here).
// ---------------------------------------------------------------------------
__global__ __launch_bounds__(256) void scatter_csr_ae_kernel(
    const int* __restrict__ row, const int* __restrict__ col,
    const float* __restrict__ edge_attr, const int* __restrict__ row_start,
    int* __restrict__ cursor, int* __restrict__ rowc,
    const float* __restrict__ Wc, const float* __restrict__ bc,
    float* __restrict__ ae4c_all, int E) {
  __shared__ float sWc[60];
  __shared__ float sbc[12];
  int t = threadIdx.x;
  if (t < 60) sWc[t] = Wc[t];
  if (t < 12) sbc[t] = bc[t];
  __syncthreads();
  int e = blockIdx.x * 256 + t;
  if (e >= E) return;
  int c = col[e];
  int p = atomicAdd(&cursor[c], 1);
  int slot = row_start[c] + p;
  rowc[slot] = row[e];
  float ea[5];
#pragma unroll
  for (int k = 0; k < 5; ++k) ea[k] = edge_attr[(size_t)e * 5 + k];
#pragma unroll
  for (int l = 0; l < NLAYER; ++l) {
    float av[NHEAD];
#pragma unroll
    for (int hh = 0; hh < NHEAD; ++hh) {
      int lh = l * NHEAD + hh;
      float s = sbc[lh];
#pragma unroll
      for (int k = 0; k < 5; ++k) s += ea[k] * sWc[k * 12 + lh];
      av[hh] = s;
    }
    *(float4*)(ae4c_all + ((size_t)l * E + slot) * 4) =
        make_float4(av[0], av[1], av[2], av[3]);
  }
}

// ---------------------------------------------------------------------------
// MFMA split-fp16 GEMM, fused epilogue. 128 rows/block (8 waves, 512 thr),
// per-kt B staged once in 32 KB LDS shared by all 8 waves: halves barrier
// count per row and B L2 traffic vs 64-row blocks.
// ---------------------------------------------------------------------------
__global__ __launch_bounds__(512) void mfma_gemm_fused_kernel(
    const float* __restrict__ A, const _Float16* __restrict__ Bf_hi,
    const _Float16* __restrict__ Bf_lo, const float* __restrict__ att_s,
    const float* __restrict__ att_d, __half* __restrict__ xh_h,
    float* __restrict__ a_src, float* __restrict__ a_dst, int N) {
  __shared__ _Float16 sBh[8192];  // 16 KB kt-slice of Bf_hi
  __shared__ _Float16 sBl[8192];  // 16 KB kt-slice of Bf_lo
  const int tid = threadIdx.x;
  const int wave = tid >> 6, lane = tid & 63;
  const int m = lane & 15, quad = lane >> 4;
  const int rowbase = blockIdx.x * 128 + wave * 16;
  const int arow = rowbase + m;
  const int arowc = (arow < N) ? arow : (N - 1);

  float4v acc[16];
#pragma unroll
  for (int nt = 0; nt < 16; ++nt) acc[nt] = (float4v){0.f, 0.f, 0.f, 0.f};

  for (int kt = 0; kt < 8; ++kt) {
    __syncthreads();  // previous iteration's LDS reads done
    {
      const float4* gh = (const float4*)(Bf_hi + (size_t)kt * 8192);
      const float4* gl = (const float4*)(Bf_lo + (size_t)kt * 8192);
      float4* dh = (float4*)sBh;
      float4* dl = (float4*)sBl;
      dh[tid] = gh[tid];
      dh[tid + 512] = gh[tid + 512];
      dl[tid] = gl[tid];
      dl[tid + 512] = gl[tid + 512];
    }
    const float* ap = A + (size_t)arowc * HD + kt * 32 + quad * 8;
    float4 av0 = *(const float4*)(ap);
    float4 av1 = *(const float4*)(ap + 4);
    float af[8] = {av0.x, av0.y, av0.z, av0.w, av1.x, av1.y, av1.z, av1.w};
    half8 ahi, alo;
#pragma unroll
    for (int j = 0; j < 8; ++j) {
      _Float16 hi = (_Float16)af[j];
      ahi[j] = hi;
      alo[j] = (_Float16)(af[j] - (float)hi);
    }
    __syncthreads();  // staging complete
#pragma unroll
    for (int nt = 0; nt < 16; ++nt) {
      half8 bhi = *(const half8*)&sBh[nt * 512 + lane * 8];
      half8 blo = *(const half8*)&sBl[nt * 512 + lane * 8];
      acc[nt] = __builtin_amdgcn_mfma_f32_16x16x32_f16(ahi, bhi, acc[nt], 0, 0, 0);
      acc[nt] = __builtin_amdgcn_mfma_f32_16x16x32_f16(alo, bhi, acc[nt], 0, 0, 0);
      acc[nt] = __builtin_amdgcn_mfma_f32_16x16x32_f16(ahi, blo, acc[nt], 0, 0, 0);
    }
  }

  const int hh = m >> 2;
  float ats[16], atd[16];
#pragma unroll
  for (int nt = 0; nt < 16; ++nt) {
    ats[nt] = att_s[m * 16 + nt];
    atd[nt] = att_d[m * 16 + nt];
  }
  _Float16* xf = (_Float16*)xh_h;
#pragma unroll
  for (int r = 0; r < 4; ++r) {
    int orow = rowbase + quad * 4 + r;
    bool valid = orow < N;
    float ps = 0.f, pd = 0.f;
    half8 h0, h1;
#pragma unroll
    for (int nt = 0; nt < 8; ++nt) {
      h0[nt] = (_Float16)acc[nt][r];
      h1[nt] = (_Float16)acc[nt + 8][r];
      ps += acc[nt][r] * ats[nt] + acc[nt + 8][r] * ats[nt + 8];
      pd += acc[nt][r] * atd[nt] + acc[nt + 8][r] * atd[nt + 8];
    }
    if (valid) {
      _Float16* dst = xf + (size_t)orow * HD + m * 16;
      *(half8*)dst = h0;
      *(half8*)(dst + 8) = h1;
    }
    ps += __shfl_xor(ps, 1, 64);
    ps += __shfl_xor(ps, 2, 64);
    pd += __shfl_xor(pd, 1, 64);
    pd += __shfl_xor(pd, 2, 64);
    if (valid && (m & 3) == 0) {
      a_src[(size_t)orow * NHEAD + hh] = ps;
      a_dst[(size_t)orow * NHEAD + hh] = pd;
    }
  }
}

// ---------------------------------------------------------------------------
// Fused softmax + gather-aggregate. 4 nodes/block, 1 wave/node.
// Pass 1: online softmax (lane = (head, j)) -> per-head m, 1/sum.
// Pass 2: cooperative weights (lane (eidx, head) computes one weight per
// 16-edge chunk; shfl broadcast); 16 gathers in flight.
// ---------------------------------------------------------------------------
__global__ __launch_bounds__(256) void fused_aggregate_kernel(
    const __half* __restrict__ xh_h, const int* __restrict__ rowc,
    const int* __restrict__ row_start, const float* __restrict__ ae4c_l,
    const float* __restrict__ a_src, const float* __restrict__ a_dst,
    const float* __restrict__ cb, const float* __restrict__ gm,
    const float* __restrict__ bt, float inv_std, float* __restrict__ hout,
    int N) {
  int tid = threadIdx.x;
  int n = blockIdx.x * 4 + (tid >> 6);
  if (n >= N) return;
  int lane = tid & 63;
  int s = row_start[n], e = row_start[n + 1];

  int hh1 = lane & 3, j = lane >> 2;
  float based1 = a_dst[n * 4 + hh1];
  float m = -3e38f, ssum = 0.f, aes = 0.f;
  for (int i = s + j; i < e; i += 16) {
    int r = rowc[i];
    float ae = ae4c_l[(size_t)i * 4 + hh1];
    float lg = a_src[r * 4 + hh1] + based1 + ae;
    lg = (lg >= 0.f) ? lg : NEG_SLOPE * lg;
    aes += ae;
    float mn = fmaxf(m, lg);
    ssum = ssum * __expf(m - mn) + __expf(lg - mn);
    m = mn;
  }
#pragma unroll
  for (int off = 4; off < 64; off <<= 1) {
    float m2 = __shfl_xor(m, off, 64);
    float s2 = __shfl_xor(ssum, off, 64);
    aes += __shfl_xor(aes, off, 64);
    float mn = fmaxf(m, m2);
    ssum = ssum * __expf(m - mn) + s2 * __expf(m2 - mn);
    m = mn;
  }
  float dinv = (e > s) ? 1.0f / (float)(e - s) : 1.0f;
  float sl = a_src[n * 4 + hh1] + based1 + aes * dinv;
  sl = (sl >= 0.f) ? sl : NEG_SLOPE * sl;
  float mfin = fmaxf(m, sl);
  float self_e = __expf(sl - mfin);
  float tot = ssum * __expf(m - mfin) + self_e;
  float is = 1.0f / (tot + 1e-16f);
  float selfw = self_e * is;

  int hw = lane >> 4;
  float m_h = __shfl(mfin, hw, 64);
  float is_h = __shfl(is, hw, 64);
  float sw_h = __shfl(selfw, hw, 64);
  float based2 = a_dst[n * 4 + hw];

  int eidx = lane & 15;
  int t = lane;
  int ch = t * 4;
  const half4v* xh4 = (const half4v*)xh_h;

  half4v sv = xh4[(size_t)n * 64 + t];
  float a0 = sw_h * (float)sv[0], a1 = sw_h * (float)sv[1];
  float a2 = sw_h * (float)sv[2], a3 = sw_h * (float)sv[3];

  const int base_src = lane & 48;
  for (int chunk = s; chunk < e; chunk += 16) {
    int myedge = chunk + eidx;
    int r_my = 0;
    float w_my = 0.f;
    if (myedge < e) {
      r_my = rowc[myedge];
      float lg = a_src[r_my * 4 + hw] + based2 + ae4c_l[(size_t)myedge * 4 + hw];
      lg = (lg >= 0.f) ? lg : NEG_SLOPE * lg;
      w_my = __expf(lg - m_h) * is_h;
    }
#pragma unroll
    for (int u = 0; u < 16; ++u) {
      float w = __shfl(w_my, base_src + u, 64);
      int ru = __shfl(r_my, base_src + u, 64);
      half4v xv = xh4[(size_t)ru * 64 + t];
      a0 += w * (float)xv[0];
      a1 += w * (float)xv[1];
      a2 += w * (float)xv[2];
      a3 += w * (float)xv[3];
    }
  }
  float4 outv;
  outv.x = fmaxf((a0 + cb[ch + 0]) * inv_std * gm[ch + 0] + bt[ch + 0], 0.f);
  outv.y = fmaxf((a1 + cb[ch + 1]) * inv_std * gm[ch + 1] + bt[ch + 1], 0.f);
  outv.z = fmaxf((a2 + cb[ch + 2]) * inv_std * gm[ch + 2] + bt[ch + 2], 0.f);
  outv.w = fmaxf((a3 + cb[ch + 3]) * inv_std * gm[ch + 3] + bt[ch + 3], 0.f);
  *(float4*)&hout[(size_t)n * HD + ch] = outv;
}

// ---------------------------------------------------------------------------
// Global mean pool over sorted batch ids. Grid (G, 2), 128 ch per block.
// ---------------------------------------------------------------------------
__global__ __launch_bounds__(128) void pool_kernel(
    const float* __restrict__ h, const int* __restrict__ batch,
    float* __restrict__ out, int N) {
  int g = blockIdx.x;
  int ch = blockIdx.y * 128 + threadIdx.x;
  __shared__ int s_lo, s_hi;
  if (threadIdx.x == 0) {
    int lo = 0, hi = N;
    while (lo < hi) { int mid = (lo + hi) >> 1; if (batch[mid] < g) lo = mid + 1; else hi = mid; }
    s_lo = lo;
    lo = 0; hi = N;
    while (lo < hi) { int mid = (lo + hi) >> 1; if (batch[mid] < g + 1) lo = mid + 1; else hi = mid; }
    s_hi = lo;
  }
  __syncthreads();
  int lo = s_lo, hi = s_hi;
  float acc = 0.f;
  for (int n = lo; n < hi; ++n) acc += h[(size_t)n * HD + ch];
  int cnt = hi - lo;
  out[(size_t)g * HD + ch] = acc / (float)(cnt > 0 ? cnt : 1);
}

// ---------------------------------------------------------------------------
extern "C" void kernel_launch(void* const* d_in, const int* in_sizes, int n_in,
                              void* d_out, int out_size, void* d_ws, size_t ws_size,
                              hipStream_t stream) {
  const float* x = (const float*)d_in[0];
  const int* ei = (const int*)d_in[1];
  const float* edge_attr = (const float*)d_in[2];
  const int* batch = (const int*)d_in[3];
  const float* Wn = (const float*)d_in[4];
  const float* bn_b = (const float*)d_in[5];
  const float* We = (const float*)d_in[6];
  const float* be_b = (const float*)d_in[7];
  const float* lin_w = (const float*)d_in[8];
  const float* att_src = (const float*)d_in[9];
  const float* att_dst = (const float*)d_in[10];
  const float* lin_edge_w = (const float*)d_in[11];
  const float* att_edge = (const float*)d_in[12];
  const float* conv_bias = (const float*)d_in[13];
  const float* gamma = (const float*)d_in[14];
  const float* beta = (const float*)d_in[15];

  const int N = in_sizes[3];
  const int E = in_sizes[1] / 2;
  const int G = out_size / HD;
  const int* row = ei;
  const int* col = ei + E;

  char* ws = (char*)d_ws;
  size_t off = 0;
  auto alloc = [&](size_t bytes) -> char* {
    char* p = ws + off;
    off += (bytes + 255) & ~(size_t)255;
    return p;
  };
  float* h = (float*)alloc((size_t)N * HD * 4);
  __half* xh_h = (__half*)alloc((size_t)N * HD * 2);
  float* a_src = (float*)alloc((size_t)N * NHEAD * 4);
  float* a_dst = (float*)alloc((size_t)N * NHEAD * 4);
  float* ae4c_all = (float*)alloc((size_t)NLAYER * E * NHEAD * 4);
  int* deg = (int*)alloc((size_t)N * 4);
  int* row_start = (int*)alloc((size_t)(N + 1) * 4);
  int* cursor = (int*)alloc((size_t)N * 4);
  int* rowc = (int*)alloc((size_t)E * 4);
  int* tsum = (int*)alloc(4096);
  int* toff = (int*)alloc(4096);
  float* Wc = (float*)alloc(64 * 4);
  float* bc = (float*)alloc(16 * 4);
  _Float16* Bf_hi = (_Float16*)alloc((size_t)NLAYER * HD * HD * 2);
  _Float16* Bf_lo = (_Float16*)alloc((size_t)NLAYER * HD * HD * 2);

  hipMemsetAsync(deg, 0, (size_t)N * 4, stream);
  hipMemsetAsync(cursor, 0, (size_t)N * 4, stream);

  node_embed_kernel<<<N, 256, 0, stream>>>(x, Wn, bn_b, h, N);
  precompute_wc_kernel<<<12, 256, 0, stream>>>(lin_edge_w, att_edge, We, be_b, Wc, bc);
  conv_bfrag_kernel<<<NLAYER * 128, 64, 0, stream>>>(lin_w, Bf_hi, Bf_lo);
  count_deg_kernel<<<(E + 255) / 256, 256, 0, stream>>>(col, deg, E);
  int T = (N + 255) / 256;
  tile_sums_kernel<<<T, 256, 0, stream>>>(deg, tsum, N);
  scan_tsums_kernel<<<1, 64, 0, stream>>>(tsum, toff, T);
  scan_local_kernel<<<T, 256, 0, stream>>>(deg, toff, row_start, N, E);
  scatter_csr_ae_kernel<<<(E + 255) / 256, 256, 0, stream>>>(
      row, col, edge_attr, row_start, cursor, rowc, Wc, bc, ae4c_all, E);

  const float inv_std = 1.0f / sqrtf(1.0f + 1e-5f);
  for (int l = 0; l < NLAYER; ++l) {
    mfma_gemm_fused_kernel<<<(N + 127) / 128, 512, 0, stream>>>(
        h, Bf_hi + (size_t)l * HD * HD, Bf_lo + (size_t)l * HD * HD,
        att_src + l * HD, att_dst + l * HD, xh_h, a_src, a_dst, N);
    fused_aggregate_kernel<<<(N + 3) / 4, 256, 0, stream>>>(
        xh_h, rowc, row_start, ae4c_all + (size_t)l * E * NHEAD, a_src, a_dst,
        conv_bias + l * HD, gamma + l * HD, beta + l * HD, inv_std, h, N);
  }
  dim3 pg(G, 2);
  pool_kernel<<<pg, 128, 0, stream>>>(h, batch, (float*)d_out, N);
}